// Round 15
// baseline (359.073 us; speedup 1.0000x reference)
//
#include <hip/hip_runtime.h>
#include <hip/hip_bf16.h>
#include <cmath>

typedef __attribute__((ext_vector_type(8))) short bf16x8;
typedef __attribute__((ext_vector_type(4))) float f32x4;

__device__ inline ushort f2bf(float f) {
  __hip_bfloat16 h = __float2bfloat16(f);
  return *reinterpret_cast<ushort*>(&h);
}
__device__ inline float bf2f(ushort u) {
  return __uint_as_float((uint)u << 16);
}
__device__ inline float bflo(uint x) { return __uint_as_float(x << 16); }
__device__ inline float bfhi(uint x) { return __uint_as_float(x & 0xffff0000u); }

// Fused-side decode with XCD-aware bijective chunking.
__device__ inline bool fdecode(int totalS, int gxS, int gyS, int gxT, int gyT,
                               int& bx, int& by, int& bz, bool& isT) {
  const int total = gridDim.x;
  const int id = blockIdx.x;
  int wid = (id & 7) * (total >> 3) + (id >> 3);
  const int totalT = gxT * gyT * 16;
  if (wid >= totalS + totalT) return false;
  isT = wid >= totalS;
  int lid = isT ? wid - totalS : wid;
  const int gx = isT ? gxT : gxS;
  const int gy = isT ? gyT : gyS;
  bx = lid % gx;
  lid /= gx;
  by = lid % gy;
  bz = lid / gy;
  return true;
}

// ---------------------------------------------------------------------------
// fused weight prep. DCN weights FRAGMENT-MAJOR:
// frag (mt,kt) = 16 rows x 32 k; elem (lane, j): o = mt*16+(lane&15),
// k = kt*32+(lane>>4)*8+j. dst = ((mt*72+kt)<<9) + lane*8 + j.
// ---------------------------------------------------------------------------
__global__ __launch_bounds__(256) void prep_weights_kernel(
    const float* __restrict__ t_qw, const float* __restrict__ t_qb,
    const float* __restrict__ t_kw, const float* __restrict__ t_kb,
    const float* __restrict__ s_qw, const float* __restrict__ s_qb,
    const float* __restrict__ s_kw, const float* __restrict__ s_kb,
    const float* __restrict__ t_vw, const float* __restrict__ s_vw,
    const float* __restrict__ t_off_w, const float* __restrict__ s_off_w,
    const float* __restrict__ t_dcn_w, const float* __restrict__ s_dcn_w,
    float* __restrict__ qkw_t, float* __restrict__ qkb_t,
    float* __restrict__ qkw_s, float* __restrict__ qkb_s,
    ushort* __restrict__ Wv_t, ushort* __restrict__ Wv_s,
    ushort* __restrict__ owb_t, ushort* __restrict__ owb_s,
    ushort* __restrict__ Awb_t, ushort* __restrict__ Awb_s) {
  int i = blockIdx.x * 256 + threadIdx.x;
  if (i < 16448) {
    if (i < 8192) qkw_t[i] = t_qw[i];
    else if (i < 16384) qkw_t[i] = t_kw[i - 8192];
    else { int j = i - 16384; qkb_t[j] = (j < 32) ? t_qb[j] : t_kb[j - 32]; }
    return;
  }
  i -= 16448;
  if (i < 16448) {
    if (i < 8192) qkw_s[i] = s_qw[i];
    else if (i < 16384) qkw_s[i] = s_kw[i - 8192];
    else { int j = i - 16384; qkb_s[j] = (j < 32) ? s_qb[j] : s_kb[j - 32]; }
    return;
  }
  i -= 16448;
  if (i < 65536) { Wv_t[i] = f2bf(t_vw[i]); return; }
  i -= 65536;
  if (i < 65536) { Wv_s[i] = f2bf(s_vw[i]); return; }
  i -= 65536;
  if (i < 73728) {
    const int o = i / 2304, k = i % 2304, tap = k >> 8, c = k & 255;
    owb_t[i] = (o < 27) ? f2bf(t_off_w[(size_t)o * 2304 + c * 9 + tap]) : (ushort)0;
    return;
  }
  i -= 73728;
  if (i < 73728) {
    const int o = i / 2304, k = i % 2304, tap = k >> 8, c = k & 255;
    owb_s[i] = (o < 27) ? f2bf(s_off_w[(size_t)o * 2304 + c * 9 + tap]) : (ushort)0;
    return;
  }
  i -= 73728;
  if (i < 589824) {
    const int frag = i >> 9, within = i & 511;
    const int lane = within >> 3, j = within & 7;
    const int mt = frag / 72, kt = frag % 72;
    const int o = mt * 16 + (lane & 15);
    const int k = kt * 32 + (lane >> 4) * 8 + j;
    const int tap = k >> 8, c = k & 255;
    Awb_t[i] = f2bf(t_dcn_w[(size_t)o * 2304 + c * 9 + tap]);
    return;
  }
  i -= 589824;
  if (i < 589824) {
    const int frag = i >> 9, within = i & 511;
    const int lane = within >> 3, j = within & 7;
    const int mt = frag / 72, kt = frag % 72;
    const int o = mt * 16 + (lane & 15);
    const int k = kt * 32 + (lane >> 4) * 8 + j;
    const int tap = k >> 8, c = k & 255;
    Awb_s[i] = f2bf(s_dcn_w[(size_t)o * 2304 + c * 9 + tap]);
  }
}

// ---------------------------------------------------------------------------
// fused conv1x1 (fp32) q|k projection, OC=64
// ---------------------------------------------------------------------------
__global__ __launch_bounds__(256) void conv1x1_fused_kernel(
    const float* __restrict__ xS, const float* __restrict__ wS,
    const float* __restrict__ bS, float* __restrict__ oS, int NS_,
    const float* __restrict__ xT, const float* __restrict__ wT,
    const float* __restrict__ bT, float* __restrict__ oT, int NT_) {
  constexpr int C = 256, OC = 64;
  __shared__ float As[64][17];
  __shared__ float Bs[16][64];
  int bx, by, bz; bool isT;
  if (!fdecode(256, 16, 1, 4, 1, bx, by, bz, isT)) return;
  const float* x = isT ? xT : xS;
  const float* w = isT ? wT : wS;
  const float* bias = isT ? bT : bS;
  float* out = isT ? oT : oS;
  const int N = isT ? NT_ : NS_;
  const int b = bz;
  const int n0 = bx * 64;
  const float* xb = x + (size_t)b * C * N;
  const int tid = threadIdx.x;
  const int tr = tid >> 4, tc = tid & 15;
  float acc[4][4] = {};
  for (int k0 = 0; k0 < C; k0 += 16) {
    for (int i = tid; i < 64 * 16; i += 256) {
      int m = i >> 4, kk = i & 15;
      As[m][kk] = w[(size_t)m * C + k0 + kk];
    }
    for (int i = tid; i < 16 * 64; i += 256) {
      int kk = i >> 6, n = i & 63;
      int gn = n0 + n;
      Bs[kk][n] = (gn < N) ? xb[(size_t)(k0 + kk) * N + gn] : 0.f;
    }
    __syncthreads();
#pragma unroll
    for (int kk = 0; kk < 16; ++kk) {
      float a[4], bb[4];
#pragma unroll
      for (int i = 0; i < 4; i++) a[i] = As[tr * 4 + i][kk];
#pragma unroll
      for (int j = 0; j < 4; j++) bb[j] = Bs[kk][tc * 4 + j];
#pragma unroll
      for (int i = 0; i < 4; i++)
#pragma unroll
        for (int j = 0; j < 4; j++) acc[i][j] += a[i] * bb[j];
    }
    __syncthreads();
  }
  for (int i = 0; i < 4; i++) {
    int gm = tr * 4 + i;
    if (gm >= OC) continue;
    float bv = bias[gm];
    for (int j = 0; j < 4; j++) {
      int gn = n0 + tc * 4 + j;
      if (gn < N) out[((size_t)b * OC + gm) * N + gn] = acc[i][j] + bv;
    }
  }
}

// ---------------------------------------------------------------------------
// fused cast+transpose: x fp32 [C][N] -> xT bf16 [NR][C]
// ---------------------------------------------------------------------------
__global__ __launch_bounds__(256) void cast_transpose_fused_kernel(
    const float* __restrict__ xS, ushort* __restrict__ oS, int NS_, int NRS_,
    const float* __restrict__ xT, ushort* __restrict__ oT, int NT_, int NRT_) {
  constexpr int C = 256;
  __shared__ float T[64][65];
  int bx, by, bz; bool isT;
  if (!fdecode(1024, 16, 4, 4, 4, bx, by, bz, isT)) return;
  const float* x = isT ? xT : xS;
  ushort* xTo = isT ? oT : oS;
  const int N = isT ? NT_ : NS_;
  const int NR = isT ? NRT_ : NRS_;
  const int b = bz;
  const int n0 = bx * 64, c0 = by * 64;
  const float* xb = x + (size_t)b * C * N;
  const int tid = threadIdx.x;
  for (int u = tid; u < 4096; u += 256) {
    const int cc = u >> 6, nn = u & 63;
    const int gn = n0 + nn;
    T[cc][nn] = (gn < N) ? xb[(size_t)(c0 + cc) * N + gn] : 0.f;
  }
  __syncthreads();
  ushort* ob = xTo + (size_t)b * NR * C;
  for (int u = tid; u < 4096; u += 256) {
    const int nn = u >> 6, cc = u & 63;
    ob[(size_t)(n0 + nn) * C + c0 + cc] = f2bf(T[cc][nn]);
  }
}

// ---------------------------------------------------------------------------
// fused cast+pad
// ---------------------------------------------------------------------------
__global__ __launch_bounds__(256) void cast_pad_fused_kernel(
    const float* __restrict__ xS, ushort* __restrict__ oS, int NS_, int NpS_,
    int totS,
    const float* __restrict__ xT, ushort* __restrict__ oT, int NT_, int NpT_,
    int totT) {
  constexpr int C = 256;
  int i = blockIdx.x * 256 + threadIdx.x;
  if (i < totS) {
    const int np = i % NpS_;
    const int c = (i / NpS_) % C;
    const int b = i / (NpS_ * C);
    oS[i] = (np < NS_) ? f2bf(xS[((size_t)b * C + c) * NS_ + np]) : (ushort)0;
    return;
  }
  i -= totS;
  if (i < totT) {
    const int np = i % NpT_;
    const int c = (i / NpT_) % C;
    const int b = i / (NpT_ * C);
    oT[i] = (np < NT_) ? f2bf(xT[((size_t)b * C + c) * NT_ + np]) : (ushort)0;
  }
}

// ---------------------------------------------------------------------------
// fused channel softmax + mcomb
// ---------------------------------------------------------------------------
__global__ __launch_bounds__(256) void softmax_mcomb_kernel(
    const float* __restrict__ Atc, const float* __restrict__ Asc,
    const float* __restrict__ w_t_ch, const float* __restrict__ w_s2t,
    const float* __restrict__ w_s_ch, const float* __restrict__ w_t2s,
    ushort* __restrict__ Mc_t, ushort* __restrict__ Mc_s) {
  const int row = blockIdx.x;
  const int tid = threadIdx.x;
  __shared__ float red[8];
  const size_t idx = (size_t)row * 256 + tid;
  const float a = -Atc[idx];
  const float s = -Asc[idx];
  float ma = a, ms = s;
#pragma unroll
  for (int off = 32; off; off >>= 1) {
    ma = fmaxf(ma, __shfl_xor(ma, off, 64));
    ms = fmaxf(ms, __shfl_xor(ms, off, 64));
  }
  if ((tid & 63) == 0) { red[tid >> 6] = ma; red[4 + (tid >> 6)] = ms; }
  __syncthreads();
  if (tid == 0) {
    float m1 = red[0], m2 = red[4];
    for (int i = 1; i < 4; i++) { m1 = fmaxf(m1, red[i]); m2 = fmaxf(m2, red[4 + i]); }
    red[0] = m1; red[4] = m2;
  }
  __syncthreads();
  ma = red[0]; ms = red[4];
  __syncthreads();
  const float ea = __expf(a - ma), es = __expf(s - ms);
  float sa = ea, ss = es;
#pragma unroll
  for (int off = 32; off; off >>= 1) {
    sa += __shfl_xor(sa, off, 64);
    ss += __shfl_xor(ss, off, 64);
  }
  if ((tid & 63) == 0) { red[tid >> 6] = sa; red[4 + (tid >> 6)] = ss; }
  __syncthreads();
  if (tid == 0) {
    float t1 = 0.f, t2 = 0.f;
    for (int i = 0; i < 4; i++) { t1 += red[i]; t2 += red[4 + i]; }
    red[0] = t1; red[4] = t2;
  }
  __syncthreads();
  const float Pa = ea / red[0], Ps = es / red[4];
  Mc_t[idx] = f2bf(w_t_ch[0] * Pa + w_s2t[0] * Ps);
  Mc_s[idx] = f2bf(w_s_ch[0] * Ps + w_t2s[0] * Pa);
}

// ---------------------------------------------------------------------------
// fused generic bf16 GEMM, BM=128, NW=4.
// EPI 0: outBf = bf16(acc+bias) padded   EPI 2: outF = acc
// ---------------------------------------------------------------------------
template <int EPI>
__global__ __launch_bounds__(256) void gemm_fused_kernel(
    const ushort* __restrict__ AS, int aPerB_S, const ushort* __restrict__ BtS,
    const float* __restrict__ biasS, ushort* __restrict__ outBfS,
    float* __restrict__ outFS, int NS_, int NpS_, int NRS_, int KpS_,
    const ushort* __restrict__ AT, int aPerB_T, const ushort* __restrict__ BtT,
    const float* __restrict__ biasT, ushort* __restrict__ outBfT,
    float* __restrict__ outFT, int NT_, int NpT_, int NRT_, int KpT_,
    int totalS, int gxS, int gxT) {
  constexpr int CM = 256, BM = 128, NW = 4, NF = 2, WN = 2;
  __shared__ ushort Asm[BM][40];
  __shared__ ushort Bsm[64][40];
  int bx, by, bz; bool isT;
  if (!fdecode(totalS, gxS, 2, gxT, 2, bx, by, bz, isT)) return;
  const ushort* A = isT ? AT : AS;
  const ushort* Bt = isT ? BtT : BtS;
  const float* bias = isT ? biasT : biasS;
  ushort* outBf = isT ? outBfT : outBfS;
  float* outF = isT ? outFT : outFS;
  const int aPerBatch = isT ? aPerB_T : aPerB_S;
  const int N = isT ? NT_ : NS_, Np = isT ? NpT_ : NpS_;
  const int NR = isT ? NRT_ : NRS_, Kp = isT ? KpT_ : KpS_;
  const int n0 = bx * 64, m0 = by * BM, b = bz;
  const ushort* Ab = A + (size_t)(aPerBatch ? b : 0) * CM * Kp;
  const ushort* Bb = Bt + (size_t)b * NR * Kp;
  const int tid = threadIdx.x, lane = tid & 63, w = tid >> 6;
  const int wr = w / WN, wc = w % WN;
  f32x4 acc[4][NF];
#pragma unroll
  for (int i = 0; i < 4; i++)
#pragma unroll
    for (int j = 0; j < NF; j++) acc[i][j] = (f32x4){0.f, 0.f, 0.f, 0.f};
  for (int k0 = 0; k0 < Kp; k0 += 32) {
    for (int u = tid; u < BM * 4; u += NW * 64) {
      const int row = u >> 2, seg = u & 3;
      *reinterpret_cast<uint4*>(&Asm[row][seg * 8]) =
          *reinterpret_cast<const uint4*>(&Ab[(size_t)(m0 + row) * Kp + k0 + seg * 8]);
    }
    for (int u = tid; u < 64 * 4; u += NW * 64) {
      const int row = u >> 2, seg = u & 3;
      *reinterpret_cast<uint4*>(&Bsm[row][seg * 8]) =
          *reinterpret_cast<const uint4*>(&Bb[(size_t)(n0 + row) * Kp + k0 + seg * 8]);
    }
    __syncthreads();
    const int koff = (lane >> 4) * 8;
    bf16x8 af[4], bfr[NF];
#pragma unroll
    for (int mf = 0; mf < 4; mf++)
      af[mf] = *reinterpret_cast<const bf16x8*>(&Asm[wr * 64 + mf * 16 + (lane & 15)][koff]);
#pragma unroll
    for (int nf = 0; nf < NF; nf++)
      bfr[nf] = *reinterpret_cast<const bf16x8*>(&Bsm[wc * NF * 16 + nf * 16 + (lane & 15)][koff]);
#pragma unroll
    for (int mf = 0; mf < 4; mf++)
#pragma unroll
      for (int nf = 0; nf < NF; nf++)
        acc[mf][nf] = __builtin_amdgcn_mfma_f32_16x16x32_bf16(af[mf], bfr[nf], acc[mf][nf], 0, 0, 0);
    __syncthreads();
  }
#pragma unroll
  for (int mf = 0; mf < 4; mf++) {
    const int mbase = m0 + wr * 64 + mf * 16 + ((lane >> 4) * 4);
#pragma unroll
    for (int nf = 0; nf < NF; nf++) {
      const int gn = n0 + wc * NF * 16 + nf * 16 + (lane & 15);
      if (EPI == 0) {
#pragma unroll
        for (int rr = 0; rr < 4; rr++) {
          const int m = mbase + rr;
          if (gn < Np) {
            ushort v = (gn < N) ? f2bf(acc[mf][nf][rr] + bias[m]) : (ushort)0;
            outBf[((size_t)b * CM + m) * Np + gn] = v;
          }
        }
      } else {
#pragma unroll
        for (int rr = 0; rr < 4; rr++) {
          if (gn < N)
            outF[((size_t)b * CM + mbase + rr) * N + gn] = acc[mf][nf][rr];
        }
      }
    }
  }
  (void)NR;
}

// ---------------------------------------------------------------------------
// fused energy (K=32)
// ---------------------------------------------------------------------------
__global__ __launch_bounds__(256) void energy_fused_kernel(
    const float* __restrict__ qkS, ushort* __restrict__ SS, int NS_, int NpS_,
    const float* __restrict__ qkT, ushort* __restrict__ ST, int NT_, int NpT_) {
  __shared__ ushort Aq[64][40];
  __shared__ ushort Bk[64][40];
  int bx, by, bz; bool isT;
  if (!fdecode(4096, 16, 16, 4, 4, bx, by, bz, isT)) return;
  const float* qk = isT ? qkT : qkS;
  ushort* Sbf = isT ? ST : SS;
  const int N = isT ? NT_ : NS_, Np = isT ? NpT_ : NpS_;
  const int m0 = bx * 64, n0 = by * 64, b = bz;
  const float* qb = qk + (size_t)b * 64 * N;
  const float* kb = qb + (size_t)32 * N;
  const int tid = threadIdx.x, lane = tid & 63, w = tid >> 6;
  for (int u = tid; u < 2048; u += 256) {
    const int c = u >> 6, nn = u & 63;
    const int gn = n0 + nn, gm = m0 + nn;
    Aq[nn][c] = (gn < N) ? f2bf(qb[(size_t)c * N + gn]) : (ushort)0;
    Bk[nn][c] = (gm < N) ? f2bf(kb[(size_t)c * N + gm]) : (ushort)0;
  }
  __syncthreads();
  const int koff = (lane >> 4) * 8;
  const bf16x8 af = *reinterpret_cast<const bf16x8*>(&Aq[w * 16 + (lane & 15)][koff]);
  f32x4 acc[4];
#pragma unroll
  for (int j = 0; j < 4; j++) {
    const bf16x8 bf = *reinterpret_cast<const bf16x8*>(&Bk[j * 16 + (lane & 15)][koff]);
    acc[j] = __builtin_amdgcn_mfma_f32_16x16x32_bf16(af, bf, (f32x4){0.f, 0.f, 0.f, 0.f}, 0, 0, 0);
  }
#pragma unroll
  for (int j = 0; j < 4; j++) {
    const int m = m0 + j * 16 + (lane & 15);
    if (m >= Np) continue;
#pragma unroll
    for (int r = 0; r < 4; r++) {
      const int n = n0 + w * 16 + (lane >> 4) * 4 + r;
      if (n < N) Sbf[((size_t)b * N + n) * Np + m] = (m < N) ? f2bf(acc[j][r]) : (ushort)0;
    }
  }
}

// ---------------------------------------------------------------------------
// fused bf16 row softmax (spatial scores)
// ---------------------------------------------------------------------------
__global__ __launch_bounds__(256) void softmax_bf16_fused_kernel(
    ushort* __restrict__ Ss, int Ns, int Nps, ushort* __restrict__ St, int Nt,
    int Npt, int rowsS) {
  __shared__ float buf[992];
  __shared__ float red[4];
  const int row = blockIdx.x;
  ushort* r;
  int N;
  if (row < rowsS) {
    r = Ss + (size_t)row * Nps;
    N = Ns;
  } else {
    r = St + (size_t)(row - rowsS) * Npt;
    N = Nt;
  }
  const int tid = threadIdx.x;
  float mx = -1e30f;
  for (int i = tid; i < N; i += 256) {
    float f = bf2f(r[i]);
    buf[i] = f;
    mx = fmaxf(mx, f);
  }
#pragma unroll
  for (int off = 32; off; off >>= 1) mx = fmaxf(mx, __shfl_xor(mx, off, 64));
  if ((tid & 63) == 0) red[tid >> 6] = mx;
  __syncthreads();
  if (tid == 0) {
    float m2 = red[0];
    for (int i = 1; i < 4; i++) m2 = fmaxf(m2, red[i]);
    red[0] = m2;
  }
  __syncthreads();
  mx = red[0];
  __syncthreads();
  float s = 0.f;
  for (int i = tid; i < N; i += 256) {
    float v = __expf(buf[i] - mx);
    buf[i] = v;
    s += v;
  }
#pragma unroll
  for (int off = 32; off; off >>= 1) s += __shfl_xor(s, off, 64);
  if ((tid & 63) == 0) red[tid >> 6] = s;
  __syncthreads();
  if (tid == 0) {
    float t = 0.f;
    for (int i = 0; i < 4; i++) t += red[i];
    red[0] = t;
  }
  __syncthreads();
  const float inv = 1.f / red[0];
  for (int i = tid; i < N; i += 256) r[i] = f2bf(buf[i] * inv);
}

// ---------------------------------------------------------------------------
// fused PV+CHAN merged GEMM (BM=128): acc = PV(v@S^T); acc *= g;
// acc += Mc@xT; out_xsT = bf16(x + acc).
// ---------------------------------------------------------------------------
__global__ __launch_bounds__(256) void pv_chan_fused_kernel(
    const ushort* __restrict__ vS, const ushort* __restrict__ SS,
    const ushort* __restrict__ McS, const ushort* __restrict__ xTS,
    const float* __restrict__ xS, const float* __restrict__ gS,
    ushort* __restrict__ xsTS, int NS_, int NpS_, int NRS_,
    const ushort* __restrict__ vT, const ushort* __restrict__ ST,
    const ushort* __restrict__ McT, const ushort* __restrict__ xTT,
    const float* __restrict__ xT_, const float* __restrict__ gT,
    ushort* __restrict__ xsTT, int NT_, int NpT_, int NRT_) {
  constexpr int C = 256, BM = 128, NW = 4, NF = 2, WN = 2;
  __shared__ ushort Asm[BM][40];
  __shared__ ushort Bsm[64][40];
  int bx, by, bz; bool isT;
  if (!fdecode(512, 16, 2, 4, 2, bx, by, bz, isT)) return;
  const ushort* vbf = isT ? vT : vS;
  const ushort* Sbf = isT ? ST : SS;
  const ushort* Mc = isT ? McT : McS;
  const ushort* xTb = isT ? xTT : xTS;
  const float* x = isT ? xT_ : xS;
  const float* gp = isT ? gT : gS;
  ushort* xsT = isT ? xsTT : xsTS;
  const int N = isT ? NT_ : NS_, Np = isT ? NpT_ : NpS_;
  const int NR = isT ? NRT_ : NRS_;
  const int n0 = bx * 64, m0 = by * BM, b = bz;
  const int tid = threadIdx.x, lane = tid & 63, w = tid >> 6;
  const int wr = w / WN, wc = w % WN;
  f32x4 acc[4][NF];
#pragma unroll
  for (int i = 0; i < 4; i++)
#pragma unroll
    for (int j = 0; j < NF; j++) acc[i][j] = (f32x4){0.f, 0.f, 0.f, 0.f};
  const int koff = (lane >> 4) * 8;
  // phase 1: PV, K = Np
  {
    const ushort* Ab = vbf + (size_t)b * C * Np;
    const ushort* Bb = Sbf + (size_t)b * (size_t)N * Np;
    for (int k0 = 0; k0 < Np; k0 += 32) {
      for (int u = tid; u < BM * 4; u += NW * 64) {
        const int row = u >> 2, seg = u & 3;
        *reinterpret_cast<uint4*>(&Asm[row][seg * 8]) =
            *reinterpret_cast<const uint4*>(&Ab[(size_t)(m0 + row) * Np + k0 + seg * 8]);
      }
      for (int u = tid; u < 64 * 4; u += NW * 64) {
        const int row = u >> 2, seg = u & 3;
        const int gn = n0 + row;
        uint4 val;
        if (gn < N)
          val = *reinterpret_cast<const uint4*>(&Bb[(size_t)gn * Np + k0 + seg * 8]);
        else
          val = make_uint4(0, 0, 0, 0);
        *reinterpret_cast<uint4*>(&Bsm[row][seg * 8]) = val;
      }
      __syncthreads();
      bf16x8 af[4], bfr[NF];
#pragma unroll
      for (int mf = 0; mf < 4; mf++)
        af[mf] = *reinterpret_cast<const bf16x8*>(&Asm[wr * 64 + mf * 16 + (lane & 15)][koff]);
#pragma unroll
      for (int nf = 0; nf < NF; nf++)
        bfr[nf] = *reinterpret_cast<const bf16x8*>(&Bsm[wc * NF * 16 + nf * 16 + (lane & 15)][koff]);
#pragma unroll
      for (int mf = 0; mf < 4; mf++)
#pragma unroll
        for (int nf = 0; nf < NF; nf++)
          acc[mf][nf] = __builtin_amdgcn_mfma_f32_16x16x32_bf16(af[mf], bfr[nf], acc[mf][nf], 0, 0, 0);
      __syncthreads();
    }
  }
  const float g = *gp;
#pragma unroll
  for (int mf = 0; mf < 4; mf++)
#pragma unroll
    for (int nf = 0; nf < NF; nf++)
#pragma unroll
      for (int rr = 0; rr < 4; rr++) acc[mf][nf][rr] *= g;
  // phase 2: chan, K = C
  {
    const ushort* Ab = Mc + (size_t)b * C * C;
    const ushort* Bb = xTb + (size_t)b * NR * C;
    for (int k0 = 0; k0 < C; k0 += 32) {
      for (int u = tid; u < BM * 4; u += NW * 64) {
        const int row = u >> 2, seg = u & 3;
        *reinterpret_cast<uint4*>(&Asm[row][seg * 8]) =
            *reinterpret_cast<const uint4*>(&Ab[(size_t)(m0 + row) * C + k0 + seg * 8]);
      }
      for (int u = tid; u < 64 * 4; u += NW * 64) {
        const int row = u >> 2, seg = u & 3;
        *reinterpret_cast<uint4*>(&Bsm[row][seg * 8]) =
            *reinterpret_cast<const uint4*>(&Bb[(size_t)(n0 + row) * C + k0 + seg * 8]);
      }
      __syncthreads();
      bf16x8 af[4], bfr[NF];
#pragma unroll
      for (int mf = 0; mf < 4; mf++)
        af[mf] = *reinterpret_cast<const bf16x8*>(&Asm[wr * 64 + mf * 16 + (lane & 15)][koff]);
#pragma unroll
      for (int nf = 0; nf < NF; nf++)
        bfr[nf] = *reinterpret_cast<const bf16x8*>(&Bsm[wc * NF * 16 + nf * 16 + (lane & 15)][koff]);
#pragma unroll
      for (int mf = 0; mf < 4; mf++)
#pragma unroll
        for (int nf = 0; nf < NF; nf++)
          acc[mf][nf] = __builtin_amdgcn_mfma_f32_16x16x32_bf16(af[mf], bfr[nf], acc[mf][nf], 0, 0, 0);
      __syncthreads();
    }
  }
#pragma unroll
  for (int mf = 0; mf < 4; mf++) {
    const int mbase = m0 + wr * 64 + mf * 16 + ((lane >> 4) * 4);
#pragma unroll
    for (int nf = 0; nf < NF; nf++) {
      const int gn = n0 + wc * NF * 16 + nf * 16 + (lane & 15);
      if (gn < N) {
        float s[4];
#pragma unroll
        for (int rr = 0; rr < 4; rr++)
          s[rr] = x[((size_t)b * C + mbase + rr) * N + gn] + acc[mf][nf][rr];
        uint lo = (uint)f2bf(s[0]) | ((uint)f2bf(s[1]) << 16);
        uint hi = (uint)f2bf(s[2]) | ((uint)f2bf(s[3]) << 16);
        *reinterpret_cast<uint2*>(&xsT[((size_t)b * NR + gn) * C + mbase]) =
            make_uint2(lo, hi);
      }
    }
  }
}

// ---------------------------------------------------------------------------
// fused offconv via MFMA on xsT. BK=128.
// ---------------------------------------------------------------------------
__global__ __launch_bounds__(256) void offconv_fused_kernel(
    const ushort* __restrict__ xS, const ushort* __restrict__ owS,
    const float* __restrict__ obS, float* __restrict__ omS, int HS_, int WS_,
    int NS_, int NRS_,
    const ushort* __restrict__ xT, const ushort* __restrict__ owT,
    const float* __restrict__ obT, float* __restrict__ omT, int HT_, int WT_,
    int NT_, int NRT_) {
  __shared__ ushort Asm[32][136];
  __shared__ ushort Bsm[64][136];
  __shared__ int qsrc[64];
  int bx, by, bz; bool isT;
  if (!fdecode(256, 16, 1, 4, 1, bx, by, bz, isT)) return;
  const ushort* xsT = isT ? xT : xS;
  const ushort* owb = isT ? owT : owS;
  const float* ob = isT ? obT : obS;
  float* om = isT ? omT : omS;
  const int H = isT ? HT_ : HS_, Wd = isT ? WT_ : WS_;
  const int N = isT ? NT_ : NS_, NR = isT ? NRT_ : NRS_;
  const int n0 = bx * 64, b = bz;
  const int tid = threadIdx.x, lane = tid & 63, w = tid >> 6;
  const ushort* xb = xsT + (size_t)b * NR * 256;
  f32x4 acc[2];
  acc[0] = (f32x4){0.f, 0.f, 0.f, 0.f};
  acc[1] = (f32x4){0.f, 0.f, 0.f, 0.f};
  for (int tap = 0; tap < 9; ++tap) {
    const int dy = tap / 3 - 1, dx = tap - (tap / 3) * 3 - 1;
    if (tid < 64) {
      const int p = n0 + tid;
      int q = -1;
      if (p < N) {
        const int h = p / Wd, ww = p - (p / Wd) * Wd;
        const int yy = h + dy, xx = ww + dx;
        if (yy >= 0 && yy < H && xx >= 0 && xx < Wd) q = yy * Wd + xx;
      }
      qsrc[tid] = q;
    }
    __syncthreads();
#pragma unroll
    for (int half = 0; half < 2; ++half) {
      const int k0 = tap * 256 + half * 128;
      for (int u = tid; u < 512; u += 256) {
        const int row = u >> 4, seg = u & 15;
        *reinterpret_cast<uint4*>(&Asm[row][seg * 8]) =
            *reinterpret_cast<const uint4*>(&owb[(size_t)row * 2304 + k0 + seg * 8]);
      }
      for (int u = tid; u < 1024; u += 256) {
        const int row = u >> 4, seg = u & 15;
        const int q = qsrc[row];
        uint4 val = make_uint4(0, 0, 0, 0);
        if (q >= 0)
          val = *reinterpret_cast<const uint4*>(&xb[(size_t)q * 256 + half * 128 + seg * 8]);
        *reinterpret_cast<uint4*>(&Bsm[row][seg * 8]) = val;
      }
      __syncthreads();
#pragma unroll
      for (int sub = 0; sub < 4; ++sub) {
        const int koff = sub * 32 + (lane >> 4) * 8;
        const bf16x8 b0 = *reinterpret_cast<const bf16x8*>(&Bsm[w * 16 + (lane & 15)][koff]);
#pragma unroll
        for (int mf = 0; mf < 2; ++mf) {
          const bf16x8 a0 = *reinterpret_cast<const bf16x8*>(&Asm[mf * 16 + (lane & 15)][koff]);
          acc[mf] = __builtin_amdgcn_mfma_f32_16x16x32_bf16(a0, b0, acc[mf], 0, 0, 0);
        }
      }
      __syncthreads();
    }
  }
#pragma unroll
  for (int mf = 0; mf < 2; ++mf) {
#pragma unroll
    for (int r = 0; r < 4; ++r) {
      const int o = mf * 16 + (lane >> 4) * 4 + r;
      const int n = n0 + w * 16 + (lane & 15);
      if (o < 27 && n < N)
        om[((size_t)b * 27 + o) * N + n] = acc[mf][r] + ob[o];
    }
  }
}

// ---------------------------------------------------------------------------
// fused bilinear gather table prep
// ---------------------------------------------------------------------------
__device__ inline void prep_one(const float* omb, uint4* prep, int i, int p,
                                int k, int H, int Wd, int N) {
  const float offy = omb[(size_t)k * N + p];
  const float offx = omb[(size_t)(9 + k) * N + p];
  const float mraw = omb[(size_t)(18 + k) * N + p];
  const float mval = 1.f / (1.f + __expf(-mraw));
  const int ky = k / 3, kx = k - (k / 3) * 3;
  const int h = p / Wd, w = p - (p / Wd) * Wd;
  const float py = offy + (float)(h + ky - 1);
  const float px = offx + (float)(w + kx - 1);
  const float y0f = floorf(py), x0f = floorf(px);
  const float wy = py - y0f, wx = px - x0f;
  const int y0 = (int)y0f, x0 = (int)x0f;
  const int ys0 = min(max(y0, 0), H - 2);
  const int xs0 = min(max(x0, 0), Wd - 2);
  const float wr0 = (ys0 == y0) ? (1.f - wy) : ((ys0 == y0 + 1) ? wy : 0.f);
  const float wr1 = (ys0 + 1 == y0) ? (1.f - wy) : ((ys0 + 1 == y0 + 1) ? wy : 0.f);
  const float wc0 = (xs0 == x0) ? (1.f - wx) : ((xs0 == x0 + 1) ? wx : 0.f);
  const float wc1 = (xs0 + 1 == x0) ? (1.f - wx) : ((xs0 + 1 == x0 + 1) ? wx : 0.f);
  const float w00 = wr0 * wc0 * mval, w01 = wr0 * wc1 * mval;
  const float w10 = wr1 * wc0 * mval, w11 = wr1 * wc1 * mval;
  uint4 pk;
  pk.x = (uint)(ys0 * Wd + xs0);
  pk.y = (uint)f2bf(w00) | ((uint)f2bf(w01) << 16);
  pk.z = (uint)f2bf(w10) | ((uint)f2bf(w11) << 16);
  pk.w = 0;
  prep[i] = pk;
}

__global__ __launch_bounds__(256) void prep_offsets_fused_kernel(
    const float* __restrict__ omS, uint4* __restrict__ prepS, int HS_, int WS_,
    int totS,
    const float* __restrict__ omT, uint4* __restrict__ prepT, int HT_, int WT_,
    int totT) {
  int i = blockIdx.x * 256 + threadIdx.x;
  if (i < totS) {
    const int N = HS_ * WS_;
    const int p = i % N, k = (i / N) % 9, b = i / (9 * N);
    prep_one(omS + (size_t)b * 27 * N, prepS, i, p, k, HS_, WS_, N);
    return;
  }
  i -= totS;
  if (i < totT) {
    const int N = HT_ * WT_;
    const int p = i % N, k = (i / N) % 9, b = i / (9 * N);
    prep_one(omT + (size_t)b * 27 * N, prepT, i, p, k, HT_, WT_, N);
  }
}

// ---------------------------------------------------------------------------
// fused DCN via MFMA. r15: fragment-major register A (no LDS) + DOUBLE-
// BUFFERED Bsm -> single barrier per K-step + setprio around MFMA.
// BM=256, BK=64, BN=32, 512 thr. s gx=32, t gx=8; gy=1.
// ---------------------------------------------------------------------------
__global__ __launch_bounds__(512) void dcn_fused_kernel(
    const ushort* __restrict__ xS, const uint4* __restrict__ prS,
    const ushort* __restrict__ AwS, const float* __restrict__ biS,
    float* __restrict__ oS, int NS_, int WS_, int NRS_,
    const ushort* __restrict__ xT, const uint4* __restrict__ prT,
    const ushort* __restrict__ AwT, const float* __restrict__ biT,
    float* __restrict__ oT, int NT_, int WT_, int NRT_) {
  constexpr int C = 256, MF = 4;
  __shared__ ushort Bsm[2][32][72];
  __shared__ int sq[32];
  __shared__ float swl[4][32];
  int bx, by, bz; bool isT;
  if (!fdecode(512, 32, 1, 8, 1, bx, by, bz, isT)) return;
  const ushort* xsT = isT ? xT : xS;
  const uint4* prep = isT ? prT : prS;
  const ushort* Awb = isT ? AwT : AwS;
  const float* bias = isT ? biT : biS;
  float* out = isT ? oT : oS;
  const int N = isT ? NT_ : NS_, Wd = isT ? WT_ : WS_, NR = isT ? NRT_ : NRS_;
  const int n0 = bx * 32, b = bz;
  const int tid = threadIdx.x, lane = tid & 63, w = tid >> 6;
  const int wr = w >> 1, wc = w & 1;
  const ushort* xb = xsT + (size_t)b * NR * C;
  const int un0 = tid >> 5;
  const int un1 = un0 + 16;
  const int kk2 = (tid & 31) * 2;
  f32x4 acc[MF];
#pragma unroll
  for (int i = 0; i < MF; i++) acc[i] = (f32x4){0.f, 0.f, 0.f, 0.f};
  uint bReg[2][4];
  int sqr0 = 0, sqr1 = 0;
  float w0a[4], w1a[4];
  const size_t rowYp = (size_t)Wd * C;

  auto loadCorners = [&](int cbase) {
    const ushort* pA = xb + sqr0 + cbase + kk2;
    bReg[0][0] = *reinterpret_cast<const uint*>(pA);
    bReg[0][1] = *reinterpret_cast<const uint*>(pA + C);
    bReg[0][2] = *reinterpret_cast<const uint*>(pA + rowYp);
    bReg[0][3] = *reinterpret_cast<const uint*>(pA + rowYp + C);
    const ushort* pB = xb + sqr1 + cbase + kk2;
    bReg[1][0] = *reinterpret_cast<const uint*>(pB);
    bReg[1][1] = *reinterpret_cast<const uint*>(pB + C);
    bReg[1][2] = *reinterpret_cast<const uint*>(pB + rowYp);
    bReg[1][3] = *reinterpret_cast<const uint*>(pB + rowYp + C);
  };
  auto packB = [&](int buf) {
    const float vlo0 = w0a[0] * bflo(bReg[0][0]) + w0a[1] * bflo(bReg[0][1]) +
                       w0a[2] * bflo(bReg[0][2]) + w0a[3] * bflo(bReg[0][3]);
    const float vhi0 = w0a[0] * bfhi(bReg[0][0]) + w0a[1] * bfhi(bReg[0][1]) +
                       w0a[2] * bfhi(bReg[0][2]) + w0a[3] * bfhi(bReg[0][3]);
    *reinterpret_cast<uint*>(&Bsm[buf][un0][kk2]) =
        (uint)f2bf(vlo0) | ((uint)f2bf(vhi0) << 16);
    const float vlo1 = w1a[0] * bflo(bReg[1][0]) + w1a[1] * bflo(bReg[1][1]) +
                       w1a[2] * bflo(bReg[1][2]) + w1a[3] * bflo(bReg[1][3]);
    const float vhi1 = w1a[0] * bfhi(bReg[1][0]) + w1a[1] * bfhi(bReg[1][1]) +
                       w1a[2] * bfhi(bReg[1][2]) + w1a[3] * bfhi(bReg[1][3]);
    *reinterpret_cast<uint*>(&Bsm[buf][un1][kk2]) =
        (uint)f2bf(vlo1) | ((uint)f2bf(vhi1) << 16);
  };

  for (int tap = 0; tap < 9; ++tap) {
    if (tid < 32) {
      const int p = n0 + tid;
      if (p < N) {
        const uint4 pk = prep[((size_t)b * 9 + tap) * N + p];
        sq[tid] = (int)pk.x * C;
        swl[0][tid] = bf2f((ushort)(pk.y & 0xffff));
        swl[1][tid] = bf2f((ushort)(pk.y >> 16));
        swl[2][tid] = bf2f((ushort)(pk.z & 0xffff));
        swl[3][tid] = bf2f((ushort)(pk.z >> 16));
      } else {
        sq[tid] = 0;
        swl[0][tid] = swl[1][tid] = swl[2][tid] = swl[3][tid] = 0.f;
      }
    }
    __syncthreads();
    sqr0 = sq[un0];
    sqr1 = sq[un1];
#pragma unroll
    for (int q = 0; q < 4; q++) {
      w0a[q] = swl[q][un0];
      w1a[q] = swl[q][un1];
    }
    loadCorners(0);
    packB(0);
    loadCorners(64);  // corners for ks=1 in flight
    __syncthreads();  // Bsm[0] visible
#pragma unroll
    for (int ks = 0; ks < 4; ++ks) {
      // pack next step's B into idle buffer (safe: last read 2 barriers ago)
      if (ks < 3) packB((ks + 1) & 1);
      // issue corner loads for ks+2 (overlap with MFMA)
      if (ks < 2) loadCorners((ks + 2) * 64);
      // A fragments: direct global->register, fragment-major (L2-hot)
      bf16x8 afr[2][4];
      const int ktb = tap * 8 + ks * 2;
#pragma unroll
      for (int sub = 0; sub < 2; ++sub)
#pragma unroll
        for (int mf = 0; mf < 4; ++mf)
          afr[sub][mf] = *reinterpret_cast<const bf16x8*>(
              Awb + ((((size_t)(wr * 4 + mf) * 72) + ktb + sub) << 9) + lane * 8);
      __builtin_amdgcn_s_setprio(1);
#pragma unroll
      for (int sub = 0; sub < 2; ++sub) {
        const int koff = sub * 32 + (lane >> 4) * 8;
        const bf16x8 bfv =
            *reinterpret_cast<const bf16x8*>(&Bsm[ks & 1][wc * 16 + (lane & 15)][koff]);
#pragma unroll
        for (int mf = 0; mf < MF; mf++)
          acc[mf] = __builtin_amdgcn_mfma_f32_16x16x32_bf16(afr[sub][mf], bfv, acc[mf], 0, 0, 0);
      }
      __builtin_amdgcn_s_setprio(0);
      __syncthreads();
    }
  }
  const int gn = n0 + wc * 16 + (lane & 15);
#pragma unroll
  for (int mf = 0; mf < MF; mf++) {
    const int mbase = wr * 64 + mf * 16 + ((lane >> 4) * 4);
    if (gn < N) {
#pragma unroll
      for (int rr = 0; rr < 4; rr++)
        out[((size_t)b * C + mbase + rr) * N + gn] = acc[mf][rr] + bias[mbase + rr];
    }
  }
}

// ---------------------------------------------------------------------------
extern "C" void kernel_launch(void* const* d_in, const int* in_sizes, int n_in,
                              void* d_out, int out_size, void* d_ws, size_t ws_size,
                              hipStream_t stream) {
  const float* t_in = (const float*)d_in[0];
  const float* s_in = (const float*)d_in[1];
  const float* t_qw = (const float*)d_in[2];
  const float* t_qb = (const float*)d_in[3];
  const float* t_kw = (const float*)d_in[4];
  const float* t_kb = (const float*)d_in[5];
  const float* t_vw = (const float*)d_in[6];
  const float* t_vb = (const float*)d_in[7];
  const float* t_g = (const float*)d_in[8];
  const float* s_qw = (const float*)d_in[9];
  const float* s_qb = (const float*)d_in[10];
  const float* s_kw = (const float*)d_in[11];
  const float* s_kb = (const float*)d_in[12];
  const float* s_vw = (const float*)d_in[13];
  const float* s_vb = (const float*)d_in[14];
  const float* s_g = (const float*)d_in[15];
  const float* w_t_ch = (const float*)d_in[16];
  const float* w_s_ch = (const float*)d_in[17];
  const float* w_s2t = (const float*)d_in[18];
  const float* w_t2s = (const float*)d_in[19];
  const float* t_off_w = (const float*)d_in[20];
  const float* t_off_b = (const float*)d_in[21];
  const float* t_dcn_w = (const float*)d_in[22];
  const float* t_dcn_b = (const float*)d_in[23];
  const float* s_off_w = (const float*)d_in[24];
  const float* s_off_b = (const float*)d_in[25];
  const float* s_dcn_w = (const float*)d_in[26];
  const float* s_dcn_b = (const float*)d_in[27];
  (void)in_sizes; (void)n_in; (void)out_size; (void)ws_size;

  constexpr int Bn = 16, C = 256;
  constexpr int HT = 15, WT = 15, NT = HT * WT;    // 225
  constexpr int HS = 31, WS2 = 31, NS = HS * WS2;  // 961
  constexpr int NpT = 256, NpS = 992;
  constexpr int NRT = 256, NRS = 1024;

  float* ws = (float*)d_ws;
  size_t off = 0;
  auto alloc = [&](size_t n) {
    n = (n + 3) & ~(size_t)3;
    float* p = ws + off; off += n; return p;
  };
  auto allocU = [&](size_t nu) { return (ushort*)alloc((nu + 1) / 2); };

  float* qk_t = alloc((size_t)Bn * 64 * NT);
  float* qk_s = alloc((size_t)Bn * 64 * NS);
  float* qkw_t = alloc((size_t)64 * C + 64);
  float* qkw_s = alloc((size_t)64 * C + 64);
  float* qkb_t = qkw_t + (size_t)64 * C;
  float* qkb_s = qkw_s + (size_t)64 * C;
  ushort* xT_t = allocU((size_t)Bn * NRT * C);
  ushort* xT_s = allocU((size_t)Bn * NRS * C);
  ushort* xbf_t = allocU((size_t)Bn * C * NpT);
  ushort* xbf_s = allocU((size_t)Bn * C * NpS);
  ushort* Wv_t = allocU((size_t)C * C);
  ushort* Wv_s = allocU((size_t)C * C);
  ushort* v_tbf = allocU((size_t)Bn * C * NpT);
  ushort* v_sbf = allocU((size_t)Bn * C * NpS);
  ushort* S_t = allocU((size_t)Bn * NT * NpT);
  ushort* S_s = allocU((size_t)Bn * NS * NpS);
  ushort* xsT_t = allocU((size_t)Bn * NRT * C);
  ushort* xsT_s = allocU((size_t)Bn * NRS * C);
  float* Atc = alloc((size_t)Bn * C * C);
  float* Asc = alloc((size_t)Bn * C * C);
  ushort* Mc_t = allocU((size_t)Bn * C * C);
  ushort* Mc_s = allocU((size_t)Bn * C * C);
  float* om_t = alloc((size_t)Bn * 27 * NT);
  float* om_s = alloc((size_t)Bn * 27 * NS);
  ushort* owb_t = allocU((size_t)32 * 2304);
  ushort* owb_s = allocU((size_t)32 * 2304);
  ushort* Awb_t = allocU((size_t)256 * 2304);
  ushort* Awb_s = allocU((size_t)256 * 2304);
  uint4* prep_t = (uint4*)alloc((size_t)Bn * 9 * NT * 4);
  uint4* prep_s = (uint4*)alloc((size_t)Bn * 9 * NS * 4);

  dim3 blk(256);

  // 1. fused weight prep (DCN weights -> fragment-major)
  prep_weights_kernel<<<dim3((1491072 + 255) / 256), blk, 0, stream>>>(
      t_qw, t_qb, t_kw, t_kb, s_qw, s_qb, s_kw, s_kb, t_vw, s_vw,
      t_off_w, s_off_w, t_dcn_w, s_dcn_w,
      qkw_t, qkb_t, qkw_s, qkb_s, Wv_t, Wv_s, owb_t, owb_s, Awb_t, Awb_s);

  // 2. fused q|k projections
  conv1x1_fused_kernel<<<dim3(320), blk, 0, stream>>>(
      s_in, qkw_s, qkb_s, qk_s, NS, t_in, qkw_t, qkb_t, qk_t, NT);

  // 3-4. fused casts
  cast_transpose_fused_kernel<<<dim3(1280), blk, 0, stream>>>(
      s_in, xT_s, NS, NRS, t_in, xT_t, NT, NRT);
  cast_pad_fused_kernel<<<dim3((Bn * C * NpS + Bn * C * NpT + 255) / 256), blk, 0, stream>>>(
      s_in, xbf_s, NS, NpS, Bn * C * NpS, t_in, xbf_t, NT, NpT, Bn * C * NpT);

  // 5. fused v projection (EPI=0)
  gemm_fused_kernel<0><<<dim3(640), blk, 0, stream>>>(
      Wv_s, 0, xT_s, s_vb, v_sbf, nullptr, NS, NpS, NRS, C,
      Wv_t, 0, xT_t, t_vb, v_tbf, nullptr, NT, NpT, NRT, C,
      512, 16, 4);

  // 6. fused energy
  energy_fused_kernel<<<dim3(4352), blk, 0, stream>>>(
      qk_s, S_s, NS, NpS, qk_t, S_t, NT, NpT);

  // 7. fused spatial softmax
  softmax_bf16_fused_kernel<<<dim3(Bn * NS + Bn * NT), blk, 0, stream>>>(
      S_s, NS, NpS, S_t, NT, NpT, Bn * NS);

  // 8. fused gram (EPI=2)
  gemm_fused_kernel<2><<<dim3(256), blk, 0, stream>>>(
      xbf_s, 1, xbf_s, nullptr, nullptr, Asc, C, C, C, NpS,
      xbf_t, 1, xbf_t, nullptr, nullptr, Atc, C, C, C, NpT,
      128, 4, 4);

  // 9. fused channel softmax + mcomb
  softmax_mcomb_kernel<<<dim3(Bn * C), blk, 0, stream>>>(
      Atc, Asc, w_t_ch, w_s2t, w_s_ch, w_t2s, Mc_t, Mc_s);

  // 10. merged PV + chan GEMM -> xsT
  pv_chan_fused_kernel<<<dim3(640), blk, 0, stream>>>(
      v_sbf, S_s, Mc_s, xT_s, s_in, s_g, xsT_s, NS, NpS, NRS,
      v_tbf, S_t, Mc_t, xT_t, t_in, t_g, xsT_t, NT, NpT, NRT);

  // 11. fused offconv
  offconv_fused_kernel<<<dim3(320), blk, 0, stream>>>(
      xsT_s, owb_s, s_off_b, om_s, HS, WS2, NS, NRS,
      xsT_t, owb_t, t_off_b, om_t, HT, WT, NT, NRT);

  // 12. fused gather-table prep
  prep_offsets_fused_kernel<<<dim3((Bn * 9 * NS + Bn * 9 * NT + 255) / 256), blk, 0, stream>>>(
      om_s, prep_s, HS, WS2, Bn * 9 * NS, om_t, prep_t, HT, WT, Bn * 9 * NT);

  // 13. fused DCN (double-buffered B, single barrier/step, setprio)
  float* out_t = (float*)d_out;
  float* out_s = out_t + (size_t)Bn * C * NT;
  dcn_fused_kernel<<<dim3(640), dim3(512), 0, stream>>>(
      xsT_s, prep_s, Awb_s, s_dcn_b, out_s, NS, WS2, NRS,
      xsT_t, prep_t, Awb_t, t_dcn_b, out_t, NT, WT, NRT);
}

// Round 16
// 352.884 us; speedup vs baseline: 1.0175x; 1.0175x over previous
//
#include <hip/hip_runtime.h>
#include <hip/hip_bf16.h>
#include <cmath>

typedef __attribute__((ext_vector_type(8))) short bf16x8;
typedef __attribute__((ext_vector_type(4))) float f32x4;

__device__ inline ushort f2bf(float f) {
  __hip_bfloat16 h = __float2bfloat16(f);
  return *reinterpret_cast<ushort*>(&h);
}
__device__ inline float bf2f(ushort u) {
  return __uint_as_float((uint)u << 16);
}
__device__ inline float bflo(uint x) { return __uint_as_float(x << 16); }
__device__ inline float bfhi(uint x) { return __uint_as_float(x & 0xffff0000u); }

// Fused-side decode with XCD-aware bijective chunking.
__device__ inline bool fdecode(int totalS, int gxS, int gyS, int gxT, int gyT,
                               int& bx, int& by, int& bz, bool& isT) {
  const int total = gridDim.x;
  const int id = blockIdx.x;
  int wid = (id & 7) * (total >> 3) + (id >> 3);
  const int totalT = gxT * gyT * 16;
  if (wid >= totalS + totalT) return false;
  isT = wid >= totalS;
  int lid = isT ? wid - totalS : wid;
  const int gx = isT ? gxT : gxS;
  const int gy = isT ? gyT : gyS;
  bx = lid % gx;
  lid /= gx;
  by = lid % gy;
  bz = lid / gy;
  return true;
}

// ---------------------------------------------------------------------------
// fused weight prep. DCN weights FRAGMENT-MAJOR:
// frag (mt,kt) = 16 rows x 32 k; elem (lane, j): o = mt*16+(lane&15),
// k = kt*32+(lane>>4)*8+j. dst = ((mt*72+kt)<<9) + lane*8 + j.
// ---------------------------------------------------------------------------
__global__ __launch_bounds__(256) void prep_weights_kernel(
    const float* __restrict__ t_qw, const float* __restrict__ t_qb,
    const float* __restrict__ t_kw, const float* __restrict__ t_kb,
    const float* __restrict__ s_qw, const float* __restrict__ s_qb,
    const float* __restrict__ s_kw, const float* __restrict__ s_kb,
    const float* __restrict__ t_vw, const float* __restrict__ s_vw,
    const float* __restrict__ t_off_w, const float* __restrict__ s_off_w,
    const float* __restrict__ t_dcn_w, const float* __restrict__ s_dcn_w,
    float* __restrict__ qkw_t, float* __restrict__ qkb_t,
    float* __restrict__ qkw_s, float* __restrict__ qkb_s,
    ushort* __restrict__ Wv_t, ushort* __restrict__ Wv_s,
    ushort* __restrict__ owb_t, ushort* __restrict__ owb_s,
    ushort* __restrict__ Awb_t, ushort* __restrict__ Awb_s) {
  int i = blockIdx.x * 256 + threadIdx.x;
  if (i < 16448) {
    if (i < 8192) qkw_t[i] = t_qw[i];
    else if (i < 16384) qkw_t[i] = t_kw[i - 8192];
    else { int j = i - 16384; qkb_t[j] = (j < 32) ? t_qb[j] : t_kb[j - 32]; }
    return;
  }
  i -= 16448;
  if (i < 16448) {
    if (i < 8192) qkw_s[i] = s_qw[i];
    else if (i < 16384) qkw_s[i] = s_kw[i - 8192];
    else { int j = i - 16384; qkb_s[j] = (j < 32) ? s_qb[j] : s_kb[j - 32]; }
    return;
  }
  i -= 16448;
  if (i < 65536) { Wv_t[i] = f2bf(t_vw[i]); return; }
  i -= 65536;
  if (i < 65536) { Wv_s[i] = f2bf(s_vw[i]); return; }
  i -= 65536;
  if (i < 73728) {
    const int o = i / 2304, k = i % 2304, tap = k >> 8, c = k & 255;
    owb_t[i] = (o < 27) ? f2bf(t_off_w[(size_t)o * 2304 + c * 9 + tap]) : (ushort)0;
    return;
  }
  i -= 73728;
  if (i < 73728) {
    const int o = i / 2304, k = i % 2304, tap = k >> 8, c = k & 255;
    owb_s[i] = (o < 27) ? f2bf(s_off_w[(size_t)o * 2304 + c * 9 + tap]) : (ushort)0;
    return;
  }
  i -= 73728;
  if (i < 589824) {
    const int frag = i >> 9, within = i & 511;
    const int lane = within >> 3, j = within & 7;
    const int mt = frag / 72, kt = frag % 72;
    const int o = mt * 16 + (lane & 15);
    const int k = kt * 32 + (lane >> 4) * 8 + j;
    const int tap = k >> 8, c = k & 255;
    Awb_t[i] = f2bf(t_dcn_w[(size_t)o * 2304 + c * 9 + tap]);
    return;
  }
  i -= 589824;
  if (i < 589824) {
    const int frag = i >> 9, within = i & 511;
    const int lane = within >> 3, j = within & 7;
    const int mt = frag / 72, kt = frag % 72;
    const int o = mt * 16 + (lane & 15);
    const int k = kt * 32 + (lane >> 4) * 8 + j;
    const int tap = k >> 8, c = k & 255;
    Awb_s[i] = f2bf(s_dcn_w[(size_t)o * 2304 + c * 9 + tap]);
  }
}

// ---------------------------------------------------------------------------
// fused conv1x1 (fp32) q|k projection, OC=64
// ---------------------------------------------------------------------------
__global__ __launch_bounds__(256) void conv1x1_fused_kernel(
    const float* __restrict__ xS, const float* __restrict__ wS,
    const float* __restrict__ bS, float* __restrict__ oS, int NS_,
    const float* __restrict__ xT, const float* __restrict__ wT,
    const float* __restrict__ bT, float* __restrict__ oT, int NT_) {
  constexpr int C = 256, OC = 64;
  __shared__ float As[64][17];
  __shared__ float Bs[16][64];
  int bx, by, bz; bool isT;
  if (!fdecode(256, 16, 1, 4, 1, bx, by, bz, isT)) return;
  const float* x = isT ? xT : xS;
  const float* w = isT ? wT : wS;
  const float* bias = isT ? bT : bS;
  float* out = isT ? oT : oS;
  const int N = isT ? NT_ : NS_;
  const int b = bz;
  const int n0 = bx * 64;
  const float* xb = x + (size_t)b * C * N;
  const int tid = threadIdx.x;
  const int tr = tid >> 4, tc = tid & 15;
  float acc[4][4] = {};
  for (int k0 = 0; k0 < C; k0 += 16) {
    for (int i = tid; i < 64 * 16; i += 256) {
      int m = i >> 4, kk = i & 15;
      As[m][kk] = w[(size_t)m * C + k0 + kk];
    }
    for (int i = tid; i < 16 * 64; i += 256) {
      int kk = i >> 6, n = i & 63;
      int gn = n0 + n;
      Bs[kk][n] = (gn < N) ? xb[(size_t)(k0 + kk) * N + gn] : 0.f;
    }
    __syncthreads();
#pragma unroll
    for (int kk = 0; kk < 16; ++kk) {
      float a[4], bb[4];
#pragma unroll
      for (int i = 0; i < 4; i++) a[i] = As[tr * 4 + i][kk];
#pragma unroll
      for (int j = 0; j < 4; j++) bb[j] = Bs[kk][tc * 4 + j];
#pragma unroll
      for (int i = 0; i < 4; i++)
#pragma unroll
        for (int j = 0; j < 4; j++) acc[i][j] += a[i] * bb[j];
    }
    __syncthreads();
  }
  for (int i = 0; i < 4; i++) {
    int gm = tr * 4 + i;
    if (gm >= OC) continue;
    float bv = bias[gm];
    for (int j = 0; j < 4; j++) {
      int gn = n0 + tc * 4 + j;
      if (gn < N) out[((size_t)b * OC + gm) * N + gn] = acc[i][j] + bv;
    }
  }
}

// ---------------------------------------------------------------------------
// fused cast+transpose: x fp32 [C][N] -> xT bf16 [NR][C]
// ---------------------------------------------------------------------------
__global__ __launch_bounds__(256) void cast_transpose_fused_kernel(
    const float* __restrict__ xS, ushort* __restrict__ oS, int NS_, int NRS_,
    const float* __restrict__ xT, ushort* __restrict__ oT, int NT_, int NRT_) {
  constexpr int C = 256;
  __shared__ float T[64][65];
  int bx, by, bz; bool isT;
  if (!fdecode(1024, 16, 4, 4, 4, bx, by, bz, isT)) return;
  const float* x = isT ? xT : xS;
  ushort* xTo = isT ? oT : oS;
  const int N = isT ? NT_ : NS_;
  const int NR = isT ? NRT_ : NRS_;
  const int b = bz;
  const int n0 = bx * 64, c0 = by * 64;
  const float* xb = x + (size_t)b * C * N;
  const int tid = threadIdx.x;
  for (int u = tid; u < 4096; u += 256) {
    const int cc = u >> 6, nn = u & 63;
    const int gn = n0 + nn;
    T[cc][nn] = (gn < N) ? xb[(size_t)(c0 + cc) * N + gn] : 0.f;
  }
  __syncthreads();
  ushort* ob = xTo + (size_t)b * NR * C;
  for (int u = tid; u < 4096; u += 256) {
    const int nn = u >> 6, cc = u & 63;
    ob[(size_t)(n0 + nn) * C + c0 + cc] = f2bf(T[cc][nn]);
  }
}

// ---------------------------------------------------------------------------
// fused cast+pad
// ---------------------------------------------------------------------------
__global__ __launch_bounds__(256) void cast_pad_fused_kernel(
    const float* __restrict__ xS, ushort* __restrict__ oS, int NS_, int NpS_,
    int totS,
    const float* __restrict__ xT, ushort* __restrict__ oT, int NT_, int NpT_,
    int totT) {
  constexpr int C = 256;
  int i = blockIdx.x * 256 + threadIdx.x;
  if (i < totS) {
    const int np = i % NpS_;
    const int c = (i / NpS_) % C;
    const int b = i / (NpS_ * C);
    oS[i] = (np < NS_) ? f2bf(xS[((size_t)b * C + c) * NS_ + np]) : (ushort)0;
    return;
  }
  i -= totS;
  if (i < totT) {
    const int np = i % NpT_;
    const int c = (i / NpT_) % C;
    const int b = i / (NpT_ * C);
    oT[i] = (np < NT_) ? f2bf(xT[((size_t)b * C + c) * NT_ + np]) : (ushort)0;
  }
}

// ---------------------------------------------------------------------------
// fused channel softmax + mcomb
// ---------------------------------------------------------------------------
__global__ __launch_bounds__(256) void softmax_mcomb_kernel(
    const float* __restrict__ Atc, const float* __restrict__ Asc,
    const float* __restrict__ w_t_ch, const float* __restrict__ w_s2t,
    const float* __restrict__ w_s_ch, const float* __restrict__ w_t2s,
    ushort* __restrict__ Mc_t, ushort* __restrict__ Mc_s) {
  const int row = blockIdx.x;
  const int tid = threadIdx.x;
  __shared__ float red[8];
  const size_t idx = (size_t)row * 256 + tid;
  const float a = -Atc[idx];
  const float s = -Asc[idx];
  float ma = a, ms = s;
#pragma unroll
  for (int off = 32; off; off >>= 1) {
    ma = fmaxf(ma, __shfl_xor(ma, off, 64));
    ms = fmaxf(ms, __shfl_xor(ms, off, 64));
  }
  if ((tid & 63) == 0) { red[tid >> 6] = ma; red[4 + (tid >> 6)] = ms; }
  __syncthreads();
  if (tid == 0) {
    float m1 = red[0], m2 = red[4];
    for (int i = 1; i < 4; i++) { m1 = fmaxf(m1, red[i]); m2 = fmaxf(m2, red[4 + i]); }
    red[0] = m1; red[4] = m2;
  }
  __syncthreads();
  ma = red[0]; ms = red[4];
  __syncthreads();
  const float ea = __expf(a - ma), es = __expf(s - ms);
  float sa = ea, ss = es;
#pragma unroll
  for (int off = 32; off; off >>= 1) {
    sa += __shfl_xor(sa, off, 64);
    ss += __shfl_xor(ss, off, 64);
  }
  if ((tid & 63) == 0) { red[tid >> 6] = sa; red[4 + (tid >> 6)] = ss; }
  __syncthreads();
  if (tid == 0) {
    float t1 = 0.f, t2 = 0.f;
    for (int i = 0; i < 4; i++) { t1 += red[i]; t2 += red[4 + i]; }
    red[0] = t1; red[4] = t2;
  }
  __syncthreads();
  const float Pa = ea / red[0], Ps = es / red[4];
  Mc_t[idx] = f2bf(w_t_ch[0] * Pa + w_s2t[0] * Ps);
  Mc_s[idx] = f2bf(w_s_ch[0] * Ps + w_t2s[0] * Pa);
}

// ---------------------------------------------------------------------------
// fused generic bf16 GEMM, BM=128, NW=4.
// EPI 0: outBf = bf16(acc+bias) padded   EPI 2: outF = acc
// ---------------------------------------------------------------------------
template <int EPI>
__global__ __launch_bounds__(256) void gemm_fused_kernel(
    const ushort* __restrict__ AS, int aPerB_S, const ushort* __restrict__ BtS,
    const float* __restrict__ biasS, ushort* __restrict__ outBfS,
    float* __restrict__ outFS, int NS_, int NpS_, int NRS_, int KpS_,
    const ushort* __restrict__ AT, int aPerB_T, const ushort* __restrict__ BtT,
    const float* __restrict__ biasT, ushort* __restrict__ outBfT,
    float* __restrict__ outFT, int NT_, int NpT_, int NRT_, int KpT_,
    int totalS, int gxS, int gxT) {
  constexpr int CM = 256, BM = 128, NW = 4, NF = 2, WN = 2;
  __shared__ ushort Asm[BM][40];
  __shared__ ushort Bsm[64][40];
  int bx, by, bz; bool isT;
  if (!fdecode(totalS, gxS, 2, gxT, 2, bx, by, bz, isT)) return;
  const ushort* A = isT ? AT : AS;
  const ushort* Bt = isT ? BtT : BtS;
  const float* bias = isT ? biasT : biasS;
  ushort* outBf = isT ? outBfT : outBfS;
  float* outF = isT ? outFT : outFS;
  const int aPerBatch = isT ? aPerB_T : aPerB_S;
  const int N = isT ? NT_ : NS_, Np = isT ? NpT_ : NpS_;
  const int NR = isT ? NRT_ : NRS_, Kp = isT ? KpT_ : KpS_;
  const int n0 = bx * 64, m0 = by * BM, b = bz;
  const ushort* Ab = A + (size_t)(aPerBatch ? b : 0) * CM * Kp;
  const ushort* Bb = Bt + (size_t)b * NR * Kp;
  const int tid = threadIdx.x, lane = tid & 63, w = tid >> 6;
  const int wr = w / WN, wc = w % WN;
  f32x4 acc[4][NF];
#pragma unroll
  for (int i = 0; i < 4; i++)
#pragma unroll
    for (int j = 0; j < NF; j++) acc[i][j] = (f32x4){0.f, 0.f, 0.f, 0.f};
  for (int k0 = 0; k0 < Kp; k0 += 32) {
    for (int u = tid; u < BM * 4; u += NW * 64) {
      const int row = u >> 2, seg = u & 3;
      *reinterpret_cast<uint4*>(&Asm[row][seg * 8]) =
          *reinterpret_cast<const uint4*>(&Ab[(size_t)(m0 + row) * Kp + k0 + seg * 8]);
    }
    for (int u = tid; u < 64 * 4; u += NW * 64) {
      const int row = u >> 2, seg = u & 3;
      *reinterpret_cast<uint4*>(&Bsm[row][seg * 8]) =
          *reinterpret_cast<const uint4*>(&Bb[(size_t)(n0 + row) * Kp + k0 + seg * 8]);
    }
    __syncthreads();
    const int koff = (lane >> 4) * 8;
    bf16x8 af[4], bfr[NF];
#pragma unroll
    for (int mf = 0; mf < 4; mf++)
      af[mf] = *reinterpret_cast<const bf16x8*>(&Asm[wr * 64 + mf * 16 + (lane & 15)][koff]);
#pragma unroll
    for (int nf = 0; nf < NF; nf++)
      bfr[nf] = *reinterpret_cast<const bf16x8*>(&Bsm[wc * NF * 16 + nf * 16 + (lane & 15)][koff]);
#pragma unroll
    for (int mf = 0; mf < 4; mf++)
#pragma unroll
      for (int nf = 0; nf < NF; nf++)
        acc[mf][nf] = __builtin_amdgcn_mfma_f32_16x16x32_bf16(af[mf], bfr[nf], acc[mf][nf], 0, 0, 0);
    __syncthreads();
  }
#pragma unroll
  for (int mf = 0; mf < 4; mf++) {
    const int mbase = m0 + wr * 64 + mf * 16 + ((lane >> 4) * 4);
#pragma unroll
    for (int nf = 0; nf < NF; nf++) {
      const int gn = n0 + wc * NF * 16 + nf * 16 + (lane & 15);
      if (EPI == 0) {
#pragma unroll
        for (int rr = 0; rr < 4; rr++) {
          const int m = mbase + rr;
          if (gn < Np) {
            ushort v = (gn < N) ? f2bf(acc[mf][nf][rr] + bias[m]) : (ushort)0;
            outBf[((size_t)b * CM + m) * Np + gn] = v;
          }
        }
      } else {
#pragma unroll
        for (int rr = 0; rr < 4; rr++) {
          if (gn < N)
            outF[((size_t)b * CM + mbase + rr) * N + gn] = acc[mf][nf][rr];
        }
      }
    }
  }
  (void)NR;
}

// ---------------------------------------------------------------------------
// fused energy (K=32)
// ---------------------------------------------------------------------------
__global__ __launch_bounds__(256) void energy_fused_kernel(
    const float* __restrict__ qkS, ushort* __restrict__ SS, int NS_, int NpS_,
    const float* __restrict__ qkT, ushort* __restrict__ ST, int NT_, int NpT_) {
  __shared__ ushort Aq[64][40];
  __shared__ ushort Bk[64][40];
  int bx, by, bz; bool isT;
  if (!fdecode(4096, 16, 16, 4, 4, bx, by, bz, isT)) return;
  const float* qk = isT ? qkT : qkS;
  ushort* Sbf = isT ? ST : SS;
  const int N = isT ? NT_ : NS_, Np = isT ? NpT_ : NpS_;
  const int m0 = bx * 64, n0 = by * 64, b = bz;
  const float* qb = qk + (size_t)b * 64 * N;
  const float* kb = qb + (size_t)32 * N;
  const int tid = threadIdx.x, lane = tid & 63, w = tid >> 6;
  for (int u = tid; u < 2048; u += 256) {
    const int c = u >> 6, nn = u & 63;
    const int gn = n0 + nn, gm = m0 + nn;
    Aq[nn][c] = (gn < N) ? f2bf(qb[(size_t)c * N + gn]) : (ushort)0;
    Bk[nn][c] = (gm < N) ? f2bf(kb[(size_t)c * N + gm]) : (ushort)0;
  }
  __syncthreads();
  const int koff = (lane >> 4) * 8;
  const bf16x8 af = *reinterpret_cast<const bf16x8*>(&Aq[w * 16 + (lane & 15)][koff]);
  f32x4 acc[4];
#pragma unroll
  for (int j = 0; j < 4; j++) {
    const bf16x8 bf = *reinterpret_cast<const bf16x8*>(&Bk[j * 16 + (lane & 15)][koff]);
    acc[j] = __builtin_amdgcn_mfma_f32_16x16x32_bf16(af, bf, (f32x4){0.f, 0.f, 0.f, 0.f}, 0, 0, 0);
  }
#pragma unroll
  for (int j = 0; j < 4; j++) {
    const int m = m0 + j * 16 + (lane & 15);
    if (m >= Np) continue;
#pragma unroll
    for (int r = 0; r < 4; r++) {
      const int n = n0 + w * 16 + (lane >> 4) * 4 + r;
      if (n < N) Sbf[((size_t)b * N + n) * Np + m] = (m < N) ? f2bf(acc[j][r]) : (ushort)0;
    }
  }
}

// ---------------------------------------------------------------------------
// fused bf16 row softmax (spatial scores)
// ---------------------------------------------------------------------------
__global__ __launch_bounds__(256) void softmax_bf16_fused_kernel(
    ushort* __restrict__ Ss, int Ns, int Nps, ushort* __restrict__ St, int Nt,
    int Npt, int rowsS) {
  __shared__ float buf[992];
  __shared__ float red[4];
  const int row = blockIdx.x;
  ushort* r;
  int N;
  if (row < rowsS) {
    r = Ss + (size_t)row * Nps;
    N = Ns;
  } else {
    r = St + (size_t)(row - rowsS) * Npt;
    N = Nt;
  }
  const int tid = threadIdx.x;
  float mx = -1e30f;
  for (int i = tid; i < N; i += 256) {
    float f = bf2f(r[i]);
    buf[i] = f;
    mx = fmaxf(mx, f);
  }
#pragma unroll
  for (int off = 32; off; off >>= 1) mx = fmaxf(mx, __shfl_xor(mx, off, 64));
  if ((tid & 63) == 0) red[tid >> 6] = mx;
  __syncthreads();
  if (tid == 0) {
    float m2 = red[0];
    for (int i = 1; i < 4; i++) m2 = fmaxf(m2, red[i]);
    red[0] = m2;
  }
  __syncthreads();
  mx = red[0];
  __syncthreads();
  float s = 0.f;
  for (int i = tid; i < N; i += 256) {
    float v = __expf(buf[i] - mx);
    buf[i] = v;
    s += v;
  }
#pragma unroll
  for (int off = 32; off; off >>= 1) s += __shfl_xor(s, off, 64);
  if ((tid & 63) == 0) red[tid >> 6] = s;
  __syncthreads();
  if (tid == 0) {
    float t = 0.f;
    for (int i = 0; i < 4; i++) t += red[i];
    red[0] = t;
  }
  __syncthreads();
  const float inv = 1.f / red[0];
  for (int i = tid; i < N; i += 256) r[i] = f2bf(buf[i] * inv);
}

// ---------------------------------------------------------------------------
// fused PV+CHAN merged GEMM (BM=128): acc = PV(v@S^T); acc *= g;
// acc += Mc@xT; out_xsT = bf16(x + acc).
// ---------------------------------------------------------------------------
__global__ __launch_bounds__(256) void pv_chan_fused_kernel(
    const ushort* __restrict__ vS, const ushort* __restrict__ SS,
    const ushort* __restrict__ McS, const ushort* __restrict__ xTS,
    const float* __restrict__ xS, const float* __restrict__ gS,
    ushort* __restrict__ xsTS, int NS_, int NpS_, int NRS_,
    const ushort* __restrict__ vT, const ushort* __restrict__ ST,
    const ushort* __restrict__ McT, const ushort* __restrict__ xTT,
    const float* __restrict__ xT_, const float* __restrict__ gT,
    ushort* __restrict__ xsTT, int NT_, int NpT_, int NRT_) {
  constexpr int C = 256, BM = 128, NW = 4, NF = 2, WN = 2;
  __shared__ ushort Asm[BM][40];
  __shared__ ushort Bsm[64][40];
  int bx, by, bz; bool isT;
  if (!fdecode(512, 16, 2, 4, 2, bx, by, bz, isT)) return;
  const ushort* vbf = isT ? vT : vS;
  const ushort* Sbf = isT ? ST : SS;
  const ushort* Mc = isT ? McT : McS;
  const ushort* xTb = isT ? xTT : xTS;
  const float* x = isT ? xT_ : xS;
  const float* gp = isT ? gT : gS;
  ushort* xsT = isT ? xsTT : xsTS;
  const int N = isT ? NT_ : NS_, Np = isT ? NpT_ : NpS_;
  const int NR = isT ? NRT_ : NRS_;
  const int n0 = bx * 64, m0 = by * BM, b = bz;
  const int tid = threadIdx.x, lane = tid & 63, w = tid >> 6;
  const int wr = w / WN, wc = w % WN;
  f32x4 acc[4][NF];
#pragma unroll
  for (int i = 0; i < 4; i++)
#pragma unroll
    for (int j = 0; j < NF; j++) acc[i][j] = (f32x4){0.f, 0.f, 0.f, 0.f};
  const int koff = (lane >> 4) * 8;
  // phase 1: PV, K = Np
  {
    const ushort* Ab = vbf + (size_t)b * C * Np;
    const ushort* Bb = Sbf + (size_t)b * (size_t)N * Np;
    for (int k0 = 0; k0 < Np; k0 += 32) {
      for (int u = tid; u < BM * 4; u += NW * 64) {
        const int row = u >> 2, seg = u & 3;
        *reinterpret_cast<uint4*>(&Asm[row][seg * 8]) =
            *reinterpret_cast<const uint4*>(&Ab[(size_t)(m0 + row) * Np + k0 + seg * 8]);
      }
      for (int u = tid; u < 64 * 4; u += NW * 64) {
        const int row = u >> 2, seg = u & 3;
        const int gn = n0 + row;
        uint4 val;
        if (gn < N)
          val = *reinterpret_cast<const uint4*>(&Bb[(size_t)gn * Np + k0 + seg * 8]);
        else
          val = make_uint4(0, 0, 0, 0);
        *reinterpret_cast<uint4*>(&Bsm[row][seg * 8]) = val;
      }
      __syncthreads();
      bf16x8 af[4], bfr[NF];
#pragma unroll
      for (int mf = 0; mf < 4; mf++)
        af[mf] = *reinterpret_cast<const bf16x8*>(&Asm[wr * 64 + mf * 16 + (lane & 15)][koff]);
#pragma unroll
      for (int nf = 0; nf < NF; nf++)
        bfr[nf] = *reinterpret_cast<const bf16x8*>(&Bsm[wc * NF * 16 + nf * 16 + (lane & 15)][koff]);
#pragma unroll
      for (int mf = 0; mf < 4; mf++)
#pragma unroll
        for (int nf = 0; nf < NF; nf++)
          acc[mf][nf] = __builtin_amdgcn_mfma_f32_16x16x32_bf16(af[mf], bfr[nf], acc[mf][nf], 0, 0, 0);
      __syncthreads();
    }
  }
  const float g = *gp;
#pragma unroll
  for (int mf = 0; mf < 4; mf++)
#pragma unroll
    for (int nf = 0; nf < NF; nf++)
#pragma unroll
      for (int rr = 0; rr < 4; rr++) acc[mf][nf][rr] *= g;
  // phase 2: chan, K = C
  {
    const ushort* Ab = Mc + (size_t)b * C * C;
    const ushort* Bb = xTb + (size_t)b * NR * C;
    for (int k0 = 0; k0 < C; k0 += 32) {
      for (int u = tid; u < BM * 4; u += NW * 64) {
        const int row = u >> 2, seg = u & 3;
        *reinterpret_cast<uint4*>(&Asm[row][seg * 8]) =
            *reinterpret_cast<const uint4*>(&Ab[(size_t)(m0 + row) * C + k0 + seg * 8]);
      }
      for (int u = tid; u < 64 * 4; u += NW * 64) {
        const int row = u >> 2, seg = u & 3;
        *reinterpret_cast<uint4*>(&Bsm[row][seg * 8]) =
            *reinterpret_cast<const uint4*>(&Bb[(size_t)(n0 + row) * C + k0 + seg * 8]);
      }
      __syncthreads();
      bf16x8 af[4], bfr[NF];
#pragma unroll
      for (int mf = 0; mf < 4; mf++)
        af[mf] = *reinterpret_cast<const bf16x8*>(&Asm[wr * 64 + mf * 16 + (lane & 15)][koff]);
#pragma unroll
      for (int nf = 0; nf < NF; nf++)
        bfr[nf] = *reinterpret_cast<const bf16x8*>(&Bsm[wc * NF * 16 + nf * 16 + (lane & 15)][koff]);
#pragma unroll
      for (int mf = 0; mf < 4; mf++)
#pragma unroll
        for (int nf = 0; nf < NF; nf++)
          acc[mf][nf] = __builtin_amdgcn_mfma_f32_16x16x32_bf16(af[mf], bfr[nf], acc[mf][nf], 0, 0, 0);
      __syncthreads();
    }
  }
#pragma unroll
  for (int mf = 0; mf < 4; mf++) {
    const int mbase = m0 + wr * 64 + mf * 16 + ((lane >> 4) * 4);
#pragma unroll
    for (int nf = 0; nf < NF; nf++) {
      const int gn = n0 + wc * NF * 16 + nf * 16 + (lane & 15);
      if (gn < N) {
        float s[4];
#pragma unroll
        for (int rr = 0; rr < 4; rr++)
          s[rr] = x[((size_t)b * C + mbase + rr) * N + gn] + acc[mf][nf][rr];
        uint lo = (uint)f2bf(s[0]) | ((uint)f2bf(s[1]) << 16);
        uint hi = (uint)f2bf(s[2]) | ((uint)f2bf(s[3]) << 16);
        *reinterpret_cast<uint2*>(&xsT[((size_t)b * NR + gn) * C + mbase]) =
            make_uint2(lo, hi);
      }
    }
  }
}

// ---------------------------------------------------------------------------
// fused offconv via MFMA on xsT. BK=128.
// ---------------------------------------------------------------------------
__global__ __launch_bounds__(256) void offconv_fused_kernel(
    const ushort* __restrict__ xS, const ushort* __restrict__ owS,
    const float* __restrict__ obS, float* __restrict__ omS, int HS_, int WS_,
    int NS_, int NRS_,
    const ushort* __restrict__ xT, const ushort* __restrict__ owT,
    const float* __restrict__ obT, float* __restrict__ omT, int HT_, int WT_,
    int NT_, int NRT_) {
  __shared__ ushort Asm[32][136];
  __shared__ ushort Bsm[64][136];
  __shared__ int qsrc[64];
  int bx, by, bz; bool isT;
  if (!fdecode(256, 16, 1, 4, 1, bx, by, bz, isT)) return;
  const ushort* xsT = isT ? xT : xS;
  const ushort* owb = isT ? owT : owS;
  const float* ob = isT ? obT : obS;
  float* om = isT ? omT : omS;
  const int H = isT ? HT_ : HS_, Wd = isT ? WT_ : WS_;
  const int N = isT ? NT_ : NS_, NR = isT ? NRT_ : NRS_;
  const int n0 = bx * 64, b = bz;
  const int tid = threadIdx.x, lane = tid & 63, w = tid >> 6;
  const ushort* xb = xsT + (size_t)b * NR * 256;
  f32x4 acc[2];
  acc[0] = (f32x4){0.f, 0.f, 0.f, 0.f};
  acc[1] = (f32x4){0.f, 0.f, 0.f, 0.f};
  for (int tap = 0; tap < 9; ++tap) {
    const int dy = tap / 3 - 1, dx = tap - (tap / 3) * 3 - 1;
    if (tid < 64) {
      const int p = n0 + tid;
      int q = -1;
      if (p < N) {
        const int h = p / Wd, ww = p - (p / Wd) * Wd;
        const int yy = h + dy, xx = ww + dx;
        if (yy >= 0 && yy < H && xx >= 0 && xx < Wd) q = yy * Wd + xx;
      }
      qsrc[tid] = q;
    }
    __syncthreads();
#pragma unroll
    for (int half = 0; half < 2; ++half) {
      const int k0 = tap * 256 + half * 128;
      for (int u = tid; u < 512; u += 256) {
        const int row = u >> 4, seg = u & 15;
        *reinterpret_cast<uint4*>(&Asm[row][seg * 8]) =
            *reinterpret_cast<const uint4*>(&owb[(size_t)row * 2304 + k0 + seg * 8]);
      }
      for (int u = tid; u < 1024; u += 256) {
        const int row = u >> 4, seg = u & 15;
        const int q = qsrc[row];
        uint4 val = make_uint4(0, 0, 0, 0);
        if (q >= 0)
          val = *reinterpret_cast<const uint4*>(&xb[(size_t)q * 256 + half * 128 + seg * 8]);
        *reinterpret_cast<uint4*>(&Bsm[row][seg * 8]) = val;
      }
      __syncthreads();
#pragma unroll
      for (int sub = 0; sub < 4; ++sub) {
        const int koff = sub * 32 + (lane >> 4) * 8;
        const bf16x8 b0 = *reinterpret_cast<const bf16x8*>(&Bsm[w * 16 + (lane & 15)][koff]);
#pragma unroll
        for (int mf = 0; mf < 2; ++mf) {
          const bf16x8 a0 = *reinterpret_cast<const bf16x8*>(&Asm[mf * 16 + (lane & 15)][koff]);
          acc[mf] = __builtin_amdgcn_mfma_f32_16x16x32_bf16(a0, b0, acc[mf], 0, 0, 0);
        }
      }
      __syncthreads();
    }
  }
#pragma unroll
  for (int mf = 0; mf < 2; ++mf) {
#pragma unroll
    for (int r = 0; r < 4; ++r) {
      const int o = mf * 16 + (lane >> 4) * 4 + r;
      const int n = n0 + w * 16 + (lane & 15);
      if (o < 27 && n < N)
        om[((size_t)b * 27 + o) * N + n] = acc[mf][r] + ob[o];
    }
  }
}

// ---------------------------------------------------------------------------
// fused bilinear gather table prep
// ---------------------------------------------------------------------------
__device__ inline void prep_one(const float* omb, uint4* prep, int i, int p,
                                int k, int H, int Wd, int N) {
  const float offy = omb[(size_t)k * N + p];
  const float offx = omb[(size_t)(9 + k) * N + p];
  const float mraw = omb[(size_t)(18 + k) * N + p];
  const float mval = 1.f / (1.f + __expf(-mraw));
  const int ky = k / 3, kx = k - (k / 3) * 3;
  const int h = p / Wd, w = p - (p / Wd) * Wd;
  const float py = offy + (float)(h + ky - 1);
  const float px = offx + (float)(w + kx - 1);
  const float y0f = floorf(py), x0f = floorf(px);
  const float wy = py - y0f, wx = px - x0f;
  const int y0 = (int)y0f, x0 = (int)x0f;
  const int ys0 = min(max(y0, 0), H - 2);
  const int xs0 = min(max(x0, 0), Wd - 2);
  const float wr0 = (ys0 == y0) ? (1.f - wy) : ((ys0 == y0 + 1) ? wy : 0.f);
  const float wr1 = (ys0 + 1 == y0) ? (1.f - wy) : ((ys0 + 1 == y0 + 1) ? wy : 0.f);
  const float wc0 = (xs0 == x0) ? (1.f - wx) : ((xs0 == x0 + 1) ? wx : 0.f);
  const float wc1 = (xs0 + 1 == x0) ? (1.f - wx) : ((xs0 + 1 == x0 + 1) ? wx : 0.f);
  const float w00 = wr0 * wc0 * mval, w01 = wr0 * wc1 * mval;
  const float w10 = wr1 * wc0 * mval, w11 = wr1 * wc1 * mval;
  uint4 pk;
  pk.x = (uint)(ys0 * Wd + xs0);
  pk.y = (uint)f2bf(w00) | ((uint)f2bf(w01) << 16);
  pk.z = (uint)f2bf(w10) | ((uint)f2bf(w11) << 16);
  pk.w = 0;
  prep[i] = pk;
}

__global__ __launch_bounds__(256) void prep_offsets_fused_kernel(
    const float* __restrict__ omS, uint4* __restrict__ prepS, int HS_, int WS_,
    int totS,
    const float* __restrict__ omT, uint4* __restrict__ prepT, int HT_, int WT_,
    int totT) {
  int i = blockIdx.x * 256 + threadIdx.x;
  if (i < totS) {
    const int N = HS_ * WS_;
    const int p = i % N, k = (i / N) % 9, b = i / (9 * N);
    prep_one(omS + (size_t)b * 27 * N, prepS, i, p, k, HS_, WS_, N);
    return;
  }
  i -= totS;
  if (i < totT) {
    const int N = HT_ * WT_;
    const int p = i % N, k = (i / N) % 9, b = i / (9 * N);
    prep_one(omT + (size_t)b * 27 * N, prepT, i, p, k, HT_, WT_, N);
  }
}

// ---------------------------------------------------------------------------
// fused DCN via MFMA (r16 = r14 best config: fragment-major register A, no
// LDS for A; single Bsm buffer; B-corner register prefetch; 2 barriers/step).
// BM=256, BK=64, BN=32, 512 thr. s gx=32, t gx=8; gy=1.
// ---------------------------------------------------------------------------
__global__ __launch_bounds__(512) void dcn_fused_kernel(
    const ushort* __restrict__ xS, const uint4* __restrict__ prS,
    const ushort* __restrict__ AwS, const float* __restrict__ biS,
    float* __restrict__ oS, int NS_, int WS_, int NRS_,
    const ushort* __restrict__ xT, const uint4* __restrict__ prT,
    const ushort* __restrict__ AwT, const float* __restrict__ biT,
    float* __restrict__ oT, int NT_, int WT_, int NRT_) {
  constexpr int C = 256, MF = 4;
  __shared__ ushort Bsm[32][72];
  __shared__ int sq[32];
  __shared__ float swl[4][32];
  int bx, by, bz; bool isT;
  if (!fdecode(512, 32, 1, 8, 1, bx, by, bz, isT)) return;
  const ushort* xsT = isT ? xT : xS;
  const uint4* prep = isT ? prT : prS;
  const ushort* Awb = isT ? AwT : AwS;
  const float* bias = isT ? biT : biS;
  float* out = isT ? oT : oS;
  const int N = isT ? NT_ : NS_, Wd = isT ? WT_ : WS_, NR = isT ? NRT_ : NRS_;
  const int n0 = bx * 32, b = bz;
  const int tid = threadIdx.x, lane = tid & 63, w = tid >> 6;
  const int wr = w >> 1, wc = w & 1;
  const ushort* xb = xsT + (size_t)b * NR * C;
  const int un0 = tid >> 5;
  const int un1 = un0 + 16;
  const int kk2 = (tid & 31) * 2;
  f32x4 acc[MF];
#pragma unroll
  for (int i = 0; i < MF; i++) acc[i] = (f32x4){0.f, 0.f, 0.f, 0.f};
  uint bReg[2][4];
  int sqr0 = 0, sqr1 = 0;
  float w0a[4], w1a[4];
  const size_t rowYp = (size_t)Wd * C;
  for (int tap = 0; tap < 9; ++tap) {
    if (tid < 32) {
      const int p = n0 + tid;
      if (p < N) {
        const uint4 pk = prep[((size_t)b * 9 + tap) * N + p];
        sq[tid] = (int)pk.x * C;
        swl[0][tid] = bf2f((ushort)(pk.y & 0xffff));
        swl[1][tid] = bf2f((ushort)(pk.y >> 16));
        swl[2][tid] = bf2f((ushort)(pk.z & 0xffff));
        swl[3][tid] = bf2f((ushort)(pk.z >> 16));
      } else {
        sq[tid] = 0;
        swl[0][tid] = swl[1][tid] = swl[2][tid] = swl[3][tid] = 0.f;
      }
    }
    __syncthreads();
    sqr0 = sq[un0];
    sqr1 = sq[un1];
#pragma unroll
    for (int q = 0; q < 4; q++) {
      w0a[q] = swl[q][un0];
      w1a[q] = swl[q][un1];
    }
    // prefetch B corners for ks=0
    {
      const ushort* pA = xb + sqr0 + kk2;
      bReg[0][0] = *reinterpret_cast<const uint*>(pA);
      bReg[0][1] = *reinterpret_cast<const uint*>(pA + C);
      bReg[0][2] = *reinterpret_cast<const uint*>(pA + rowYp);
      bReg[0][3] = *reinterpret_cast<const uint*>(pA + rowYp + C);
      const ushort* pB = xb + sqr1 + kk2;
      bReg[1][0] = *reinterpret_cast<const uint*>(pB);
      bReg[1][1] = *reinterpret_cast<const uint*>(pB + C);
      bReg[1][2] = *reinterpret_cast<const uint*>(pB + rowYp);
      bReg[1][3] = *reinterpret_cast<const uint*>(pB + rowYp + C);
    }
#pragma unroll
    for (int ks = 0; ks < 4; ++ks) {
      // A fragments for this step: direct global->register, fragment-major
      bf16x8 afr[2][4];
      const int ktb = tap * 8 + ks * 2;
#pragma unroll
      for (int sub = 0; sub < 2; ++sub)
#pragma unroll
        for (int mf = 0; mf < 4; ++mf)
          afr[sub][mf] = *reinterpret_cast<const bf16x8*>(
              Awb + ((((size_t)(wr * 4 + mf) * 72) + ktb + sub) << 9) + lane * 8);
      // B-stage: pack prefetched corners to LDS
      {
        const float vlo0 = w0a[0] * bflo(bReg[0][0]) + w0a[1] * bflo(bReg[0][1]) +
                           w0a[2] * bflo(bReg[0][2]) + w0a[3] * bflo(bReg[0][3]);
        const float vhi0 = w0a[0] * bfhi(bReg[0][0]) + w0a[1] * bfhi(bReg[0][1]) +
                           w0a[2] * bfhi(bReg[0][2]) + w0a[3] * bfhi(bReg[0][3]);
        *reinterpret_cast<uint*>(&Bsm[un0][kk2]) =
            (uint)f2bf(vlo0) | ((uint)f2bf(vhi0) << 16);
        const float vlo1 = w1a[0] * bflo(bReg[1][0]) + w1a[1] * bflo(bReg[1][1]) +
                           w1a[2] * bflo(bReg[1][2]) + w1a[3] * bflo(bReg[1][3]);
        const float vhi1 = w1a[0] * bfhi(bReg[1][0]) + w1a[1] * bfhi(bReg[1][1]) +
                           w1a[2] * bfhi(bReg[1][2]) + w1a[3] * bfhi(bReg[1][3]);
        *reinterpret_cast<uint*>(&Bsm[un1][kk2]) =
            (uint)f2bf(vlo1) | ((uint)f2bf(vhi1) << 16);
      }
      __syncthreads();
      // prefetch next ks B corners (overlaps MFMA)
      if (ks < 3) {
        const int c1 = (ks + 1) * 64;
        const ushort* pA = xb + sqr0 + c1 + kk2;
        bReg[0][0] = *reinterpret_cast<const uint*>(pA);
        bReg[0][1] = *reinterpret_cast<const uint*>(pA + C);
        bReg[0][2] = *reinterpret_cast<const uint*>(pA + rowYp);
        bReg[0][3] = *reinterpret_cast<const uint*>(pA + rowYp + C);
        const ushort* pB = xb + sqr1 + c1 + kk2;
        bReg[1][0] = *reinterpret_cast<const uint*>(pB);
        bReg[1][1] = *reinterpret_cast<const uint*>(pB + C);
        bReg[1][2] = *reinterpret_cast<const uint*>(pB + rowYp);
        bReg[1][3] = *reinterpret_cast<const uint*>(pB + rowYp + C);
      }
#pragma unroll
      for (int sub = 0; sub < 2; ++sub) {
        const int koff = sub * 32 + (lane >> 4) * 8;
        const bf16x8 bfv = *reinterpret_cast<const bf16x8*>(&Bsm[wc * 16 + (lane & 15)][koff]);
#pragma unroll
        for (int mf = 0; mf < MF; mf++)
          acc[mf] = __builtin_amdgcn_mfma_f32_16x16x32_bf16(afr[sub][mf], bfv, acc[mf], 0, 0, 0);
      }
      __syncthreads();
    }
  }
  const int gn = n0 + wc * 16 + (lane & 15);
#pragma unroll
  for (int mf = 0; mf < MF; mf++) {
    const int mbase = wr * 64 + mf * 16 + ((lane >> 4) * 4);
    if (gn < N) {
#pragma unroll
      for (int rr = 0; rr < 4; rr++)
        out[((size_t)b * C + mbase + rr) * N + gn] = acc[mf][rr] + bias[mbase + rr];
    }
  }
}

// ---------------------------------------------------------------------------
extern "C" void kernel_launch(void* const* d_in, const int* in_sizes, int n_in,
                              void* d_out, int out_size, void* d_ws, size_t ws_size,
                              hipStream_t stream) {
  const float* t_in = (const float*)d_in[0];
  const float* s_in = (const float*)d_in[1];
  const float* t_qw = (const float*)d_in[2];
  const float* t_qb = (const float*)d_in[3];
  const float* t_kw = (const float*)d_in[4];
  const float* t_kb = (const float*)d_in[5];
  const float* t_vw = (const float*)d_in[6];
  const float* t_vb = (const float*)d_in[7];
  const float* t_g = (const float*)d_in[8];
  const float* s_qw = (const float*)d_in[9];
  const float* s_qb = (const float*)d_in[10];
  const float* s_kw = (const float*)d_in[11];
  const float* s_kb = (const float*)d_in[12];
  const float* s_vw = (const float*)d_in[13];
  const float* s_vb = (const float*)d_in[14];
  const float* s_g = (const float*)d_in[15];
  const float* w_t_ch = (const float*)d_in[16];
  const float* w_s_ch = (const float*)d_in[17];
  const float* w_s2t = (const float*)d_in[18];
  const float* w_t2s = (const float*)d_in[19];
  const float* t_off_w = (const float*)d_in[20];
  const float* t_off_b = (const float*)d_in[21];
  const float* t_dcn_w = (const float*)d_in[22];
  const float* t_dcn_b = (const float*)d_in[23];
  const float* s_off_w = (const float*)d_in[24];
  const float* s_off_b = (const float*)d_in[25];
  const float* s_dcn_w = (const float*)d_in[26];
  const float* s_dcn_b = (const float*)d_in[27];
  (void)in_sizes; (void)n_in; (void)out_size; (void)ws_size;

  constexpr int Bn = 16, C = 256;
  constexpr int HT = 15, WT = 15, NT = HT * WT;    // 225
  constexpr int HS = 31, WS2 = 31, NS = HS * WS2;  // 961
  constexpr int NpT = 256, NpS = 992;
  constexpr int NRT = 256, NRS = 1024;

  float* ws = (float*)d_ws;
  size_t off = 0;
  auto alloc = [&](size_t n) {
    n = (n + 3) & ~(size_t)3;
    float* p = ws + off; off += n; return p;
  };
  auto allocU = [&](size_t nu) { return (ushort*)alloc((nu + 1) / 2); };

  float* qk_t = alloc((size_t)Bn * 64 * NT);
  float* qk_s = alloc((size_t)Bn * 64 * NS);
  float* qkw_t = alloc((size_t)64 * C + 64);
  float* qkw_s = alloc((size_t)64 * C + 64);
  float* qkb_t = qkw_t + (size_t)64 * C;
  float* qkb_s = qkw_s + (size_t)64 * C;
  ushort* xT_t = allocU((size_t)Bn * NRT * C);
  ushort* xT_s = allocU((size_t)Bn * NRS * C);
  ushort* xbf_t = allocU((size_t)Bn * C * NpT);
  ushort* xbf_s = allocU((size_t)Bn * C * NpS);
  ushort* Wv_t = allocU((size_t)C * C);
  ushort* Wv_s = allocU((size_t)C * C);
  ushort* v_tbf = allocU((size_t)Bn * C * NpT);
  ushort* v_sbf = allocU((size_t)Bn * C * NpS);
  ushort* S_t = allocU((size_t)Bn * NT * NpT);
  ushort* S_s = allocU((size_t)Bn * NS * NpS);
  ushort* xsT_t = allocU((size_t)Bn * NRT * C);
  ushort* xsT_s = allocU((size_t)Bn * NRS * C);
  float* Atc = alloc((size_t)Bn * C * C);
  float* Asc = alloc((size_t)Bn * C * C);
  ushort* Mc_t = allocU((size_t)Bn * C * C);
  ushort* Mc_s = allocU((size_t)Bn * C * C);
  float* om_t = alloc((size_t)Bn * 27 * NT);
  float* om_s = alloc((size_t)Bn * 27 * NS);
  ushort* owb_t = allocU((size_t)32 * 2304);
  ushort* owb_s = allocU((size_t)32 * 2304);
  ushort* Awb_t = allocU((size_t)256 * 2304);
  ushort* Awb_s = allocU((size_t)256 * 2304);
  uint4* prep_t = (uint4*)alloc((size_t)Bn * 9 * NT * 4);
  uint4* prep_s = (uint4*)alloc((size_t)Bn * 9 * NS * 4);

  dim3 blk(256);

  // 1. fused weight prep (DCN weights -> fragment-major)
  prep_weights_kernel<<<dim3((1491072 + 255) / 256), blk, 0, stream>>>(
      t_qw, t_qb, t_kw, t_kb, s_qw, s_qb, s_kw, s_kb, t_vw, s_vw,
      t_off_w, s_off_w, t_dcn_w, s_dcn_w,
      qkw_t, qkb_t, qkw_s, qkb_s, Wv_t, Wv_s, owb_t, owb_s, Awb_t, Awb_s);

  // 2. fused q|k projections
  conv1x1_fused_kernel<<<dim3(320), blk, 0, stream>>>(
      s_in, qkw_s, qkb_s, qk_s, NS, t_in, qkw_t, qkb_t, qk_t, NT);

  // 3-4. fused casts
  cast_transpose_fused_kernel<<<dim3(1280), blk, 0, stream>>>(
      s_in, xT_s, NS, NRS, t_in, xT_t, NT, NRT);
  cast_pad_fused_kernel<<<dim3((Bn * C * NpS + Bn * C * NpT + 255) / 256), blk, 0, stream>>>(
      s_in, xbf_s, NS, NpS, Bn * C * NpS, t_in, xbf_t, NT, NpT, Bn * C * NpT);

  // 5. fused v projection (EPI=0)
  gemm_fused_kernel<0><<<dim3(640), blk, 0, stream>>>(
      Wv_s, 0, xT_s, s_vb, v_sbf, nullptr, NS, NpS, NRS, C,
      Wv_t, 0, xT_t, t_vb, v_tbf, nullptr, NT, NpT, NRT, C,
      512, 16, 4);

  // 6. fused energy
  energy_fused_kernel<<<dim3(4352), blk, 0, stream>>>(
      qk_s, S_s, NS, NpS, qk_t, S_t, NT, NpT);

  // 7. fused spatial softmax
  softmax_bf16_fused_kernel<<<dim3(Bn * NS + Bn * NT), blk, 0, stream>>>(
      S_s, NS, NpS, S_t, NT, NpT, Bn * NS);

  // 8. fused gram (EPI=2)
  gemm_fused_kernel<2><<<dim3(256), blk, 0, stream>>>(
      xbf_s, 1, xbf_s, nullptr, nullptr, Asc, C, C, C, NpS,
      xbf_t, 1, xbf_t, nullptr, nullptr, Atc, C, C, C, NpT,
      128, 4, 4);

  // 9. fused channel softmax + mcomb
  softmax_mcomb_kernel<<<dim3(Bn * C), blk, 0, stream>>>(
      Atc, Asc, w_t_ch, w_s2t, w_s_ch, w_t2s, Mc_t, Mc_s);

  // 10. merged PV + chan GEMM -> xsT
  pv_chan_fused_kernel<<<dim3(640), blk, 0, stream>>>(
      v_sbf, S_s, Mc_s, xT_s, s_in, s_g, xsT_s, NS, NpS, NRS,
      v_tbf, S_t, Mc_t, xT_t, t_in, t_g, xsT_t, NT, NpT, NRT);

  // 11. fused offconv
  offconv_fused_kernel<<<dim3(320), blk, 0, stream>>>(
      xsT_s, owb_s, s_off_b, om_s, HS, WS2, NS, NRS,
      xsT_t, owb_t, t_off_b, om_t, HT, WT, NT, NRT);

  // 12. fused gather-table prep
  prep_offsets_fused_kernel<<<dim3((Bn * 9 * NS + Bn * 9 * NT + 255) / 256), blk, 0, stream>>>(
      om_s, prep_s, HS, WS2, Bn * 9 * NS, om_t, prep_t, HT, WT, Bn * 9 * NT);

  // 13. fused DCN (r14 best config)
  float* out_t = (float*)d_out;
  float* out_s = out_t + (size_t)Bn * C * NT;
  dcn_fused_kernel<<<dim3(640), dim3(512), 0, stream>>>(
      xsT_s, prep_s, Awb_s, s_dcn_b, out_s, NS, WS2, NRS,
      xsT_t, prep_t, Awb_t, t_dcn_b, out_t, NT, WT, NRT);
}

// Round 17
// 348.651 us; speedup vs baseline: 1.0299x; 1.0121x over previous
//
#include <hip/hip_runtime.h>
#include <hip/hip_bf16.h>
#include <cmath>

typedef __attribute__((ext_vector_type(8))) short bf16x8;
typedef __attribute__((ext_vector_type(4))) float f32x4;

__device__ inline ushort f2bf(float f) {
  __hip_bfloat16 h = __float2bfloat16(f);
  return *reinterpret_cast<ushort*>(&h);
}
__device__ inline float bf2f(ushort u) {
  return __uint_as_float((uint)u << 16);
}
__device__ inline float bflo(uint x) { return __uint_as_float(x << 16); }
__device__ inline float bfhi(uint x) { return __uint_as_float(x & 0xffff0000u); }

// Fused-side decode with XCD-aware bijective chunking.
__device__ inline bool fdecode(int totalS, int gxS, int gyS, int gxT, int gyT,
                               int& bx, int& by, int& bz, bool& isT) {
  const int total = gridDim.x;
  const int id = blockIdx.x;
  int wid = (id & 7) * (total >> 3) + (id >> 3);
  const int totalT = gxT * gyT * 16;
  if (wid >= totalS + totalT) return false;
  isT = wid >= totalS;
  int lid = isT ? wid - totalS : wid;
  const int gx = isT ? gxT : gxS;
  const int gy = isT ? gyT : gyS;
  bx = lid % gx;
  lid /= gx;
  by = lid % gy;
  bz = lid / gy;
  return true;
}

// ---------------------------------------------------------------------------
// fused weight prep. DCN weights FRAGMENT-MAJOR:
// frag (mt,kt) = 16 rows x 32 k; elem (lane, j): o = mt*16+(lane&15),
// k = kt*32+(lane>>4)*8+j. dst = ((mt*72+kt)<<9) + lane*8 + j.
// ---------------------------------------------------------------------------
__global__ __launch_bounds__(256) void prep_weights_kernel(
    const float* __restrict__ t_qw, const float* __restrict__ t_qb,
    const float* __restrict__ t_kw, const float* __restrict__ t_kb,
    const float* __restrict__ s_qw, const float* __restrict__ s_qb,
    const float* __restrict__ s_kw, const float* __restrict__ s_kb,
    const float* __restrict__ t_vw, const float* __restrict__ s_vw,
    const float* __restrict__ t_off_w, const float* __restrict__ s_off_w,
    const float* __restrict__ t_dcn_w, const float* __restrict__ s_dcn_w,
    float* __restrict__ qkw_t, float* __restrict__ qkb_t,
    float* __restrict__ qkw_s, float* __restrict__ qkb_s,
    ushort* __restrict__ Wv_t, ushort* __restrict__ Wv_s,
    ushort* __restrict__ owb_t, ushort* __restrict__ owb_s,
    ushort* __restrict__ Awb_t, ushort* __restrict__ Awb_s) {
  int i = blockIdx.x * 256 + threadIdx.x;
  if (i < 16448) {
    if (i < 8192) qkw_t[i] = t_qw[i];
    else if (i < 16384) qkw_t[i] = t_kw[i - 8192];
    else { int j = i - 16384; qkb_t[j] = (j < 32) ? t_qb[j] : t_kb[j - 32]; }
    return;
  }
  i -= 16448;
  if (i < 16448) {
    if (i < 8192) qkw_s[i] = s_qw[i];
    else if (i < 16384) qkw_s[i] = s_kw[i - 8192];
    else { int j = i - 16384; qkb_s[j] = (j < 32) ? s_qb[j] : s_kb[j - 32]; }
    return;
  }
  i -= 16448;
  if (i < 65536) { Wv_t[i] = f2bf(t_vw[i]); return; }
  i -= 65536;
  if (i < 65536) { Wv_s[i] = f2bf(s_vw[i]); return; }
  i -= 65536;
  if (i < 73728) {
    const int o = i / 2304, k = i % 2304, tap = k >> 8, c = k & 255;
    owb_t[i] = (o < 27) ? f2bf(t_off_w[(size_t)o * 2304 + c * 9 + tap]) : (ushort)0;
    return;
  }
  i -= 73728;
  if (i < 73728) {
    const int o = i / 2304, k = i % 2304, tap = k >> 8, c = k & 255;
    owb_s[i] = (o < 27) ? f2bf(s_off_w[(size_t)o * 2304 + c * 9 + tap]) : (ushort)0;
    return;
  }
  i -= 73728;
  if (i < 589824) {
    const int frag = i >> 9, within = i & 511;
    const int lane = within >> 3, j = within & 7;
    const int mt = frag / 72, kt = frag % 72;
    const int o = mt * 16 + (lane & 15);
    const int k = kt * 32 + (lane >> 4) * 8 + j;
    const int tap = k >> 8, c = k & 255;
    Awb_t[i] = f2bf(t_dcn_w[(size_t)o * 2304 + c * 9 + tap]);
    return;
  }
  i -= 589824;
  if (i < 589824) {
    const int frag = i >> 9, within = i & 511;
    const int lane = within >> 3, j = within & 7;
    const int mt = frag / 72, kt = frag % 72;
    const int o = mt * 16 + (lane & 15);
    const int k = kt * 32 + (lane >> 4) * 8 + j;
    const int tap = k >> 8, c = k & 255;
    Awb_s[i] = f2bf(s_dcn_w[(size_t)o * 2304 + c * 9 + tap]);
  }
}

// ---------------------------------------------------------------------------
// fused conv1x1 (fp32) q|k projection, OC=64
// ---------------------------------------------------------------------------
__global__ __launch_bounds__(256) void conv1x1_fused_kernel(
    const float* __restrict__ xS, const float* __restrict__ wS,
    const float* __restrict__ bS, float* __restrict__ oS, int NS_,
    const float* __restrict__ xT, const float* __restrict__ wT,
    const float* __restrict__ bT, float* __restrict__ oT, int NT_) {
  constexpr int C = 256, OC = 64;
  __shared__ float As[64][17];
  __shared__ float Bs[16][64];
  int bx, by, bz; bool isT;
  if (!fdecode(256, 16, 1, 4, 1, bx, by, bz, isT)) return;
  const float* x = isT ? xT : xS;
  const float* w = isT ? wT : wS;
  const float* bias = isT ? bT : bS;
  float* out = isT ? oT : oS;
  const int N = isT ? NT_ : NS_;
  const int b = bz;
  const int n0 = bx * 64;
  const float* xb = x + (size_t)b * C * N;
  const int tid = threadIdx.x;
  const int tr = tid >> 4, tc = tid & 15;
  float acc[4][4] = {};
  for (int k0 = 0; k0 < C; k0 += 16) {
    for (int i = tid; i < 64 * 16; i += 256) {
      int m = i >> 4, kk = i & 15;
      As[m][kk] = w[(size_t)m * C + k0 + kk];
    }
    for (int i = tid; i < 16 * 64; i += 256) {
      int kk = i >> 6, n = i & 63;
      int gn = n0 + n;
      Bs[kk][n] = (gn < N) ? xb[(size_t)(k0 + kk) * N + gn] : 0.f;
    }
    __syncthreads();
#pragma unroll
    for (int kk = 0; kk < 16; ++kk) {
      float a[4], bb[4];
#pragma unroll
      for (int i = 0; i < 4; i++) a[i] = As[tr * 4 + i][kk];
#pragma unroll
      for (int j = 0; j < 4; j++) bb[j] = Bs[kk][tc * 4 + j];
#pragma unroll
      for (int i = 0; i < 4; i++)
#pragma unroll
        for (int j = 0; j < 4; j++) acc[i][j] += a[i] * bb[j];
    }
    __syncthreads();
  }
  for (int i = 0; i < 4; i++) {
    int gm = tr * 4 + i;
    if (gm >= OC) continue;
    float bv = bias[gm];
    for (int j = 0; j < 4; j++) {
      int gn = n0 + tc * 4 + j;
      if (gn < N) out[((size_t)b * OC + gm) * N + gn] = acc[i][j] + bv;
    }
  }
}

// ---------------------------------------------------------------------------
// fused cast+transpose: x fp32 [C][N] -> xT bf16 [NR][C]
// ---------------------------------------------------------------------------
__global__ __launch_bounds__(256) void cast_transpose_fused_kernel(
    const float* __restrict__ xS, ushort* __restrict__ oS, int NS_, int NRS_,
    const float* __restrict__ xT, ushort* __restrict__ oT, int NT_, int NRT_) {
  constexpr int C = 256;
  __shared__ float T[64][65];
  int bx, by, bz; bool isT;
  if (!fdecode(1024, 16, 4, 4, 4, bx, by, bz, isT)) return;
  const float* x = isT ? xT : xS;
  ushort* xTo = isT ? oT : oS;
  const int N = isT ? NT_ : NS_;
  const int NR = isT ? NRT_ : NRS_;
  const int b = bz;
  const int n0 = bx * 64, c0 = by * 64;
  const float* xb = x + (size_t)b * C * N;
  const int tid = threadIdx.x;
  for (int u = tid; u < 4096; u += 256) {
    const int cc = u >> 6, nn = u & 63;
    const int gn = n0 + nn;
    T[cc][nn] = (gn < N) ? xb[(size_t)(c0 + cc) * N + gn] : 0.f;
  }
  __syncthreads();
  ushort* ob = xTo + (size_t)b * NR * C;
  for (int u = tid; u < 4096; u += 256) {
    const int nn = u >> 6, cc = u & 63;
    ob[(size_t)(n0 + nn) * C + c0 + cc] = f2bf(T[cc][nn]);
  }
}

// ---------------------------------------------------------------------------
// fused cast+pad
// ---------------------------------------------------------------------------
__global__ __launch_bounds__(256) void cast_pad_fused_kernel(
    const float* __restrict__ xS, ushort* __restrict__ oS, int NS_, int NpS_,
    int totS,
    const float* __restrict__ xT, ushort* __restrict__ oT, int NT_, int NpT_,
    int totT) {
  constexpr int C = 256;
  int i = blockIdx.x * 256 + threadIdx.x;
  if (i < totS) {
    const int np = i % NpS_;
    const int c = (i / NpS_) % C;
    const int b = i / (NpS_ * C);
    oS[i] = (np < NS_) ? f2bf(xS[((size_t)b * C + c) * NS_ + np]) : (ushort)0;
    return;
  }
  i -= totS;
  if (i < totT) {
    const int np = i % NpT_;
    const int c = (i / NpT_) % C;
    const int b = i / (NpT_ * C);
    oT[i] = (np < NT_) ? f2bf(xT[((size_t)b * C + c) * NT_ + np]) : (ushort)0;
  }
}

// ---------------------------------------------------------------------------
// fused channel softmax + mcomb
// ---------------------------------------------------------------------------
__global__ __launch_bounds__(256) void softmax_mcomb_kernel(
    const float* __restrict__ Atc, const float* __restrict__ Asc,
    const float* __restrict__ w_t_ch, const float* __restrict__ w_s2t,
    const float* __restrict__ w_s_ch, const float* __restrict__ w_t2s,
    ushort* __restrict__ Mc_t, ushort* __restrict__ Mc_s) {
  const int row = blockIdx.x;
  const int tid = threadIdx.x;
  __shared__ float red[8];
  const size_t idx = (size_t)row * 256 + tid;
  const float a = -Atc[idx];
  const float s = -Asc[idx];
  float ma = a, ms = s;
#pragma unroll
  for (int off = 32; off; off >>= 1) {
    ma = fmaxf(ma, __shfl_xor(ma, off, 64));
    ms = fmaxf(ms, __shfl_xor(ms, off, 64));
  }
  if ((tid & 63) == 0) { red[tid >> 6] = ma; red[4 + (tid >> 6)] = ms; }
  __syncthreads();
  if (tid == 0) {
    float m1 = red[0], m2 = red[4];
    for (int i = 1; i < 4; i++) { m1 = fmaxf(m1, red[i]); m2 = fmaxf(m2, red[4 + i]); }
    red[0] = m1; red[4] = m2;
  }
  __syncthreads();
  ma = red[0]; ms = red[4];
  __syncthreads();
  const float ea = __expf(a - ma), es = __expf(s - ms);
  float sa = ea, ss = es;
#pragma unroll
  for (int off = 32; off; off >>= 1) {
    sa += __shfl_xor(sa, off, 64);
    ss += __shfl_xor(ss, off, 64);
  }
  if ((tid & 63) == 0) { red[tid >> 6] = sa; red[4 + (tid >> 6)] = ss; }
  __syncthreads();
  if (tid == 0) {
    float t1 = 0.f, t2 = 0.f;
    for (int i = 0; i < 4; i++) { t1 += red[i]; t2 += red[4 + i]; }
    red[0] = t1; red[4] = t2;
  }
  __syncthreads();
  const float Pa = ea / red[0], Ps = es / red[4];
  Mc_t[idx] = f2bf(w_t_ch[0] * Pa + w_s2t[0] * Ps);
  Mc_s[idx] = f2bf(w_s_ch[0] * Ps + w_t2s[0] * Pa);
}

// ---------------------------------------------------------------------------
// fused generic bf16 GEMM, BM=128, NW=4.
// EPI 0: outBf = bf16(acc+bias) padded   EPI 2: outF = acc
// ---------------------------------------------------------------------------
template <int EPI>
__global__ __launch_bounds__(256) void gemm_fused_kernel(
    const ushort* __restrict__ AS, int aPerB_S, const ushort* __restrict__ BtS,
    const float* __restrict__ biasS, ushort* __restrict__ outBfS,
    float* __restrict__ outFS, int NS_, int NpS_, int NRS_, int KpS_,
    const ushort* __restrict__ AT, int aPerB_T, const ushort* __restrict__ BtT,
    const float* __restrict__ biasT, ushort* __restrict__ outBfT,
    float* __restrict__ outFT, int NT_, int NpT_, int NRT_, int KpT_,
    int totalS, int gxS, int gxT) {
  constexpr int CM = 256, BM = 128, NW = 4, NF = 2, WN = 2;
  __shared__ ushort Asm[BM][40];
  __shared__ ushort Bsm[64][40];
  int bx, by, bz; bool isT;
  if (!fdecode(totalS, gxS, 2, gxT, 2, bx, by, bz, isT)) return;
  const ushort* A = isT ? AT : AS;
  const ushort* Bt = isT ? BtT : BtS;
  const float* bias = isT ? biasT : biasS;
  ushort* outBf = isT ? outBfT : outBfS;
  float* outF = isT ? outFT : outFS;
  const int aPerBatch = isT ? aPerB_T : aPerB_S;
  const int N = isT ? NT_ : NS_, Np = isT ? NpT_ : NpS_;
  const int NR = isT ? NRT_ : NRS_, Kp = isT ? KpT_ : KpS_;
  const int n0 = bx * 64, m0 = by * BM, b = bz;
  const ushort* Ab = A + (size_t)(aPerBatch ? b : 0) * CM * Kp;
  const ushort* Bb = Bt + (size_t)b * NR * Kp;
  const int tid = threadIdx.x, lane = tid & 63, w = tid >> 6;
  const int wr = w / WN, wc = w % WN;
  f32x4 acc[4][NF];
#pragma unroll
  for (int i = 0; i < 4; i++)
#pragma unroll
    for (int j = 0; j < NF; j++) acc[i][j] = (f32x4){0.f, 0.f, 0.f, 0.f};
  for (int k0 = 0; k0 < Kp; k0 += 32) {
    for (int u = tid; u < BM * 4; u += NW * 64) {
      const int row = u >> 2, seg = u & 3;
      *reinterpret_cast<uint4*>(&Asm[row][seg * 8]) =
          *reinterpret_cast<const uint4*>(&Ab[(size_t)(m0 + row) * Kp + k0 + seg * 8]);
    }
    for (int u = tid; u < 64 * 4; u += NW * 64) {
      const int row = u >> 2, seg = u & 3;
      *reinterpret_cast<uint4*>(&Bsm[row][seg * 8]) =
          *reinterpret_cast<const uint4*>(&Bb[(size_t)(n0 + row) * Kp + k0 + seg * 8]);
    }
    __syncthreads();
    const int koff = (lane >> 4) * 8;
    bf16x8 af[4], bfr[NF];
#pragma unroll
    for (int mf = 0; mf < 4; mf++)
      af[mf] = *reinterpret_cast<const bf16x8*>(&Asm[wr * 64 + mf * 16 + (lane & 15)][koff]);
#pragma unroll
    for (int nf = 0; nf < NF; nf++)
      bfr[nf] = *reinterpret_cast<const bf16x8*>(&Bsm[wc * NF * 16 + nf * 16 + (lane & 15)][koff]);
#pragma unroll
    for (int mf = 0; mf < 4; mf++)
#pragma unroll
      for (int nf = 0; nf < NF; nf++)
        acc[mf][nf] = __builtin_amdgcn_mfma_f32_16x16x32_bf16(af[mf], bfr[nf], acc[mf][nf], 0, 0, 0);
    __syncthreads();
  }
#pragma unroll
  for (int mf = 0; mf < 4; mf++) {
    const int mbase = m0 + wr * 64 + mf * 16 + ((lane >> 4) * 4);
#pragma unroll
    for (int nf = 0; nf < NF; nf++) {
      const int gn = n0 + wc * NF * 16 + nf * 16 + (lane & 15);
      if (EPI == 0) {
#pragma unroll
        for (int rr = 0; rr < 4; rr++) {
          const int m = mbase + rr;
          if (gn < Np) {
            ushort v = (gn < N) ? f2bf(acc[mf][nf][rr] + bias[m]) : (ushort)0;
            outBf[((size_t)b * CM + m) * Np + gn] = v;
          }
        }
      } else {
#pragma unroll
        for (int rr = 0; rr < 4; rr++) {
          if (gn < N)
            outF[((size_t)b * CM + mbase + rr) * N + gn] = acc[mf][nf][rr];
        }
      }
    }
  }
  (void)NR;
}

// ---------------------------------------------------------------------------
// fused energy (K=32)
// ---------------------------------------------------------------------------
__global__ __launch_bounds__(256) void energy_fused_kernel(
    const float* __restrict__ qkS, ushort* __restrict__ SS, int NS_, int NpS_,
    const float* __restrict__ qkT, ushort* __restrict__ ST, int NT_, int NpT_) {
  __shared__ ushort Aq[64][40];
  __shared__ ushort Bk[64][40];
  int bx, by, bz; bool isT;
  if (!fdecode(4096, 16, 16, 4, 4, bx, by, bz, isT)) return;
  const float* qk = isT ? qkT : qkS;
  ushort* Sbf = isT ? ST : SS;
  const int N = isT ? NT_ : NS_, Np = isT ? NpT_ : NpS_;
  const int m0 = bx * 64, n0 = by * 64, b = bz;
  const float* qb = qk + (size_t)b * 64 * N;
  const float* kb = qb + (size_t)32 * N;
  const int tid = threadIdx.x, lane = tid & 63, w = tid >> 6;
  for (int u = tid; u < 2048; u += 256) {
    const int c = u >> 6, nn = u & 63;
    const int gn = n0 + nn, gm = m0 + nn;
    Aq[nn][c] = (gn < N) ? f2bf(qb[(size_t)c * N + gn]) : (ushort)0;
    Bk[nn][c] = (gm < N) ? f2bf(kb[(size_t)c * N + gm]) : (ushort)0;
  }
  __syncthreads();
  const int koff = (lane >> 4) * 8;
  const bf16x8 af = *reinterpret_cast<const bf16x8*>(&Aq[w * 16 + (lane & 15)][koff]);
  f32x4 acc[4];
#pragma unroll
  for (int j = 0; j < 4; j++) {
    const bf16x8 bf = *reinterpret_cast<const bf16x8*>(&Bk[j * 16 + (lane & 15)][koff]);
    acc[j] = __builtin_amdgcn_mfma_f32_16x16x32_bf16(af, bf, (f32x4){0.f, 0.f, 0.f, 0.f}, 0, 0, 0);
  }
#pragma unroll
  for (int j = 0; j < 4; j++) {
    const int m = m0 + j * 16 + (lane & 15);
    if (m >= Np) continue;
#pragma unroll
    for (int r = 0; r < 4; r++) {
      const int n = n0 + w * 16 + (lane >> 4) * 4 + r;
      if (n < N) Sbf[((size_t)b * N + n) * Np + m] = (m < N) ? f2bf(acc[j][r]) : (ushort)0;
    }
  }
}

// ---------------------------------------------------------------------------
// fused bf16 row softmax (spatial scores)
// ---------------------------------------------------------------------------
__global__ __launch_bounds__(256) void softmax_bf16_fused_kernel(
    ushort* __restrict__ Ss, int Ns, int Nps, ushort* __restrict__ St, int Nt,
    int Npt, int rowsS) {
  __shared__ float buf[992];
  __shared__ float red[4];
  const int row = blockIdx.x;
  ushort* r;
  int N;
  if (row < rowsS) {
    r = Ss + (size_t)row * Nps;
    N = Ns;
  } else {
    r = St + (size_t)(row - rowsS) * Npt;
    N = Nt;
  }
  const int tid = threadIdx.x;
  float mx = -1e30f;
  for (int i = tid; i < N; i += 256) {
    float f = bf2f(r[i]);
    buf[i] = f;
    mx = fmaxf(mx, f);
  }
#pragma unroll
  for (int off = 32; off; off >>= 1) mx = fmaxf(mx, __shfl_xor(mx, off, 64));
  if ((tid & 63) == 0) red[tid >> 6] = mx;
  __syncthreads();
  if (tid == 0) {
    float m2 = red[0];
    for (int i = 1; i < 4; i++) m2 = fmaxf(m2, red[i]);
    red[0] = m2;
  }
  __syncthreads();
  mx = red[0];
  __syncthreads();
  float s = 0.f;
  for (int i = tid; i < N; i += 256) {
    float v = __expf(buf[i] - mx);
    buf[i] = v;
    s += v;
  }
#pragma unroll
  for (int off = 32; off; off >>= 1) s += __shfl_xor(s, off, 64);
  if ((tid & 63) == 0) red[tid >> 6] = s;
  __syncthreads();
  if (tid == 0) {
    float t = 0.f;
    for (int i = 0; i < 4; i++) t += red[i];
    red[0] = t;
  }
  __syncthreads();
  const float inv = 1.f / red[0];
  for (int i = tid; i < N; i += 256) r[i] = f2bf(buf[i] * inv);
}

// ---------------------------------------------------------------------------
// fused PV+CHAN merged GEMM (BM=128): acc = PV(v@S^T); acc *= g;
// acc += Mc@xT; out_xsT = bf16(x + acc).
// ---------------------------------------------------------------------------
__global__ __launch_bounds__(256) void pv_chan_fused_kernel(
    const ushort* __restrict__ vS, const ushort* __restrict__ SS,
    const ushort* __restrict__ McS, const ushort* __restrict__ xTS,
    const float* __restrict__ xS, const float* __restrict__ gS,
    ushort* __restrict__ xsTS, int NS_, int NpS_, int NRS_,
    const ushort* __restrict__ vT, const ushort* __restrict__ ST,
    const ushort* __restrict__ McT, const ushort* __restrict__ xTT,
    const float* __restrict__ xT_, const float* __restrict__ gT,
    ushort* __restrict__ xsTT, int NT_, int NpT_, int NRT_) {
  constexpr int C = 256, BM = 128, NW = 4, NF = 2, WN = 2;
  __shared__ ushort Asm[BM][40];
  __shared__ ushort Bsm[64][40];
  int bx, by, bz; bool isT;
  if (!fdecode(512, 16, 2, 4, 2, bx, by, bz, isT)) return;
  const ushort* vbf = isT ? vT : vS;
  const ushort* Sbf = isT ? ST : SS;
  const ushort* Mc = isT ? McT : McS;
  const ushort* xTb = isT ? xTT : xTS;
  const float* x = isT ? xT_ : xS;
  const float* gp = isT ? gT : gS;
  ushort* xsT = isT ? xsTT : xsTS;
  const int N = isT ? NT_ : NS_, Np = isT ? NpT_ : NpS_;
  const int NR = isT ? NRT_ : NRS_;
  const int n0 = bx * 64, m0 = by * BM, b = bz;
  const int tid = threadIdx.x, lane = tid & 63, w = tid >> 6;
  const int wr = w / WN, wc = w % WN;
  f32x4 acc[4][NF];
#pragma unroll
  for (int i = 0; i < 4; i++)
#pragma unroll
    for (int j = 0; j < NF; j++) acc[i][j] = (f32x4){0.f, 0.f, 0.f, 0.f};
  const int koff = (lane >> 4) * 8;
  // phase 1: PV, K = Np
  {
    const ushort* Ab = vbf + (size_t)b * C * Np;
    const ushort* Bb = Sbf + (size_t)b * (size_t)N * Np;
    for (int k0 = 0; k0 < Np; k0 += 32) {
      for (int u = tid; u < BM * 4; u += NW * 64) {
        const int row = u >> 2, seg = u & 3;
        *reinterpret_cast<uint4*>(&Asm[row][seg * 8]) =
            *reinterpret_cast<const uint4*>(&Ab[(size_t)(m0 + row) * Np + k0 + seg * 8]);
      }
      for (int u = tid; u < 64 * 4; u += NW * 64) {
        const int row = u >> 2, seg = u & 3;
        const int gn = n0 + row;
        uint4 val;
        if (gn < N)
          val = *reinterpret_cast<const uint4*>(&Bb[(size_t)gn * Np + k0 + seg * 8]);
        else
          val = make_uint4(0, 0, 0, 0);
        *reinterpret_cast<uint4*>(&Bsm[row][seg * 8]) = val;
      }
      __syncthreads();
      bf16x8 af[4], bfr[NF];
#pragma unroll
      for (int mf = 0; mf < 4; mf++)
        af[mf] = *reinterpret_cast<const bf16x8*>(&Asm[wr * 64 + mf * 16 + (lane & 15)][koff]);
#pragma unroll
      for (int nf = 0; nf < NF; nf++)
        bfr[nf] = *reinterpret_cast<const bf16x8*>(&Bsm[wc * NF * 16 + nf * 16 + (lane & 15)][koff]);
#pragma unroll
      for (int mf = 0; mf < 4; mf++)
#pragma unroll
        for (int nf = 0; nf < NF; nf++)
          acc[mf][nf] = __builtin_amdgcn_mfma_f32_16x16x32_bf16(af[mf], bfr[nf], acc[mf][nf], 0, 0, 0);
      __syncthreads();
    }
  }
  const float g = *gp;
#pragma unroll
  for (int mf = 0; mf < 4; mf++)
#pragma unroll
    for (int nf = 0; nf < NF; nf++)
#pragma unroll
      for (int rr = 0; rr < 4; rr++) acc[mf][nf][rr] *= g;
  // phase 2: chan, K = C
  {
    const ushort* Ab = Mc + (size_t)b * C * C;
    const ushort* Bb = xTb + (size_t)b * NR * C;
    for (int k0 = 0; k0 < C; k0 += 32) {
      for (int u = tid; u < BM * 4; u += NW * 64) {
        const int row = u >> 2, seg = u & 3;
        *reinterpret_cast<uint4*>(&Asm[row][seg * 8]) =
            *reinterpret_cast<const uint4*>(&Ab[(size_t)(m0 + row) * C + k0 + seg * 8]);
      }
      for (int u = tid; u < 64 * 4; u += NW * 64) {
        const int row = u >> 2, seg = u & 3;
        *reinterpret_cast<uint4*>(&Bsm[row][seg * 8]) =
            *reinterpret_cast<const uint4*>(&Bb[(size_t)(n0 + row) * C + k0 + seg * 8]);
      }
      __syncthreads();
      bf16x8 af[4], bfr[NF];
#pragma unroll
      for (int mf = 0; mf < 4; mf++)
        af[mf] = *reinterpret_cast<const bf16x8*>(&Asm[wr * 64 + mf * 16 + (lane & 15)][koff]);
#pragma unroll
      for (int nf = 0; nf < NF; nf++)
        bfr[nf] = *reinterpret_cast<const bf16x8*>(&Bsm[wc * NF * 16 + nf * 16 + (lane & 15)][koff]);
#pragma unroll
      for (int mf = 0; mf < 4; mf++)
#pragma unroll
        for (int nf = 0; nf < NF; nf++)
          acc[mf][nf] = __builtin_amdgcn_mfma_f32_16x16x32_bf16(af[mf], bfr[nf], acc[mf][nf], 0, 0, 0);
      __syncthreads();
    }
  }
#pragma unroll
  for (int mf = 0; mf < 4; mf++) {
    const int mbase = m0 + wr * 64 + mf * 16 + ((lane >> 4) * 4);
#pragma unroll
    for (int nf = 0; nf < NF; nf++) {
      const int gn = n0 + wc * NF * 16 + nf * 16 + (lane & 15);
      if (gn < N) {
        float s[4];
#pragma unroll
        for (int rr = 0; rr < 4; rr++)
          s[rr] = x[((size_t)b * C + mbase + rr) * N + gn] + acc[mf][nf][rr];
        uint lo = (uint)f2bf(s[0]) | ((uint)f2bf(s[1]) << 16);
        uint hi = (uint)f2bf(s[2]) | ((uint)f2bf(s[3]) << 16);
        *reinterpret_cast<uint2*>(&xsT[((size_t)b * NR + gn) * C + mbase]) =
            make_uint2(lo, hi);
      }
    }
  }
}

// ---------------------------------------------------------------------------
// fused offconv via MFMA on xsT, WITH FUSED gather-table prep (r17):
// the block holds all 27 om channels for its 64-position tile; epilogue
// stages them through LDS and computes the 9 prep entries per position
// directly. om buffer and prep_offsets launch are eliminated.
// ---------------------------------------------------------------------------
__global__ __launch_bounds__(256) void offconv_prep_fused_kernel(
    const ushort* __restrict__ xS, const ushort* __restrict__ owS,
    const float* __restrict__ obS, uint4* __restrict__ prS, int HS_, int WS_,
    int NS_, int NRS_,
    const ushort* __restrict__ xT, const ushort* __restrict__ owT,
    const float* __restrict__ obT, uint4* __restrict__ prT, int HT_, int WT_,
    int NT_, int NRT_) {
  __shared__ ushort Asm[32][136];
  __shared__ ushort Bsm[64][136];
  __shared__ int qsrc[64];
  __shared__ float som[27][65];
  int bx, by, bz; bool isT;
  if (!fdecode(256, 16, 1, 4, 1, bx, by, bz, isT)) return;
  const ushort* xsT = isT ? xT : xS;
  const ushort* owb = isT ? owT : owS;
  const float* ob = isT ? obT : obS;
  uint4* prep = isT ? prT : prS;
  const int H = isT ? HT_ : HS_, Wd = isT ? WT_ : WS_;
  const int N = isT ? NT_ : NS_, NR = isT ? NRT_ : NRS_;
  const int n0 = bx * 64, b = bz;
  const int tid = threadIdx.x, lane = tid & 63, w = tid >> 6;
  const ushort* xb = xsT + (size_t)b * NR * 256;
  f32x4 acc[2];
  acc[0] = (f32x4){0.f, 0.f, 0.f, 0.f};
  acc[1] = (f32x4){0.f, 0.f, 0.f, 0.f};
  for (int tap = 0; tap < 9; ++tap) {
    const int dy = tap / 3 - 1, dx = tap - (tap / 3) * 3 - 1;
    if (tid < 64) {
      const int p = n0 + tid;
      int q = -1;
      if (p < N) {
        const int h = p / Wd, ww = p - (p / Wd) * Wd;
        const int yy = h + dy, xx = ww + dx;
        if (yy >= 0 && yy < H && xx >= 0 && xx < Wd) q = yy * Wd + xx;
      }
      qsrc[tid] = q;
    }
    __syncthreads();
#pragma unroll
    for (int half = 0; half < 2; ++half) {
      const int k0 = tap * 256 + half * 128;
      for (int u = tid; u < 512; u += 256) {
        const int row = u >> 4, seg = u & 15;
        *reinterpret_cast<uint4*>(&Asm[row][seg * 8]) =
            *reinterpret_cast<const uint4*>(&owb[(size_t)row * 2304 + k0 + seg * 8]);
      }
      for (int u = tid; u < 1024; u += 256) {
        const int row = u >> 4, seg = u & 15;
        const int q = qsrc[row];
        uint4 val = make_uint4(0, 0, 0, 0);
        if (q >= 0)
          val = *reinterpret_cast<const uint4*>(&xb[(size_t)q * 256 + half * 128 + seg * 8]);
        *reinterpret_cast<uint4*>(&Bsm[row][seg * 8]) = val;
      }
      __syncthreads();
#pragma unroll
      for (int sub = 0; sub < 4; ++sub) {
        const int koff = sub * 32 + (lane >> 4) * 8;
        const bf16x8 b0 = *reinterpret_cast<const bf16x8*>(&Bsm[w * 16 + (lane & 15)][koff]);
#pragma unroll
        for (int mf = 0; mf < 2; ++mf) {
          const bf16x8 a0 = *reinterpret_cast<const bf16x8*>(&Asm[mf * 16 + (lane & 15)][koff]);
          acc[mf] = __builtin_amdgcn_mfma_f32_16x16x32_bf16(a0, b0, acc[mf], 0, 0, 0);
        }
      }
      __syncthreads();
    }
  }
  // stage om tile to LDS: som[o][p-local]
#pragma unroll
  for (int mf = 0; mf < 2; ++mf) {
#pragma unroll
    for (int r = 0; r < 4; ++r) {
      const int o = mf * 16 + (lane >> 4) * 4 + r;
      const int n = w * 16 + (lane & 15);
      if (o < 27) som[o][n] = acc[mf][r] + ob[o];
    }
  }
  __syncthreads();
  // fused prep: 9 taps x 64 positions = 576 work items
  for (int u = tid; u < 576; u += 256) {
    const int tap = u / 64, pp = u - (u / 64) * 64;
    const int p = n0 + pp;
    if (p >= N) continue;
    const float offy = som[tap][pp];
    const float offx = som[9 + tap][pp];
    const float mraw = som[18 + tap][pp];
    const float mval = 1.f / (1.f + __expf(-mraw));
    const int ky = tap / 3, kx = tap - (tap / 3) * 3;
    const int h = p / Wd, ww = p - (p / Wd) * Wd;
    const float py = offy + (float)(h + ky - 1);
    const float px = offx + (float)(ww + kx - 1);
    const float y0f = floorf(py), x0f = floorf(px);
    const float wy = py - y0f, wx = px - x0f;
    const int y0 = (int)y0f, x0 = (int)x0f;
    const int ys0 = min(max(y0, 0), H - 2);
    const int xs0 = min(max(x0, 0), Wd - 2);
    const float wr0 = (ys0 == y0) ? (1.f - wy) : ((ys0 == y0 + 1) ? wy : 0.f);
    const float wr1 = (ys0 + 1 == y0) ? (1.f - wy) : ((ys0 + 1 == y0 + 1) ? wy : 0.f);
    const float wc0 = (xs0 == x0) ? (1.f - wx) : ((xs0 == x0 + 1) ? wx : 0.f);
    const float wc1 = (xs0 + 1 == x0) ? (1.f - wx) : ((xs0 + 1 == x0 + 1) ? wx : 0.f);
    const float w00 = wr0 * wc0 * mval, w01 = wr0 * wc1 * mval;
    const float w10 = wr1 * wc0 * mval, w11 = wr1 * wc1 * mval;
    uint4 pk;
    pk.x = (uint)(ys0 * Wd + xs0);
    pk.y = (uint)f2bf(w00) | ((uint)f2bf(w01) << 16);
    pk.z = (uint)f2bf(w10) | ((uint)f2bf(w11) << 16);
    pk.w = 0;
    prep[((size_t)b * 9 + tap) * N + p] = pk;
  }
}

// ---------------------------------------------------------------------------
// fused DCN via MFMA (r14 best config: fragment-major register A, no LDS for
// A; single Bsm buffer; B-corner register prefetch; 2 barriers/step).
// BM=256, BK=64, BN=32, 512 thr. s gx=32, t gx=8; gy=1.
// ---------------------------------------------------------------------------
__global__ __launch_bounds__(512) void dcn_fused_kernel(
    const ushort* __restrict__ xS, const uint4* __restrict__ prS,
    const ushort* __restrict__ AwS, const float* __restrict__ biS,
    float* __restrict__ oS, int NS_, int WS_, int NRS_,
    const ushort* __restrict__ xT, const uint4* __restrict__ prT,
    const ushort* __restrict__ AwT, const float* __restrict__ biT,
    float* __restrict__ oT, int NT_, int WT_, int NRT_) {
  constexpr int C = 256, MF = 4;
  __shared__ ushort Bsm[32][72];
  __shared__ int sq[32];
  __shared__ float swl[4][32];
  int bx, by, bz; bool isT;
  if (!fdecode(512, 32, 1, 8, 1, bx, by, bz, isT)) return;
  const ushort* xsT = isT ? xT : xS;
  const uint4* prep = isT ? prT : prS;
  const ushort* Awb = isT ? AwT : AwS;
  const float* bias = isT ? biT : biS;
  float* out = isT ? oT : oS;
  const int N = isT ? NT_ : NS_, Wd = isT ? WT_ : WS_, NR = isT ? NRT_ : NRS_;
  const int n0 = bx * 32, b = bz;
  const int tid = threadIdx.x, lane = tid & 63, w = tid >> 6;
  const int wr = w >> 1, wc = w & 1;
  const ushort* xb = xsT + (size_t)b * NR * C;
  const int un0 = tid >> 5;
  const int un1 = un0 + 16;
  const int kk2 = (tid & 31) * 2;
  f32x4 acc[MF];
#pragma unroll
  for (int i = 0; i < MF; i++) acc[i] = (f32x4){0.f, 0.f, 0.f, 0.f};
  uint bReg[2][4];
  int sqr0 = 0, sqr1 = 0;
  float w0a[4], w1a[4];
  const size_t rowYp = (size_t)Wd * C;
  for (int tap = 0; tap < 9; ++tap) {
    if (tid < 32) {
      const int p = n0 + tid;
      if (p < N) {
        const uint4 pk = prep[((size_t)b * 9 + tap) * N + p];
        sq[tid] = (int)pk.x * C;
        swl[0][tid] = bf2f((ushort)(pk.y & 0xffff));
        swl[1][tid] = bf2f((ushort)(pk.y >> 16));
        swl[2][tid] = bf2f((ushort)(pk.z & 0xffff));
        swl[3][tid] = bf2f((ushort)(pk.z >> 16));
      } else {
        sq[tid] = 0;
        swl[0][tid] = swl[1][tid] = swl[2][tid] = swl[3][tid] = 0.f;
      }
    }
    __syncthreads();
    sqr0 = sq[un0];
    sqr1 = sq[un1];
#pragma unroll
    for (int q = 0; q < 4; q++) {
      w0a[q] = swl[q][un0];
      w1a[q] = swl[q][un1];
    }
    // prefetch B corners for ks=0
    {
      const ushort* pA = xb + sqr0 + kk2;
      bReg[0][0] = *reinterpret_cast<const uint*>(pA);
      bReg[0][1] = *reinterpret_cast<const uint*>(pA + C);
      bReg[0][2] = *reinterpret_cast<const uint*>(pA + rowYp);
      bReg[0][3] = *reinterpret_cast<const uint*>(pA + rowYp + C);
      const ushort* pB = xb + sqr1 + kk2;
      bReg[1][0] = *reinterpret_cast<const uint*>(pB);
      bReg[1][1] = *reinterpret_cast<const uint*>(pB + C);
      bReg[1][2] = *reinterpret_cast<const uint*>(pB + rowYp);
      bReg[1][3] = *reinterpret_cast<const uint*>(pB + rowYp + C);
    }
#pragma unroll
    for (int ks = 0; ks < 4; ++ks) {
      // A fragments for this step: direct global->register, fragment-major
      bf16x8 afr[2][4];
      const int ktb = tap * 8 + ks * 2;
#pragma unroll
      for (int sub = 0; sub < 2; ++sub)
#pragma unroll
        for (int mf = 0; mf < 4; ++mf)
          afr[sub][mf] = *reinterpret_cast<const bf16x8*>(
              Awb + ((((size_t)(wr * 4 + mf) * 72) + ktb + sub) << 9) + lane * 8);
      // B-stage: pack prefetched corners to LDS
      {
        const float vlo0 = w0a[0] * bflo(bReg[0][0]) + w0a[1] * bflo(bReg[0][1]) +
                           w0a[2] * bflo(bReg[0][2]) + w0a[3] * bflo(bReg[0][3]);
        const float vhi0 = w0a[0] * bfhi(bReg[0][0]) + w0a[1] * bfhi(bReg[0][1]) +
                           w0a[2] * bfhi(bReg[0][2]) + w0a[3] * bfhi(bReg[0][3]);
        *reinterpret_cast<uint*>(&Bsm[un0][kk2]) =
            (uint)f2bf(vlo0) | ((uint)f2bf(vhi0) << 16);
        const float vlo1 = w1a[0] * bflo(bReg[1][0]) + w1a[1] * bflo(bReg[1][1]) +
                           w1a[2] * bflo(bReg[1][2]) + w1a[3] * bflo(bReg[1][3]);
        const float vhi1 = w1a[0] * bfhi(bReg[1][0]) + w1a[1] * bfhi(bReg[1][1]) +
                           w1a[2] * bfhi(bReg[1][2]) + w1a[3] * bfhi(bReg[1][3]);
        *reinterpret_cast<uint*>(&Bsm[un1][kk2]) =
            (uint)f2bf(vlo1) | ((uint)f2bf(vhi1) << 16);
      }
      __syncthreads();
      // prefetch next ks B corners (overlaps MFMA)
      if (ks < 3) {
        const int c1 = (ks + 1) * 64;
        const ushort* pA = xb + sqr0 + c1 + kk2;
        bReg[0][0] = *reinterpret_cast<const uint*>(pA);
        bReg[0][1] = *reinterpret_cast<const uint*>(pA + C);
        bReg[0][2] = *reinterpret_cast<const uint*>(pA + rowYp);
        bReg[0][3] = *reinterpret_cast<const uint*>(pA + rowYp + C);
        const ushort* pB = xb + sqr1 + c1 + kk2;
        bReg[1][0] = *reinterpret_cast<const uint*>(pB);
        bReg[1][1] = *reinterpret_cast<const uint*>(pB + C);
        bReg[1][2] = *reinterpret_cast<const uint*>(pB + rowYp);
        bReg[1][3] = *reinterpret_cast<const uint*>(pB + rowYp + C);
      }
#pragma unroll
      for (int sub = 0; sub < 2; ++sub) {
        const int koff = sub * 32 + (lane >> 4) * 8;
        const bf16x8 bfv = *reinterpret_cast<const bf16x8*>(&Bsm[wc * 16 + (lane & 15)][koff]);
#pragma unroll
        for (int mf = 0; mf < MF; mf++)
          acc[mf] = __builtin_amdgcn_mfma_f32_16x16x32_bf16(afr[sub][mf], bfv, acc[mf], 0, 0, 0);
      }
      __syncthreads();
    }
  }
  const int gn = n0 + wc * 16 + (lane & 15);
#pragma unroll
  for (int mf = 0; mf < MF; mf++) {
    const int mbase = wr * 64 + mf * 16 + ((lane >> 4) * 4);
    if (gn < N) {
#pragma unroll
      for (int rr = 0; rr < 4; rr++)
        out[((size_t)b * C + mbase + rr) * N + gn] = acc[mf][rr] + bias[mbase + rr];
    }
  }
}

// ---------------------------------------------------------------------------
extern "C" void kernel_launch(void* const* d_in, const int* in_sizes, int n_in,
                              void* d_out, int out_size, void* d_ws, size_t ws_size,
                              hipStream_t stream) {
  const float* t_in = (const float*)d_in[0];
  const float* s_in = (const float*)d_in[1];
  const float* t_qw = (const float*)d_in[2];
  const float* t_qb = (const float*)d_in[3];
  const float* t_kw = (const float*)d_in[4];
  const float* t_kb = (const float*)d_in[5];
  const float* t_vw = (const float*)d_in[6];
  const float* t_vb = (const float*)d_in[7];
  const float* t_g = (const float*)d_in[8];
  const float* s_qw = (const float*)d_in[9];
  const float* s_qb = (const float*)d_in[10];
  const float* s_kw = (const float*)d_in[11];
  const float* s_kb = (const float*)d_in[12];
  const float* s_vw = (const float*)d_in[13];
  const float* s_vb = (const float*)d_in[14];
  const float* s_g = (const float*)d_in[15];
  const float* w_t_ch = (const float*)d_in[16];
  const float* w_s_ch = (const float*)d_in[17];
  const float* w_s2t = (const float*)d_in[18];
  const float* w_t2s = (const float*)d_in[19];
  const float* t_off_w = (const float*)d_in[20];
  const float* t_off_b = (const float*)d_in[21];
  const float* t_dcn_w = (const float*)d_in[22];
  const float* t_dcn_b = (const float*)d_in[23];
  const float* s_off_w = (const float*)d_in[24];
  const float* s_off_b = (const float*)d_in[25];
  const float* s_dcn_w = (const float*)d_in[26];
  const float* s_dcn_b = (const float*)d_in[27];
  (void)in_sizes; (void)n_in; (void)out_size; (void)ws_size;

  constexpr int Bn = 16, C = 256;
  constexpr int HT = 15, WT = 15, NT = HT * WT;    // 225
  constexpr int HS = 31, WS2 = 31, NS = HS * WS2;  // 961
  constexpr int NpT = 256, NpS = 992;
  constexpr int NRT = 256, NRS = 1024;

  float* ws = (float*)d_ws;
  size_t off = 0;
  auto alloc = [&](size_t n) {
    n = (n + 3) & ~(size_t)3;
    float* p = ws + off; off += n; return p;
  };
  auto allocU = [&](size_t nu) { return (ushort*)alloc((nu + 1) / 2); };

  float* qk_t = alloc((size_t)Bn * 64 * NT);
  float* qk_s = alloc((size_t)Bn * 64 * NS);
  float* qkw_t = alloc((size_t)64 * C + 64);
  float* qkw_s = alloc((size_t)64 * C + 64);
  float* qkb_t = qkw_t + (size_t)64 * C;
  float* qkb_s = qkw_s + (size_t)64 * C;
  ushort* xT_t = allocU((size_t)Bn * NRT * C);
  ushort* xT_s = allocU((size_t)Bn * NRS * C);
  ushort* xbf_t = allocU((size_t)Bn * C * NpT);
  ushort* xbf_s = allocU((size_t)Bn * C * NpS);
  ushort* Wv_t = allocU((size_t)C * C);
  ushort* Wv_s = allocU((size_t)C * C);
  ushort* v_tbf = allocU((size_t)Bn * C * NpT);
  ushort* v_sbf = allocU((size_t)Bn * C * NpS);
  ushort* S_t = allocU((size_t)Bn * NT * NpT);
  ushort* S_s = allocU((size_t)Bn * NS * NpS);
  ushort* xsT_t = allocU((size_t)Bn * NRT * C);
  ushort* xsT_s = allocU((size_t)Bn * NRS * C);
  float* Atc = alloc((size_t)Bn * C * C);
  float* Asc = alloc((size_t)Bn * C * C);
  ushort* Mc_t = allocU((size_t)Bn * C * C);
  ushort* Mc_s = allocU((size_t)Bn * C * C);
  ushort* owb_t = allocU((size_t)32 * 2304);
  ushort* owb_s = allocU((size_t)32 * 2304);
  ushort* Awb_t = allocU((size_t)256 * 2304);
  ushort* Awb_s = allocU((size_t)256 * 2304);
  uint4* prep_t = (uint4*)alloc((size_t)Bn * 9 * NT * 4);
  uint4* prep_s = (uint4*)alloc((size_t)Bn * 9 * NS * 4);

  dim3 blk(256);

  // 1. fused weight prep (DCN weights -> fragment-major)
  prep_weights_kernel<<<dim3((1491072 + 255) / 256), blk, 0, stream>>>(
      t_qw, t_qb, t_kw, t_kb, s_qw, s_qb, s_kw, s_kb, t_vw, s_vw,
      t_off_w, s_off_w, t_dcn_w, s_dcn_w,
      qkw_t, qkb_t, qkw_s, qkb_s, Wv_t, Wv_s, owb_t, owb_s, Awb_t, Awb_s);

  // 2. fused q|k projections
  conv1x1_fused_kernel<<<dim3(320), blk, 0, stream>>>(
      s_in, qkw_s, qkb_s, qk_s, NS, t_in, qkw_t, qkb_t, qk_t, NT);

  // 3-4. fused casts
  cast_transpose_fused_kernel<<<dim3(1280), blk, 0, stream>>>(
      s_in, xT_s, NS, NRS, t_in, xT_t, NT, NRT);
  cast_pad_fused_kernel<<<dim3((Bn * C * NpS + Bn * C * NpT + 255) / 256), blk, 0, stream>>>(
      s_in, xbf_s, NS, NpS, Bn * C * NpS, t_in, xbf_t, NT, NpT, Bn * C * NpT);

  // 5. fused v projection (EPI=0)
  gemm_fused_kernel<0><<<dim3(640), blk, 0, stream>>>(
      Wv_s, 0, xT_s, s_vb, v_sbf, nullptr, NS, NpS, NRS, C,
      Wv_t, 0, xT_t, t_vb, v_tbf, nullptr, NT, NpT, NRT, C,
      512, 16, 4);

  // 6. fused energy
  energy_fused_kernel<<<dim3(4352), blk, 0, stream>>>(
      qk_s, S_s, NS, NpS, qk_t, S_t, NT, NpT);

  // 7. fused spatial softmax
  softmax_bf16_fused_kernel<<<dim3(Bn * NS + Bn * NT), blk, 0, stream>>>(
      S_s, NS, NpS, S_t, NT, NpT, Bn * NS);

  // 8. fused gram (EPI=2)
  gemm_fused_kernel<2><<<dim3(256), blk, 0, stream>>>(
      xbf_s, 1, xbf_s, nullptr, nullptr, Asc, C, C, C, NpS,
      xbf_t, 1, xbf_t, nullptr, nullptr, Atc, C, C, C, NpT,
      128, 4, 4);

  // 9. fused channel softmax + mcomb
  softmax_mcomb_kernel<<<dim3(Bn * C), blk, 0, stream>>>(
      Atc, Asc, w_t_ch, w_s2t, w_s_ch, w_t2s, Mc_t, Mc_s);

  // 10. merged PV + chan GEMM -> xsT
  pv_chan_fused_kernel<<<dim3(640), blk, 0, stream>>>(
      v_sbf, S_s, Mc_s, xT_s, s_in, s_g, xsT_s, NS, NpS, NRS,
      v_tbf, S_t, Mc_t, xT_t, t_in, t_g, xsT_t, NT, NpT, NRT);

  // 11. fused offconv + gather-table prep (om buffer eliminated)
  offconv_prep_fused_kernel<<<dim3(320), blk, 0, stream>>>(
      xsT_s, owb_s, s_off_b, prep_s, HS, WS2, NS, NRS,
      xsT_t, owb_t, t_off_b, prep_t, HT, WT, NT, NRT);

  // 12. fused DCN (r14 best config)
  float* out_t = (float*)d_out;
  float* out_s = out_t + (size_t)Bn * C * NT;
  dcn_fused_kernel<<<dim3(640), dim3(512), 0, stream>>>(
      xsT_s, prep_s, Awb_s, s_dcn_b, out_s, NS, WS2, NRS,
      xsT_t, prep_t, Awb_t, t_dcn_b, out_t, NT, WT, NRT);
}

// Round 18
// 339.333 us; speedup vs baseline: 1.0582x; 1.0275x over previous
//
#include <hip/hip_runtime.h>
#include <hip/hip_bf16.h>
#include <cmath>

typedef __attribute__((ext_vector_type(8))) short bf16x8;
typedef __attribute__((ext_vector_type(4))) float f32x4;

__device__ inline ushort f2bf(float f) {
  __hip_bfloat16 h = __float2bfloat16(f);
  return *reinterpret_cast<ushort*>(&h);
}
__device__ inline float bf2f(ushort u) {
  return __uint_as_float((uint)u << 16);
}
__device__ inline float bflo(uint x) { return __uint_as_float(x << 16); }
__device__ inline float bfhi(uint x) { return __uint_as_float(x & 0xffff0000u); }

// Fused-side decode with XCD-aware bijective chunking.
__device__ inline bool fdecode(int totalS, int gxS, int gyS, int gxT, int gyT,
                               int& bx, int& by, int& bz, bool& isT) {
  const int total = gridDim.x;
  const int id = blockIdx.x;
  int wid = (id & 7) * (total >> 3) + (id >> 3);
  const int totalT = gxT * gyT * 16;
  if (wid >= totalS + totalT) return false;
  isT = wid >= totalS;
  int lid = isT ? wid - totalS : wid;
  const int gx = isT ? gxT : gxS;
  const int gy = isT ? gyT : gyS;
  bx = lid % gx;
  lid /= gx;
  by = lid % gy;
  bz = lid / gy;
  return true;
}

// ---------------------------------------------------------------------------
// fused weight prep. DCN weights FRAGMENT-MAJOR:
// frag (mt,kt) = 16 rows x 32 k; elem (lane, j): o = mt*16+(lane&15),
// k = kt*32+(lane>>4)*8+j. dst = ((mt*72+kt)<<9) + lane*8 + j.
// ---------------------------------------------------------------------------
__global__ __launch_bounds__(256) void prep_weights_kernel(
    const float* __restrict__ t_qw, const float* __restrict__ t_qb,
    const float* __restrict__ t_kw, const float* __restrict__ t_kb,
    const float* __restrict__ s_qw, const float* __restrict__ s_qb,
    const float* __restrict__ s_kw, const float* __restrict__ s_kb,
    const float* __restrict__ t_vw, const float* __restrict__ s_vw,
    const float* __restrict__ t_off_w, const float* __restrict__ s_off_w,
    const float* __restrict__ t_dcn_w, const float* __restrict__ s_dcn_w,
    float* __restrict__ qkw_t, float* __restrict__ qkb_t,
    float* __restrict__ qkw_s, float* __restrict__ qkb_s,
    ushort* __restrict__ Wv_t, ushort* __restrict__ Wv_s,
    ushort* __restrict__ owb_t, ushort* __restrict__ owb_s,
    ushort* __restrict__ Awb_t, ushort* __restrict__ Awb_s) {
  int i = blockIdx.x * 256 + threadIdx.x;
  if (i < 16448) {
    if (i < 8192) qkw_t[i] = t_qw[i];
    else if (i < 16384) qkw_t[i] = t_kw[i - 8192];
    else { int j = i - 16384; qkb_t[j] = (j < 32) ? t_qb[j] : t_kb[j - 32]; }
    return;
  }
  i -= 16448;
  if (i < 16448) {
    if (i < 8192) qkw_s[i] = s_qw[i];
    else if (i < 16384) qkw_s[i] = s_kw[i - 8192];
    else { int j = i - 16384; qkb_s[j] = (j < 32) ? s_qb[j] : s_kb[j - 32]; }
    return;
  }
  i -= 16448;
  if (i < 65536) { Wv_t[i] = f2bf(t_vw[i]); return; }
  i -= 65536;
  if (i < 65536) { Wv_s[i] = f2bf(s_vw[i]); return; }
  i -= 65536;
  if (i < 73728) {
    const int o = i / 2304, k = i % 2304, tap = k >> 8, c = k & 255;
    owb_t[i] = (o < 27) ? f2bf(t_off_w[(size_t)o * 2304 + c * 9 + tap]) : (ushort)0;
    return;
  }
  i -= 73728;
  if (i < 73728) {
    const int o = i / 2304, k = i % 2304, tap = k >> 8, c = k & 255;
    owb_s[i] = (o < 27) ? f2bf(s_off_w[(size_t)o * 2304 + c * 9 + tap]) : (ushort)0;
    return;
  }
  i -= 73728;
  if (i < 589824) {
    const int frag = i >> 9, within = i & 511;
    const int lane = within >> 3, j = within & 7;
    const int mt = frag / 72, kt = frag % 72;
    const int o = mt * 16 + (lane & 15);
    const int k = kt * 32 + (lane >> 4) * 8 + j;
    const int tap = k >> 8, c = k & 255;
    Awb_t[i] = f2bf(t_dcn_w[(size_t)o * 2304 + c * 9 + tap]);
    return;
  }
  i -= 589824;
  if (i < 589824) {
    const int frag = i >> 9, within = i & 511;
    const int lane = within >> 3, j = within & 7;
    const int mt = frag / 72, kt = frag % 72;
    const int o = mt * 16 + (lane & 15);
    const int k = kt * 32 + (lane >> 4) * 8 + j;
    const int tap = k >> 8, c = k & 255;
    Awb_s[i] = f2bf(s_dcn_w[(size_t)o * 2304 + c * 9 + tap]);
  }
}

// ---------------------------------------------------------------------------
// fused conv1x1 (fp32) q|k projection, OC=64
// ---------------------------------------------------------------------------
__global__ __launch_bounds__(256) void conv1x1_fused_kernel(
    const float* __restrict__ xS, const float* __restrict__ wS,
    const float* __restrict__ bS, float* __restrict__ oS, int NS_,
    const float* __restrict__ xT, const float* __restrict__ wT,
    const float* __restrict__ bT, float* __restrict__ oT, int NT_) {
  constexpr int C = 256, OC = 64;
  __shared__ float As[64][17];
  __shared__ float Bs[16][64];
  int bx, by, bz; bool isT;
  if (!fdecode(256, 16, 1, 4, 1, bx, by, bz, isT)) return;
  const float* x = isT ? xT : xS;
  const float* w = isT ? wT : wS;
  const float* bias = isT ? bT : bS;
  float* out = isT ? oT : oS;
  const int N = isT ? NT_ : NS_;
  const int b = bz;
  const int n0 = bx * 64;
  const float* xb = x + (size_t)b * C * N;
  const int tid = threadIdx.x;
  const int tr = tid >> 4, tc = tid & 15;
  float acc[4][4] = {};
  for (int k0 = 0; k0 < C; k0 += 16) {
    for (int i = tid; i < 64 * 16; i += 256) {
      int m = i >> 4, kk = i & 15;
      As[m][kk] = w[(size_t)m * C + k0 + kk];
    }
    for (int i = tid; i < 16 * 64; i += 256) {
      int kk = i >> 6, n = i & 63;
      int gn = n0 + n;
      Bs[kk][n] = (gn < N) ? xb[(size_t)(k0 + kk) * N + gn] : 0.f;
    }
    __syncthreads();
#pragma unroll
    for (int kk = 0; kk < 16; ++kk) {
      float a[4], bb[4];
#pragma unroll
      for (int i = 0; i < 4; i++) a[i] = As[tr * 4 + i][kk];
#pragma unroll
      for (int j = 0; j < 4; j++) bb[j] = Bs[kk][tc * 4 + j];
#pragma unroll
      for (int i = 0; i < 4; i++)
#pragma unroll
        for (int j = 0; j < 4; j++) acc[i][j] += a[i] * bb[j];
    }
    __syncthreads();
  }
  for (int i = 0; i < 4; i++) {
    int gm = tr * 4 + i;
    if (gm >= OC) continue;
    float bv = bias[gm];
    for (int j = 0; j < 4; j++) {
      int gn = n0 + tc * 4 + j;
      if (gn < N) out[((size_t)b * OC + gm) * N + gn] = acc[i][j] + bv;
    }
  }
}

// ---------------------------------------------------------------------------
// fused cast+transpose+pad (r18): from one LDS tile emit BOTH
//   xT  bf16 [NR][C]  (transposed, rows >= N zeroed)
//   xbf bf16 [C][Np]  (same layout as input, cols >= N zeroed)
// Replaces the separate cast_pad kernel and its extra 25 MB read of x.
// ---------------------------------------------------------------------------
__global__ __launch_bounds__(256) void cast_transpose_fused_kernel(
    const float* __restrict__ xS, ushort* __restrict__ oS, ushort* __restrict__ pS,
    int NS_, int NRS_, int NpS_,
    const float* __restrict__ xT, ushort* __restrict__ oT, ushort* __restrict__ pT,
    int NT_, int NRT_, int NpT_) {
  constexpr int C = 256;
  __shared__ float T[64][65];
  int bx, by, bz; bool isT;
  if (!fdecode(1024, 16, 4, 4, 4, bx, by, bz, isT)) return;
  const float* x = isT ? xT : xS;
  ushort* xTo = isT ? oT : oS;
  ushort* xbf = isT ? pT : pS;
  const int N = isT ? NT_ : NS_;
  const int NR = isT ? NRT_ : NRS_;
  const int Np = isT ? NpT_ : NpS_;
  const int b = bz;
  const int n0 = bx * 64, c0 = by * 64;
  const float* xb = x + (size_t)b * C * N;
  const int tid = threadIdx.x;
  for (int u = tid; u < 4096; u += 256) {
    const int cc = u >> 6, nn = u & 63;
    const int gn = n0 + nn;
    T[cc][nn] = (gn < N) ? xb[(size_t)(c0 + cc) * N + gn] : 0.f;
  }
  __syncthreads();
  ushort* ob = xTo + (size_t)b * NR * C;
  for (int u = tid; u < 4096; u += 256) {
    const int nn = u >> 6, cc = u & 63;
    ob[(size_t)(n0 + nn) * C + c0 + cc] = f2bf(T[cc][nn]);
  }
  // non-transposed padded copy (coalesced over nn)
  ushort* pb = xbf + (size_t)b * C * Np;
  for (int u = tid; u < 4096; u += 256) {
    const int cc = u >> 6, nn = u & 63;
    const int gn = n0 + nn;
    if (gn < Np) pb[(size_t)(c0 + cc) * Np + gn] = f2bf(T[cc][nn]);
  }
}

// ---------------------------------------------------------------------------
// fused channel softmax + mcomb
// ---------------------------------------------------------------------------
__global__ __launch_bounds__(256) void softmax_mcomb_kernel(
    const float* __restrict__ Atc, const float* __restrict__ Asc,
    const float* __restrict__ w_t_ch, const float* __restrict__ w_s2t,
    const float* __restrict__ w_s_ch, const float* __restrict__ w_t2s,
    ushort* __restrict__ Mc_t, ushort* __restrict__ Mc_s) {
  const int row = blockIdx.x;
  const int tid = threadIdx.x;
  __shared__ float red[8];
  const size_t idx = (size_t)row * 256 + tid;
  const float a = -Atc[idx];
  const float s = -Asc[idx];
  float ma = a, ms = s;
#pragma unroll
  for (int off = 32; off; off >>= 1) {
    ma = fmaxf(ma, __shfl_xor(ma, off, 64));
    ms = fmaxf(ms, __shfl_xor(ms, off, 64));
  }
  if ((tid & 63) == 0) { red[tid >> 6] = ma; red[4 + (tid >> 6)] = ms; }
  __syncthreads();
  if (tid == 0) {
    float m1 = red[0], m2 = red[4];
    for (int i = 1; i < 4; i++) { m1 = fmaxf(m1, red[i]); m2 = fmaxf(m2, red[4 + i]); }
    red[0] = m1; red[4] = m2;
  }
  __syncthreads();
  ma = red[0]; ms = red[4];
  __syncthreads();
  const float ea = __expf(a - ma), es = __expf(s - ms);
  float sa = ea, ss = es;
#pragma unroll
  for (int off = 32; off; off >>= 1) {
    sa += __shfl_xor(sa, off, 64);
    ss += __shfl_xor(ss, off, 64);
  }
  if ((tid & 63) == 0) { red[tid >> 6] = sa; red[4 + (tid >> 6)] = ss; }
  __syncthreads();
  if (tid == 0) {
    float t1 = 0.f, t2 = 0.f;
    for (int i = 0; i < 4; i++) { t1 += red[i]; t2 += red[4 + i]; }
    red[0] = t1; red[4] = t2;
  }
  __syncthreads();
  const float Pa = ea / red[0], Ps = es / red[4];
  Mc_t[idx] = f2bf(w_t_ch[0] * Pa + w_s2t[0] * Ps);
  Mc_s[idx] = f2bf(w_s_ch[0] * Ps + w_t2s[0] * Pa);
}

// ---------------------------------------------------------------------------
// fused generic bf16 GEMM, BM=128, NW=4.
// EPI 0: outBf = bf16(acc+bias) padded   EPI 2: outF = acc
// ---------------------------------------------------------------------------
template <int EPI>
__global__ __launch_bounds__(256) void gemm_fused_kernel(
    const ushort* __restrict__ AS, int aPerB_S, const ushort* __restrict__ BtS,
    const float* __restrict__ biasS, ushort* __restrict__ outBfS,
    float* __restrict__ outFS, int NS_, int NpS_, int NRS_, int KpS_,
    const ushort* __restrict__ AT, int aPerB_T, const ushort* __restrict__ BtT,
    const float* __restrict__ biasT, ushort* __restrict__ outBfT,
    float* __restrict__ outFT, int NT_, int NpT_, int NRT_, int KpT_,
    int totalS, int gxS, int gxT) {
  constexpr int CM = 256, BM = 128, NW = 4, NF = 2, WN = 2;
  __shared__ ushort Asm[BM][40];
  __shared__ ushort Bsm[64][40];
  int bx, by, bz; bool isT;
  if (!fdecode(totalS, gxS, 2, gxT, 2, bx, by, bz, isT)) return;
  const ushort* A = isT ? AT : AS;
  const ushort* Bt = isT ? BtT : BtS;
  const float* bias = isT ? biasT : biasS;
  ushort* outBf = isT ? outBfT : outBfS;
  float* outF = isT ? outFT : outFS;
  const int aPerBatch = isT ? aPerB_T : aPerB_S;
  const int N = isT ? NT_ : NS_, Np = isT ? NpT_ : NpS_;
  const int NR = isT ? NRT_ : NRS_, Kp = isT ? KpT_ : KpS_;
  const int n0 = bx * 64, m0 = by * BM, b = bz;
  const ushort* Ab = A + (size_t)(aPerBatch ? b : 0) * CM * Kp;
  const ushort* Bb = Bt + (size_t)b * NR * Kp;
  const int tid = threadIdx.x, lane = tid & 63, w = tid >> 6;
  const int wr = w / WN, wc = w % WN;
  f32x4 acc[4][NF];
#pragma unroll
  for (int i = 0; i < 4; i++)
#pragma unroll
    for (int j = 0; j < NF; j++) acc[i][j] = (f32x4){0.f, 0.f, 0.f, 0.f};
  for (int k0 = 0; k0 < Kp; k0 += 32) {
    for (int u = tid; u < BM * 4; u += NW * 64) {
      const int row = u >> 2, seg = u & 3;
      *reinterpret_cast<uint4*>(&Asm[row][seg * 8]) =
          *reinterpret_cast<const uint4*>(&Ab[(size_t)(m0 + row) * Kp + k0 + seg * 8]);
    }
    for (int u = tid; u < 64 * 4; u += NW * 64) {
      const int row = u >> 2, seg = u & 3;
      *reinterpret_cast<uint4*>(&Bsm[row][seg * 8]) =
          *reinterpret_cast<const uint4*>(&Bb[(size_t)(n0 + row) * Kp + k0 + seg * 8]);
    }
    __syncthreads();
    const int koff = (lane >> 4) * 8;
    bf16x8 af[4], bfr[NF];
#pragma unroll
    for (int mf = 0; mf < 4; mf++)
      af[mf] = *reinterpret_cast<const bf16x8*>(&Asm[wr * 64 + mf * 16 + (lane & 15)][koff]);
#pragma unroll
    for (int nf = 0; nf < NF; nf++)
      bfr[nf] = *reinterpret_cast<const bf16x8*>(&Bsm[wc * NF * 16 + nf * 16 + (lane & 15)][koff]);
#pragma unroll
    for (int mf = 0; mf < 4; mf++)
#pragma unroll
      for (int nf = 0; nf < NF; nf++)
        acc[mf][nf] = __builtin_amdgcn_mfma_f32_16x16x32_bf16(af[mf], bfr[nf], acc[mf][nf], 0, 0, 0);
    __syncthreads();
  }
#pragma unroll
  for (int mf = 0; mf < 4; mf++) {
    const int mbase = m0 + wr * 64 + mf * 16 + ((lane >> 4) * 4);
#pragma unroll
    for (int nf = 0; nf < NF; nf++) {
      const int gn = n0 + wc * NF * 16 + nf * 16 + (lane & 15);
      if (EPI == 0) {
#pragma unroll
        for (int rr = 0; rr < 4; rr++) {
          const int m = mbase + rr;
          if (gn < Np) {
            ushort v = (gn < N) ? f2bf(acc[mf][nf][rr] + bias[m]) : (ushort)0;
            outBf[((size_t)b * CM + m) * Np + gn] = v;
          }
        }
      } else {
#pragma unroll
        for (int rr = 0; rr < 4; rr++) {
          if (gn < N)
            outF[((size_t)b * CM + mbase + rr) * N + gn] = acc[mf][nf][rr];
        }
      }
    }
  }
  (void)NR;
}

// ---------------------------------------------------------------------------
// fused energy (K=32)
// ---------------------------------------------------------------------------
__global__ __launch_bounds__(256) void energy_fused_kernel(
    const float* __restrict__ qkS, ushort* __restrict__ SS, int NS_, int NpS_,
    const float* __restrict__ qkT, ushort* __restrict__ ST, int NT_, int NpT_) {
  __shared__ ushort Aq[64][40];
  __shared__ ushort Bk[64][40];
  int bx, by, bz; bool isT;
  if (!fdecode(4096, 16, 16, 4, 4, bx, by, bz, isT)) return;
  const float* qk = isT ? qkT : qkS;
  ushort* Sbf = isT ? ST : SS;
  const int N = isT ? NT_ : NS_, Np = isT ? NpT_ : NpS_;
  const int m0 = bx * 64, n0 = by * 64, b = bz;
  const float* qb = qk + (size_t)b * 64 * N;
  const float* kb = qb + (size_t)32 * N;
  const int tid = threadIdx.x, lane = tid & 63, w = tid >> 6;
  for (int u = tid; u < 2048; u += 256) {
    const int c = u >> 6, nn = u & 63;
    const int gn = n0 + nn, gm = m0 + nn;
    Aq[nn][c] = (gn < N) ? f2bf(qb[(size_t)c * N + gn]) : (ushort)0;
    Bk[nn][c] = (gm < N) ? f2bf(kb[(size_t)c * N + gm]) : (ushort)0;
  }
  __syncthreads();
  const int koff = (lane >> 4) * 8;
  const bf16x8 af = *reinterpret_cast<const bf16x8*>(&Aq[w * 16 + (lane & 15)][koff]);
  f32x4 acc[4];
#pragma unroll
  for (int j = 0; j < 4; j++) {
    const bf16x8 bf = *reinterpret_cast<const bf16x8*>(&Bk[j * 16 + (lane & 15)][koff]);
    acc[j] = __builtin_amdgcn_mfma_f32_16x16x32_bf16(af, bf, (f32x4){0.f, 0.f, 0.f, 0.f}, 0, 0, 0);
  }
#pragma unroll
  for (int j = 0; j < 4; j++) {
    const int m = m0 + j * 16 + (lane & 15);
    if (m >= Np) continue;
#pragma unroll
    for (int r = 0; r < 4; r++) {
      const int n = n0 + w * 16 + (lane >> 4) * 4 + r;
      if (n < N) Sbf[((size_t)b * N + n) * Np + m] = (m < N) ? f2bf(acc[j][r]) : (ushort)0;
    }
  }
}

// ---------------------------------------------------------------------------
// fused bf16 row softmax (spatial scores)
// ---------------------------------------------------------------------------
__global__ __launch_bounds__(256) void softmax_bf16_fused_kernel(
    ushort* __restrict__ Ss, int Ns, int Nps, ushort* __restrict__ St, int Nt,
    int Npt, int rowsS) {
  __shared__ float buf[992];
  __shared__ float red[4];
  const int row = blockIdx.x;
  ushort* r;
  int N;
  if (row < rowsS) {
    r = Ss + (size_t)row * Nps;
    N = Ns;
  } else {
    r = St + (size_t)(row - rowsS) * Npt;
    N = Nt;
  }
  const int tid = threadIdx.x;
  float mx = -1e30f;
  for (int i = tid; i < N; i += 256) {
    float f = bf2f(r[i]);
    buf[i] = f;
    mx = fmaxf(mx, f);
  }
#pragma unroll
  for (int off = 32; off; off >>= 1) mx = fmaxf(mx, __shfl_xor(mx, off, 64));
  if ((tid & 63) == 0) red[tid >> 6] = mx;
  __syncthreads();
  if (tid == 0) {
    float m2 = red[0];
    for (int i = 1; i < 4; i++) m2 = fmaxf(m2, red[i]);
    red[0] = m2;
  }
  __syncthreads();
  mx = red[0];
  __syncthreads();
  float s = 0.f;
  for (int i = tid; i < N; i += 256) {
    float v = __expf(buf[i] - mx);
    buf[i] = v;
    s += v;
  }
#pragma unroll
  for (int off = 32; off; off >>= 1) s += __shfl_xor(s, off, 64);
  if ((tid & 63) == 0) red[tid >> 6] = s;
  __syncthreads();
  if (tid == 0) {
    float t = 0.f;
    for (int i = 0; i < 4; i++) t += red[i];
    red[0] = t;
  }
  __syncthreads();
  const float inv = 1.f / red[0];
  for (int i = tid; i < N; i += 256) r[i] = f2bf(buf[i] * inv);
}

// ---------------------------------------------------------------------------
// fused PV+CHAN merged GEMM (BM=128): acc = PV(v@S^T); acc *= g;
// acc += Mc@xT; out_xsT = bf16(x + acc).
// ---------------------------------------------------------------------------
__global__ __launch_bounds__(256) void pv_chan_fused_kernel(
    const ushort* __restrict__ vS, const ushort* __restrict__ SS,
    const ushort* __restrict__ McS, const ushort* __restrict__ xTS,
    const float* __restrict__ xS, const float* __restrict__ gS,
    ushort* __restrict__ xsTS, int NS_, int NpS_, int NRS_,
    const ushort* __restrict__ vT, const ushort* __restrict__ ST,
    const ushort* __restrict__ McT, const ushort* __restrict__ xTT,
    const float* __restrict__ xT_, const float* __restrict__ gT,
    ushort* __restrict__ xsTT, int NT_, int NpT_, int NRT_) {
  constexpr int C = 256, BM = 128, NW = 4, NF = 2, WN = 2;
  __shared__ ushort Asm[BM][40];
  __shared__ ushort Bsm[64][40];
  int bx, by, bz; bool isT;
  if (!fdecode(512, 16, 2, 4, 2, bx, by, bz, isT)) return;
  const ushort* vbf = isT ? vT : vS;
  const ushort* Sbf = isT ? ST : SS;
  const ushort* Mc = isT ? McT : McS;
  const ushort* xTb = isT ? xTT : xTS;
  const float* x = isT ? xT_ : xS;
  const float* gp = isT ? gT : gS;
  ushort* xsT = isT ? xsTT : xsTS;
  const int N = isT ? NT_ : NS_, Np = isT ? NpT_ : NpS_;
  const int NR = isT ? NRT_ : NRS_;
  const int n0 = bx * 64, m0 = by * BM, b = bz;
  const int tid = threadIdx.x, lane = tid & 63, w = tid >> 6;
  const int wr = w / WN, wc = w % WN;
  f32x4 acc[4][NF];
#pragma unroll
  for (int i = 0; i < 4; i++)
#pragma unroll
    for (int j = 0; j < NF; j++) acc[i][j] = (f32x4){0.f, 0.f, 0.f, 0.f};
  const int koff = (lane >> 4) * 8;
  // phase 1: PV, K = Np
  {
    const ushort* Ab = vbf + (size_t)b * C * Np;
    const ushort* Bb = Sbf + (size_t)b * (size_t)N * Np;
    for (int k0 = 0; k0 < Np; k0 += 32) {
      for (int u = tid; u < BM * 4; u += NW * 64) {
        const int row = u >> 2, seg = u & 3;
        *reinterpret_cast<uint4*>(&Asm[row][seg * 8]) =
            *reinterpret_cast<const uint4*>(&Ab[(size_t)(m0 + row) * Np + k0 + seg * 8]);
      }
      for (int u = tid; u < 64 * 4; u += NW * 64) {
        const int row = u >> 2, seg = u & 3;
        const int gn = n0 + row;
        uint4 val;
        if (gn < N)
          val = *reinterpret_cast<const uint4*>(&Bb[(size_t)gn * Np + k0 + seg * 8]);
        else
          val = make_uint4(0, 0, 0, 0);
        *reinterpret_cast<uint4*>(&Bsm[row][seg * 8]) = val;
      }
      __syncthreads();
      bf16x8 af[4], bfr[NF];
#pragma unroll
      for (int mf = 0; mf < 4; mf++)
        af[mf] = *reinterpret_cast<const bf16x8*>(&Asm[wr * 64 + mf * 16 + (lane & 15)][koff]);
#pragma unroll
      for (int nf = 0; nf < NF; nf++)
        bfr[nf] = *reinterpret_cast<const bf16x8*>(&Bsm[wc * NF * 16 + nf * 16 + (lane & 15)][koff]);
#pragma unroll
      for (int mf = 0; mf < 4; mf++)
#pragma unroll
        for (int nf = 0; nf < NF; nf++)
          acc[mf][nf] = __builtin_amdgcn_mfma_f32_16x16x32_bf16(af[mf], bfr[nf], acc[mf][nf], 0, 0, 0);
      __syncthreads();
    }
  }
  const float g = *gp;
#pragma unroll
  for (int mf = 0; mf < 4; mf++)
#pragma unroll
    for (int nf = 0; nf < NF; nf++)
#pragma unroll
      for (int rr = 0; rr < 4; rr++) acc[mf][nf][rr] *= g;
  // phase 2: chan, K = C
  {
    const ushort* Ab = Mc + (size_t)b * C * C;
    const ushort* Bb = xTb + (size_t)b * NR * C;
    for (int k0 = 0; k0 < C; k0 += 32) {
      for (int u = tid; u < BM * 4; u += NW * 64) {
        const int row = u >> 2, seg = u & 3;
        *reinterpret_cast<uint4*>(&Asm[row][seg * 8]) =
            *reinterpret_cast<const uint4*>(&Ab[(size_t)(m0 + row) * C + k0 + seg * 8]);
      }
      for (int u = tid; u < 64 * 4; u += NW * 64) {
        const int row = u >> 2, seg = u & 3;
        *reinterpret_cast<uint4*>(&Bsm[row][seg * 8]) =
            *reinterpret_cast<const uint4*>(&Bb[(size_t)(n0 + row) * C + k0 + seg * 8]);
      }
      __syncthreads();
      bf16x8 af[4], bfr[NF];
#pragma unroll
      for (int mf = 0; mf < 4; mf++)
        af[mf] = *reinterpret_cast<const bf16x8*>(&Asm[wr * 64 + mf * 16 + (lane & 15)][koff]);
#pragma unroll
      for (int nf = 0; nf < NF; nf++)
        bfr[nf] = *reinterpret_cast<const bf16x8*>(&Bsm[wc * NF * 16 + nf * 16 + (lane & 15)][koff]);
#pragma unroll
      for (int mf = 0; mf < 4; mf++)
#pragma unroll
        for (int nf = 0; nf < NF; nf++)
          acc[mf][nf] = __builtin_amdgcn_mfma_f32_16x16x32_bf16(af[mf], bfr[nf], acc[mf][nf], 0, 0, 0);
      __syncthreads();
    }
  }
#pragma unroll
  for (int mf = 0; mf < 4; mf++) {
    const int mbase = m0 + wr * 64 + mf * 16 + ((lane >> 4) * 4);
#pragma unroll
    for (int nf = 0; nf < NF; nf++) {
      const int gn = n0 + wc * NF * 16 + nf * 16 + (lane & 15);
      if (gn < N) {
        float s[4];
#pragma unroll
        for (int rr = 0; rr < 4; rr++)
          s[rr] = x[((size_t)b * C + mbase + rr) * N + gn] + acc[mf][nf][rr];
        uint lo = (uint)f2bf(s[0]) | ((uint)f2bf(s[1]) << 16);
        uint hi = (uint)f2bf(s[2]) | ((uint)f2bf(s[3]) << 16);
        *reinterpret_cast<uint2*>(&xsT[((size_t)b * NR + gn) * C + mbase]) =
            make_uint2(lo, hi);
      }
    }
  }
}

// ---------------------------------------------------------------------------
// fused offconv via MFMA on xsT, WITH FUSED gather-table prep:
// the block holds all 27 om channels for its 64-position tile; epilogue
// stages them through LDS and computes the 9 prep entries per position.
// ---------------------------------------------------------------------------
__global__ __launch_bounds__(256) void offconv_prep_fused_kernel(
    const ushort* __restrict__ xS, const ushort* __restrict__ owS,
    const float* __restrict__ obS, uint4* __restrict__ prS, int HS_, int WS_,
    int NS_, int NRS_,
    const ushort* __restrict__ xT, const ushort* __restrict__ owT,
    const float* __restrict__ obT, uint4* __restrict__ prT, int HT_, int WT_,
    int NT_, int NRT_) {
  __shared__ ushort Asm[32][136];
  __shared__ ushort Bsm[64][136];
  __shared__ int qsrc[64];
  __shared__ float som[27][65];
  int bx, by, bz; bool isT;
  if (!fdecode(256, 16, 1, 4, 1, bx, by, bz, isT)) return;
  const ushort* xsT = isT ? xT : xS;
  const ushort* owb = isT ? owT : owS;
  const float* ob = isT ? obT : obS;
  uint4* prep = isT ? prT : prS;
  const int H = isT ? HT_ : HS_, Wd = isT ? WT_ : WS_;
  const int N = isT ? NT_ : NS_, NR = isT ? NRT_ : NRS_;
  const int n0 = bx * 64, b = bz;
  const int tid = threadIdx.x, lane = tid & 63, w = tid >> 6;
  const ushort* xb = xsT + (size_t)b * NR * 256;
  f32x4 acc[2];
  acc[0] = (f32x4){0.f, 0.f, 0.f, 0.f};
  acc[1] = (f32x4){0.f, 0.f, 0.f, 0.f};
  for (int tap = 0; tap < 9; ++tap) {
    const int dy = tap / 3 - 1, dx = tap - (tap / 3) * 3 - 1;
    if (tid < 64) {
      const int p = n0 + tid;
      int q = -1;
      if (p < N) {
        const int h = p / Wd, ww = p - (p / Wd) * Wd;
        const int yy = h + dy, xx = ww + dx;
        if (yy >= 0 && yy < H && xx >= 0 && xx < Wd) q = yy * Wd + xx;
      }
      qsrc[tid] = q;
    }
    __syncthreads();
#pragma unroll
    for (int half = 0; half < 2; ++half) {
      const int k0 = tap * 256 + half * 128;
      for (int u = tid; u < 512; u += 256) {
        const int row = u >> 4, seg = u & 15;
        *reinterpret_cast<uint4*>(&Asm[row][seg * 8]) =
            *reinterpret_cast<const uint4*>(&owb[(size_t)row * 2304 + k0 + seg * 8]);
      }
      for (int u = tid; u < 1024; u += 256) {
        const int row = u >> 4, seg = u & 15;
        const int q = qsrc[row];
        uint4 val = make_uint4(0, 0, 0, 0);
        if (q >= 0)
          val = *reinterpret_cast<const uint4*>(&xb[(size_t)q * 256 + half * 128 + seg * 8]);
        *reinterpret_cast<uint4*>(&Bsm[row][seg * 8]) = val;
      }
      __syncthreads();
#pragma unroll
      for (int sub = 0; sub < 4; ++sub) {
        const int koff = sub * 32 + (lane >> 4) * 8;
        const bf16x8 b0 = *reinterpret_cast<const bf16x8*>(&Bsm[w * 16 + (lane & 15)][koff]);
#pragma unroll
        for (int mf = 0; mf < 2; ++mf) {
          const bf16x8 a0 = *reinterpret_cast<const bf16x8*>(&Asm[mf * 16 + (lane & 15)][koff]);
          acc[mf] = __builtin_amdgcn_mfma_f32_16x16x32_bf16(a0, b0, acc[mf], 0, 0, 0);
        }
      }
      __syncthreads();
    }
  }
  // stage om tile to LDS: som[o][p-local]
#pragma unroll
  for (int mf = 0; mf < 2; ++mf) {
#pragma unroll
    for (int r = 0; r < 4; ++r) {
      const int o = mf * 16 + (lane >> 4) * 4 + r;
      const int n = w * 16 + (lane & 15);
      if (o < 27) som[o][n] = acc[mf][r] + ob[o];
    }
  }
  __syncthreads();
  // fused prep: 9 taps x 64 positions = 576 work items
  for (int u = tid; u < 576; u += 256) {
    const int tap = u / 64, pp = u - (u / 64) * 64;
    const int p = n0 + pp;
    if (p >= N) continue;
    const float offy = som[tap][pp];
    const float offx = som[9 + tap][pp];
    const float mraw = som[18 + tap][pp];
    const float mval = 1.f / (1.f + __expf(-mraw));
    const int ky = tap / 3, kx = tap - (tap / 3) * 3;
    const int h = p / Wd, ww = p - (p / Wd) * Wd;
    const float py = offy + (float)(h + ky - 1);
    const float px = offx + (float)(ww + kx - 1);
    const float y0f = floorf(py), x0f = floorf(px);
    const float wy = py - y0f, wx = px - x0f;
    const int y0 = (int)y0f, x0 = (int)x0f;
    const int ys0 = min(max(y0, 0), H - 2);
    const int xs0 = min(max(x0, 0), Wd - 2);
    const float wr0 = (ys0 == y0) ? (1.f - wy) : ((ys0 == y0 + 1) ? wy : 0.f);
    const float wr1 = (ys0 + 1 == y0) ? (1.f - wy) : ((ys0 + 1 == y0 + 1) ? wy : 0.f);
    const float wc0 = (xs0 == x0) ? (1.f - wx) : ((xs0 == x0 + 1) ? wx : 0.f);
    const float wc1 = (xs0 + 1 == x0) ? (1.f - wx) : ((xs0 + 1 == x0 + 1) ? wx : 0.f);
    const float w00 = wr0 * wc0 * mval, w01 = wr0 * wc1 * mval;
    const float w10 = wr1 * wc0 * mval, w11 = wr1 * wc1 * mval;
    uint4 pk;
    pk.x = (uint)(ys0 * Wd + xs0);
    pk.y = (uint)f2bf(w00) | ((uint)f2bf(w01) << 16);
    pk.z = (uint)f2bf(w10) | ((uint)f2bf(w11) << 16);
    pk.w = 0;
    prep[((size_t)b * 9 + tap) * N + p] = pk;
  }
}

// ---------------------------------------------------------------------------
// fused DCN via MFMA (r14 best config: fragment-major register A, no LDS for
// A; single Bsm buffer; B-corner register prefetch; 2 barriers/step).
// BM=256, BK=64, BN=32, 512 thr. s gx=32, t gx=8; gy=1.
// ---------------------------------------------------------------------------
__global__ __launch_bounds__(512) void dcn_fused_kernel(
    const ushort* __restrict__ xS, const uint4* __restrict__ prS,
    const ushort* __restrict__ AwS, const float* __restrict__ biS,
    float* __restrict__ oS, int NS_, int WS_, int NRS_,
    const ushort* __restrict__ xT, const uint4* __restrict__ prT,
    const ushort* __restrict__ AwT, const float* __restrict__ biT,
    float* __restrict__ oT, int NT_, int WT_, int NRT_) {
  constexpr int C = 256, MF = 4;
  __shared__ ushort Bsm[32][72];
  __shared__ int sq[32];
  __shared__ float swl[4][32];
  int bx, by, bz; bool isT;
  if (!fdecode(512, 32, 1, 8, 1, bx, by, bz, isT)) return;
  const ushort* xsT = isT ? xT : xS;
  const uint4* prep = isT ? prT : prS;
  const ushort* Awb = isT ? AwT : AwS;
  const float* bias = isT ? biT : biS;
  float* out = isT ? oT : oS;
  const int N = isT ? NT_ : NS_, Wd = isT ? WT_ : WS_, NR = isT ? NRT_ : NRS_;
  const int n0 = bx * 32, b = bz;
  const int tid = threadIdx.x, lane = tid & 63, w = tid >> 6;
  const int wr = w >> 1, wc = w & 1;
  const ushort* xb = xsT + (size_t)b * NR * C;
  const int un0 = tid >> 5;
  const int un1 = un0 + 16;
  const int kk2 = (tid & 31) * 2;
  f32x4 acc[MF];
#pragma unroll
  for (int i = 0; i < MF; i++) acc[i] = (f32x4){0.f, 0.f, 0.f, 0.f};
  uint bReg[2][4];
  int sqr0 = 0, sqr1 = 0;
  float w0a[4], w1a[4];
  const size_t rowYp = (size_t)Wd * C;
  for (int tap = 0; tap < 9; ++tap) {
    if (tid < 32) {
      const int p = n0 + tid;
      if (p < N) {
        const uint4 pk = prep[((size_t)b * 9 + tap) * N + p];
        sq[tid] = (int)pk.x * C;
        swl[0][tid] = bf2f((ushort)(pk.y & 0xffff));
        swl[1][tid] = bf2f((ushort)(pk.y >> 16));
        swl[2][tid] = bf2f((ushort)(pk.z & 0xffff));
        swl[3][tid] = bf2f((ushort)(pk.z >> 16));
      } else {
        sq[tid] = 0;
        swl[0][tid] = swl[1][tid] = swl[2][tid] = swl[3][tid] = 0.f;
      }
    }
    __syncthreads();
    sqr0 = sq[un0];
    sqr1 = sq[un1];
#pragma unroll
    for (int q = 0; q < 4; q++) {
      w0a[q] = swl[q][un0];
      w1a[q] = swl[q][un1];
    }
    // prefetch B corners for ks=0
    {
      const ushort* pA = xb + sqr0 + kk2;
      bReg[0][0] = *reinterpret_cast<const uint*>(pA);
      bReg[0][1] = *reinterpret_cast<const uint*>(pA + C);
      bReg[0][2] = *reinterpret_cast<const uint*>(pA + rowYp);
      bReg[0][3] = *reinterpret_cast<const uint*>(pA + rowYp + C);
      const ushort* pB = xb + sqr1 + kk2;
      bReg[1][0] = *reinterpret_cast<const uint*>(pB);
      bReg[1][1] = *reinterpret_cast<const uint*>(pB + C);
      bReg[1][2] = *reinterpret_cast<const uint*>(pB + rowYp);
      bReg[1][3] = *reinterpret_cast<const uint*>(pB + rowYp + C);
    }
#pragma unroll
    for (int ks = 0; ks < 4; ++ks) {
      // A fragments for this step: direct global->register, fragment-major
      bf16x8 afr[2][4];
      const int ktb = tap * 8 + ks * 2;
#pragma unroll
      for (int sub = 0; sub < 2; ++sub)
#pragma unroll
        for (int mf = 0; mf < 4; ++mf)
          afr[sub][mf] = *reinterpret_cast<const bf16x8*>(
              Awb + ((((size_t)(wr * 4 + mf) * 72) + ktb + sub) << 9) + lane * 8);
      // B-stage: pack prefetched corners to LDS
      {
        const float vlo0 = w0a[0] * bflo(bReg[0][0]) + w0a[1] * bflo(bReg[0][1]) +
                           w0a[2] * bflo(bReg[0][2]) + w0a[3] * bflo(bReg[0][3]);
        const float vhi0 = w0a[0] * bfhi(bReg[0][0]) + w0a[1] * bfhi(bReg[0][1]) +
                           w0a[2] * bfhi(bReg[0][2]) + w0a[3] * bfhi(bReg[0][3]);
        *reinterpret_cast<uint*>(&Bsm[un0][kk2]) =
            (uint)f2bf(vlo0) | ((uint)f2bf(vhi0) << 16);
        const float vlo1 = w1a[0] * bflo(bReg[1][0]) + w1a[1] * bflo(bReg[1][1]) +
                           w1a[2] * bflo(bReg[1][2]) + w1a[3] * bflo(bReg[1][3]);
        const float vhi1 = w1a[0] * bfhi(bReg[1][0]) + w1a[1] * bfhi(bReg[1][1]) +
                           w1a[2] * bfhi(bReg[1][2]) + w1a[3] * bfhi(bReg[1][3]);
        *reinterpret_cast<uint*>(&Bsm[un1][kk2]) =
            (uint)f2bf(vlo1) | ((uint)f2bf(vhi1) << 16);
      }
      __syncthreads();
      // prefetch next ks B corners (overlaps MFMA)
      if (ks < 3) {
        const int c1 = (ks + 1) * 64;
        const ushort* pA = xb + sqr0 + c1 + kk2;
        bReg[0][0] = *reinterpret_cast<const uint*>(pA);
        bReg[0][1] = *reinterpret_cast<const uint*>(pA + C);
        bReg[0][2] = *reinterpret_cast<const uint*>(pA + rowYp);
        bReg[0][3] = *reinterpret_cast<const uint*>(pA + rowYp + C);
        const ushort* pB = xb + sqr1 + c1 + kk2;
        bReg[1][0] = *reinterpret_cast<const uint*>(pB);
        bReg[1][1] = *reinterpret_cast<const uint*>(pB + C);
        bReg[1][2] = *reinterpret_cast<const uint*>(pB + rowYp);
        bReg[1][3] = *reinterpret_cast<const uint*>(pB + rowYp + C);
      }
#pragma unroll
      for (int sub = 0; sub < 2; ++sub) {
        const int koff = sub * 32 + (lane >> 4) * 8;
        const bf16x8 bfv = *reinterpret_cast<const bf16x8*>(&Bsm[wc * 16 + (lane & 15)][koff]);
#pragma unroll
        for (int mf = 0; mf < MF; mf++)
          acc[mf] = __builtin_amdgcn_mfma_f32_16x16x32_bf16(afr[sub][mf], bfv, acc[mf], 0, 0, 0);
      }
      __syncthreads();
    }
  }
  const int gn = n0 + wc * 16 + (lane & 15);
#pragma unroll
  for (int mf = 0; mf < MF; mf++) {
    const int mbase = wr * 64 + mf * 16 + ((lane >> 4) * 4);
    if (gn < N) {
#pragma unroll
      for (int rr = 0; rr < 4; rr++)
        out[((size_t)b * C + mbase + rr) * N + gn] = acc[mf][rr] + bias[mbase + rr];
    }
  }
}

// ---------------------------------------------------------------------------
extern "C" void kernel_launch(void* const* d_in, const int* in_sizes, int n_in,
                              void* d_out, int out_size, void* d_ws, size_t ws_size,
                              hipStream_t stream) {
  const float* t_in = (const float*)d_in[0];
  const float* s_in = (const float*)d_in[1];
  const float* t_qw = (const float*)d_in[2];
  const float* t_qb = (const float*)d_in[3];
  const float* t_kw = (const float*)d_in[4];
  const float* t_kb = (const float*)d_in[5];
  const float* t_vw = (const float*)d_in[6];
  const float* t_vb = (const float*)d_in[7];
  const float* t_g = (const float*)d_in[8];
  const float* s_qw = (const float*)d_in[9];
  const float* s_qb = (const float*)d_in[10];
  const float* s_kw = (const float*)d_in[11];
  const float* s_kb = (const float*)d_in[12];
  const float* s_vw = (const float*)d_in[13];
  const float* s_vb = (const float*)d_in[14];
  const float* s_g = (const float*)d_in[15];
  const float* w_t_ch = (const float*)d_in[16];
  const float* w_s_ch = (const float*)d_in[17];
  const float* w_s2t = (const float*)d_in[18];
  const float* w_t2s = (const float*)d_in[19];
  const float* t_off_w = (const float*)d_in[20];
  const float* t_off_b = (const float*)d_in[21];
  const float* t_dcn_w = (const float*)d_in[22];
  const float* t_dcn_b = (const float*)d_in[23];
  const float* s_off_w = (const float*)d_in[24];
  const float* s_off_b = (const float*)d_in[25];
  const float* s_dcn_w = (const float*)d_in[26];
  const float* s_dcn_b = (const float*)d_in[27];
  (void)in_sizes; (void)n_in; (void)out_size; (void)ws_size;

  constexpr int Bn = 16, C = 256;
  constexpr int HT = 15, WT = 15, NT = HT * WT;    // 225
  constexpr int HS = 31, WS2 = 31, NS = HS * WS2;  // 961
  constexpr int NpT = 256, NpS = 992;
  constexpr int NRT = 256, NRS = 1024;

  float* ws = (float*)d_ws;
  size_t off = 0;
  auto alloc = [&](size_t n) {
    n = (n + 3) & ~(size_t)3;
    float* p = ws + off; off += n; return p;
  };
  auto allocU = [&](size_t nu) { return (ushort*)alloc((nu + 1) / 2); };

  float* qk_t = alloc((size_t)Bn * 64 * NT);
  float* qk_s = alloc((size_t)Bn * 64 * NS);
  float* qkw_t = alloc((size_t)64 * C + 64);
  float* qkw_s = alloc((size_t)64 * C + 64);
  float* qkb_t = qkw_t + (size_t)64 * C;
  float* qkb_s = qkw_s + (size_t)64 * C;
  ushort* xT_t = allocU((size_t)Bn * NRT * C);
  ushort* xT_s = allocU((size_t)Bn * NRS * C);
  ushort* xbf_t = allocU((size_t)Bn * C * NpT);
  ushort* xbf_s = allocU((size_t)Bn * C * NpS);
  ushort* Wv_t = allocU((size_t)C * C);
  ushort* Wv_s = allocU((size_t)C * C);
  ushort* v_tbf = allocU((size_t)Bn * C * NpT);
  ushort* v_sbf = allocU((size_t)Bn * C * NpS);
  ushort* S_t = allocU((size_t)Bn * NT * NpT);
  ushort* S_s = allocU((size_t)Bn * NS * NpS);
  ushort* xsT_t = allocU((size_t)Bn * NRT * C);
  ushort* xsT_s = allocU((size_t)Bn * NRS * C);
  float* Atc = alloc((size_t)Bn * C * C);
  float* Asc = alloc((size_t)Bn * C * C);
  ushort* Mc_t = allocU((size_t)Bn * C * C);
  ushort* Mc_s = allocU((size_t)Bn * C * C);
  ushort* owb_t = allocU((size_t)32 * 2304);
  ushort* owb_s = allocU((size_t)32 * 2304);
  ushort* Awb_t = allocU((size_t)256 * 2304);
  ushort* Awb_s = allocU((size_t)256 * 2304);
  uint4* prep_t = (uint4*)alloc((size_t)Bn * 9 * NT * 4);
  uint4* prep_s = (uint4*)alloc((size_t)Bn * 9 * NS * 4);

  dim3 blk(256);

  // 1. fused weight prep (DCN weights -> fragment-major)
  prep_weights_kernel<<<dim3((1491072 + 255) / 256), blk, 0, stream>>>(
      t_qw, t_qb, t_kw, t_kb, s_qw, s_qb, s_kw, s_kb, t_vw, s_vw,
      t_off_w, s_off_w, t_dcn_w, s_dcn_w,
      qkw_t, qkb_t, qkw_s, qkb_s, Wv_t, Wv_s, owb_t, owb_s, Awb_t, Awb_s);

  // 2. fused q|k projections
  conv1x1_fused_kernel<<<dim3(320), blk, 0, stream>>>(
      s_in, qkw_s, qkb_s, qk_s, NS, t_in, qkw_t, qkb_t, qk_t, NT);

  // 3. fused cast+transpose+pad (one x read -> xT and xbf)
  cast_transpose_fused_kernel<<<dim3(1280), blk, 0, stream>>>(
      s_in, xT_s, xbf_s, NS, NRS, NpS, t_in, xT_t, xbf_t, NT, NRT, NpT);

  // 4. fused v projection (EPI=0)
  gemm_fused_kernel<0><<<dim3(640), blk, 0, stream>>>(
      Wv_s, 0, xT_s, s_vb, v_sbf, nullptr, NS, NpS, NRS, C,
      Wv_t, 0, xT_t, t_vb, v_tbf, nullptr, NT, NpT, NRT, C,
      512, 16, 4);

  // 5. fused energy
  energy_fused_kernel<<<dim3(4352), blk, 0, stream>>>(
      qk_s, S_s, NS, NpS, qk_t, S_t, NT, NpT);

  // 6. fused spatial softmax
  softmax_bf16_fused_kernel<<<dim3(Bn * NS + Bn * NT), blk, 0, stream>>>(
      S_s, NS, NpS, S_t, NT, NpT, Bn * NS);

  // 7. fused gram (EPI=2)
  gemm_fused_kernel<2><<<dim3(256), blk, 0, stream>>>(
      xbf_s, 1, xbf_s, nullptr, nullptr, Asc, C, C, C, NpS,
      xbf_t, 1, xbf_t, nullptr, nullptr, Atc, C, C, C, NpT,
      128, 4, 4);

  // 8. fused channel softmax + mcomb
  softmax_mcomb_kernel<<<dim3(Bn * C), blk, 0, stream>>>(
      Atc, Asc, w_t_ch, w_s2t, w_s_ch, w_t2s, Mc_t, Mc_s);

  // 9. merged PV + chan GEMM -> xsT
  pv_chan_fused_kernel<<<dim3(640), blk, 0, stream>>>(
      v_sbf, S_s, Mc_s, xT_s, s_in, s_g, xsT_s, NS, NpS, NRS,
      v_tbf, S_t, Mc_t, xT_t, t_in, t_g, xsT_t, NT, NpT, NRT);

  // 10. fused offconv + gather-table prep
  offconv_prep_fused_kernel<<<dim3(320), blk, 0, stream>>>(
      xsT_s, owb_s, s_off_b, prep_s, HS, WS2, NS, NRS,
      xsT_t, owb_t, t_off_b, prep_t, HT, WT, NT, NRT);

  // 11. fused DCN (r14 best config)
  float* out_t = (float*)d_out;
  float* out_s = out_t + (size_t)Bn * C * NT;
  dcn_fused_kernel<<<dim3(640), dim3(512), 0, stream>>>(
      xsT_s, prep_s, Awb_s, s_dcn_b, out_s, NS, WS2, NRS,
      xsT_t, prep_t, Awb_t, t_dcn_b, out_t, NT, WT, NRT);
}

// Round 19
// 290.009 us; speedup vs baseline: 1.2381x; 1.1701x over previous
//
#include <hip/hip_runtime.h>
#include <hip/hip_bf16.h>
#include <cmath>

typedef __attribute__((ext_vector_type(8))) short bf16x8;
typedef __attribute__((ext_vector_type(4))) float f32x4;

__device__ inline ushort f2bf(float f) {
  __hip_bfloat16 h = __float2bfloat16(f);
  return *reinterpret_cast<ushort*>(&h);
}
__device__ inline float bf2f(ushort u) {
  return __uint_as_float((uint)u << 16);
}
__device__ inline float bflo(uint x) { return __uint_as_float(x << 16); }
__device__ inline float bfhi(uint x) { return __uint_as_float(x & 0xffff0000u); }

// Fused-side decode with XCD-aware bijective chunking.
__device__ inline bool fdecode(int totalS, int gxS, int gyS, int gxT, int gyT,
                               int& bx, int& by, int& bz, bool& isT) {
  const int total = gridDim.x;
  const int id = blockIdx.x;
  int wid = (id & 7) * (total >> 3) + (id >> 3);
  const int totalT = gxT * gyT * 16;
  if (wid >= totalS + totalT) return false;
  isT = wid >= totalS;
  int lid = isT ? wid - totalS : wid;
  const int gx = isT ? gxT : gxS;
  const int gy = isT ? gyT : gyS;
  bx = lid % gx;
  lid /= gx;
  by = lid % gy;
  bz = lid / gy;
  return true;
}

// ---------------------------------------------------------------------------
// fused weight prep (r19): combined projection weights Wall[320][256] bf16
// (rows 0-255 v, 256-287 q, 288-319 k) + biasAll[320] fp32; offconv reorder;
// DCN weights fragment-major.
// ---------------------------------------------------------------------------
__global__ __launch_bounds__(256) void prep_weights_kernel(
    const float* __restrict__ t_qw, const float* __restrict__ t_qb,
    const float* __restrict__ t_kw, const float* __restrict__ t_kb,
    const float* __restrict__ s_qw, const float* __restrict__ s_qb,
    const float* __restrict__ s_kw, const float* __restrict__ s_kb,
    const float* __restrict__ t_vw, const float* __restrict__ t_vb,
    const float* __restrict__ s_vw, const float* __restrict__ s_vb,
    const float* __restrict__ t_off_w, const float* __restrict__ s_off_w,
    const float* __restrict__ t_dcn_w, const float* __restrict__ s_dcn_w,
    ushort* __restrict__ Wall_t, ushort* __restrict__ Wall_s,
    float* __restrict__ biasAll_t, float* __restrict__ biasAll_s,
    ushort* __restrict__ owb_t, ushort* __restrict__ owb_s,
    ushort* __restrict__ Awb_t, ushort* __restrict__ Awb_s) {
  int i = blockIdx.x * 256 + threadIdx.x;
  if (i < 81920) {
    const int r = i >> 8, c = i & 255;
    float v;
    if (r < 256) v = t_vw[(size_t)r * 256 + c];
    else if (r < 288) v = t_qw[(size_t)(r - 256) * 256 + c];
    else v = t_kw[(size_t)(r - 288) * 256 + c];
    Wall_t[i] = f2bf(v);
    return;
  }
  i -= 81920;
  if (i < 81920) {
    const int r = i >> 8, c = i & 255;
    float v;
    if (r < 256) v = s_vw[(size_t)r * 256 + c];
    else if (r < 288) v = s_qw[(size_t)(r - 256) * 256 + c];
    else v = s_kw[(size_t)(r - 288) * 256 + c];
    Wall_s[i] = f2bf(v);
    return;
  }
  i -= 81920;
  if (i < 320) {
    biasAll_t[i] = (i < 256) ? t_vb[i] : ((i < 288) ? t_qb[i - 256] : t_kb[i - 288]);
    return;
  }
  i -= 320;
  if (i < 320) {
    biasAll_s[i] = (i < 256) ? s_vb[i] : ((i < 288) ? s_qb[i - 256] : s_kb[i - 288]);
    return;
  }
  i -= 320;
  if (i < 73728) {
    const int o = i / 2304, k = i % 2304, tap = k >> 8, c = k & 255;
    owb_t[i] = (o < 27) ? f2bf(t_off_w[(size_t)o * 2304 + c * 9 + tap]) : (ushort)0;
    return;
  }
  i -= 73728;
  if (i < 73728) {
    const int o = i / 2304, k = i % 2304, tap = k >> 8, c = k & 255;
    owb_s[i] = (o < 27) ? f2bf(s_off_w[(size_t)o * 2304 + c * 9 + tap]) : (ushort)0;
    return;
  }
  i -= 73728;
  if (i < 589824) {
    const int frag = i >> 9, within = i & 511;
    const int lane = within >> 3, j = within & 7;
    const int mt = frag / 72, kt = frag % 72;
    const int o = mt * 16 + (lane & 15);
    const int k = kt * 32 + (lane >> 4) * 8 + j;
    const int tap = k >> 8, c = k & 255;
    Awb_t[i] = f2bf(t_dcn_w[(size_t)o * 2304 + c * 9 + tap]);
    return;
  }
  i -= 589824;
  if (i < 589824) {
    const int frag = i >> 9, within = i & 511;
    const int lane = within >> 3, j = within & 7;
    const int mt = frag / 72, kt = frag % 72;
    const int o = mt * 16 + (lane & 15);
    const int k = kt * 32 + (lane >> 4) * 8 + j;
    const int tap = k >> 8, c = k & 255;
    Awb_s[i] = f2bf(s_dcn_w[(size_t)o * 2304 + c * 9 + tap]);
  }
}

// ---------------------------------------------------------------------------
// fused cast+transpose+pad: from one LDS tile emit BOTH
//   xT  bf16 [NR][C]  (transposed, rows >= N zeroed)
//   xbf bf16 [C][Np]  (same layout as input, cols >= N zeroed)
// ---------------------------------------------------------------------------
__global__ __launch_bounds__(256) void cast_transpose_fused_kernel(
    const float* __restrict__ xS, ushort* __restrict__ oS, ushort* __restrict__ pS,
    int NS_, int NRS_, int NpS_,
    const float* __restrict__ xT, ushort* __restrict__ oT, ushort* __restrict__ pT,
    int NT_, int NRT_, int NpT_) {
  constexpr int C = 256;
  __shared__ float T[64][65];
  int bx, by, bz; bool isT;
  if (!fdecode(1024, 16, 4, 4, 4, bx, by, bz, isT)) return;
  const float* x = isT ? xT : xS;
  ushort* xTo = isT ? oT : oS;
  ushort* xbf = isT ? pT : pS;
  const int N = isT ? NT_ : NS_;
  const int NR = isT ? NRT_ : NRS_;
  const int Np = isT ? NpT_ : NpS_;
  const int b = bz;
  const int n0 = bx * 64, c0 = by * 64;
  const float* xb = x + (size_t)b * C * N;
  const int tid = threadIdx.x;
  for (int u = tid; u < 4096; u += 256) {
    const int cc = u >> 6, nn = u & 63;
    const int gn = n0 + nn;
    T[cc][nn] = (gn < N) ? xb[(size_t)(c0 + cc) * N + gn] : 0.f;
  }
  __syncthreads();
  ushort* ob = xTo + (size_t)b * NR * C;
  for (int u = tid; u < 4096; u += 256) {
    const int nn = u >> 6, cc = u & 63;
    ob[(size_t)(n0 + nn) * C + c0 + cc] = f2bf(T[cc][nn]);
  }
  ushort* pb = xbf + (size_t)b * C * Np;
  for (int u = tid; u < 4096; u += 256) {
    const int cc = u >> 6, nn = u & 63;
    const int gn = n0 + nn;
    if (gn < Np) pb[(size_t)(c0 + cc) * Np + gn] = f2bf(T[cc][nn]);
  }
}

// ---------------------------------------------------------------------------
// combined projection GEMM (r19): out[m] = Wall[m] @ xT^T + biasAll[m]
// m in [0,256): v -> bf16 padded [C][Np]; m in [256,320): q|k -> fp32 [64][N].
// BM=64, 4 waves x (64m x 16n). s gx=16, t gx=4; gy=5.
// ---------------------------------------------------------------------------
__global__ __launch_bounds__(256) void proj_fused_kernel(
    const ushort* __restrict__ WallS, const float* __restrict__ bS,
    const ushort* __restrict__ BtS, ushort* __restrict__ vS,
    float* __restrict__ qkS, int NS_, int NpS_, int NRS_,
    const ushort* __restrict__ WallT, const float* __restrict__ bT,
    const ushort* __restrict__ BtT, ushort* __restrict__ vT,
    float* __restrict__ qkT, int NT_, int NpT_, int NRT_) {
  constexpr int C = 256;
  __shared__ ushort Asm[64][40];
  __shared__ ushort Bsm[64][40];
  int bx, by, bz; bool isT;
  if (!fdecode(1280, 16, 5, 4, 5, bx, by, bz, isT)) return;
  const ushort* Wall = isT ? WallT : WallS;
  const float* bias = isT ? bT : bS;
  const ushort* Bt = isT ? BtT : BtS;
  ushort* vbf = isT ? vT : vS;
  float* qk = isT ? qkT : qkS;
  const int N = isT ? NT_ : NS_, Np = isT ? NpT_ : NpS_, NR = isT ? NRT_ : NRS_;
  const int n0 = bx * 64, m0 = by * 64, b = bz;
  const ushort* Ab = Wall + (size_t)m0 * C;
  const ushort* Bb = Bt + (size_t)b * NR * C;
  const int tid = threadIdx.x, lane = tid & 63, w = tid >> 6;
  f32x4 acc[4];
#pragma unroll
  for (int i = 0; i < 4; i++) acc[i] = (f32x4){0.f, 0.f, 0.f, 0.f};
  for (int k0 = 0; k0 < C; k0 += 32) {
    {
      const int row = tid >> 2, seg = tid & 3;
      *reinterpret_cast<uint4*>(&Asm[row][seg * 8]) =
          *reinterpret_cast<const uint4*>(&Ab[(size_t)row * C + k0 + seg * 8]);
    }
    {
      const int row = tid >> 2, seg = tid & 3;
      *reinterpret_cast<uint4*>(&Bsm[row][seg * 8]) =
          *reinterpret_cast<const uint4*>(&Bb[(size_t)(n0 + row) * C + k0 + seg * 8]);
    }
    __syncthreads();
    const int koff = (lane >> 4) * 8;
    const bf16x8 bfr = *reinterpret_cast<const bf16x8*>(&Bsm[w * 16 + (lane & 15)][koff]);
#pragma unroll
    for (int mf = 0; mf < 4; mf++) {
      const bf16x8 af = *reinterpret_cast<const bf16x8*>(&Asm[mf * 16 + (lane & 15)][koff]);
      acc[mf] = __builtin_amdgcn_mfma_f32_16x16x32_bf16(af, bfr, acc[mf], 0, 0, 0);
    }
    __syncthreads();
  }
  const int gn = n0 + w * 16 + (lane & 15);
#pragma unroll
  for (int mf = 0; mf < 4; mf++) {
    const int mbase = m0 + mf * 16 + ((lane >> 4) * 4);
#pragma unroll
    for (int rr = 0; rr < 4; rr++) {
      const int m = mbase + rr;
      if (m < 256) {
        if (gn < Np) {
          ushort v = (gn < N) ? f2bf(acc[mf][rr] + bias[m]) : (ushort)0;
          vbf[((size_t)b * 256 + m) * Np + gn] = v;
        }
      } else {
        if (gn < N)
          qk[((size_t)b * 64 + (m - 256)) * N + gn] = acc[mf][rr] + bias[m];
      }
    }
  }
}

// ---------------------------------------------------------------------------
// fused channel softmax + mcomb
// ---------------------------------------------------------------------------
__global__ __launch_bounds__(256) void softmax_mcomb_kernel(
    const float* __restrict__ Atc, const float* __restrict__ Asc,
    const float* __restrict__ w_t_ch, const float* __restrict__ w_s2t,
    const float* __restrict__ w_s_ch, const float* __restrict__ w_t2s,
    ushort* __restrict__ Mc_t, ushort* __restrict__ Mc_s) {
  const int row = blockIdx.x;
  const int tid = threadIdx.x;
  __shared__ float red[8];
  const size_t idx = (size_t)row * 256 + tid;
  const float a = -Atc[idx];
  const float s = -Asc[idx];
  float ma = a, ms = s;
#pragma unroll
  for (int off = 32; off; off >>= 1) {
    ma = fmaxf(ma, __shfl_xor(ma, off, 64));
    ms = fmaxf(ms, __shfl_xor(ms, off, 64));
  }
  if ((tid & 63) == 0) { red[tid >> 6] = ma; red[4 + (tid >> 6)] = ms; }
  __syncthreads();
  if (tid == 0) {
    float m1 = red[0], m2 = red[4];
    for (int i = 1; i < 4; i++) { m1 = fmaxf(m1, red[i]); m2 = fmaxf(m2, red[4 + i]); }
    red[0] = m1; red[4] = m2;
  }
  __syncthreads();
  ma = red[0]; ms = red[4];
  __syncthreads();
  const float ea = __expf(a - ma), es = __expf(s - ms);
  float sa = ea, ss = es;
#pragma unroll
  for (int off = 32; off; off >>= 1) {
    sa += __shfl_xor(sa, off, 64);
    ss += __shfl_xor(ss, off, 64);
  }
  if ((tid & 63) == 0) { red[tid >> 6] = sa; red[4 + (tid >> 6)] = ss; }
  __syncthreads();
  if (tid == 0) {
    float t1 = 0.f, t2 = 0.f;
    for (int i = 0; i < 4; i++) { t1 += red[i]; t2 += red[4 + i]; }
    red[0] = t1; red[4] = t2;
  }
  __syncthreads();
  const float Pa = ea / red[0], Ps = es / red[4];
  Mc_t[idx] = f2bf(w_t_ch[0] * Pa + w_s2t[0] * Ps);
  Mc_s[idx] = f2bf(w_s_ch[0] * Ps + w_t2s[0] * Pa);
}

// ---------------------------------------------------------------------------
// fused generic bf16 GEMM, BM=128, NW=4. EPI 2 only (gram): outF = acc
// ---------------------------------------------------------------------------
template <int EPI>
__global__ __launch_bounds__(256) void gemm_fused_kernel(
    const ushort* __restrict__ AS, int aPerB_S, const ushort* __restrict__ BtS,
    const float* __restrict__ biasS, ushort* __restrict__ outBfS,
    float* __restrict__ outFS, int NS_, int NpS_, int NRS_, int KpS_,
    const ushort* __restrict__ AT, int aPerB_T, const ushort* __restrict__ BtT,
    const float* __restrict__ biasT, ushort* __restrict__ outBfT,
    float* __restrict__ outFT, int NT_, int NpT_, int NRT_, int KpT_,
    int totalS, int gxS, int gxT) {
  constexpr int CM = 256, BM = 128, NW = 4, NF = 2, WN = 2;
  __shared__ ushort Asm[BM][40];
  __shared__ ushort Bsm[64][40];
  int bx, by, bz; bool isT;
  if (!fdecode(totalS, gxS, 2, gxT, 2, bx, by, bz, isT)) return;
  const ushort* A = isT ? AT : AS;
  const ushort* Bt = isT ? BtT : BtS;
  const float* bias = isT ? biasT : biasS;
  ushort* outBf = isT ? outBfT : outBfS;
  float* outF = isT ? outFT : outFS;
  const int aPerBatch = isT ? aPerB_T : aPerB_S;
  const int N = isT ? NT_ : NS_, Np = isT ? NpT_ : NpS_;
  const int NR = isT ? NRT_ : NRS_, Kp = isT ? KpT_ : KpS_;
  const int n0 = bx * 64, m0 = by * BM, b = bz;
  const ushort* Ab = A + (size_t)(aPerBatch ? b : 0) * CM * Kp;
  const ushort* Bb = Bt + (size_t)b * NR * Kp;
  const int tid = threadIdx.x, lane = tid & 63, w = tid >> 6;
  const int wr = w / WN, wc = w % WN;
  f32x4 acc[4][NF];
#pragma unroll
  for (int i = 0; i < 4; i++)
#pragma unroll
    for (int j = 0; j < NF; j++) acc[i][j] = (f32x4){0.f, 0.f, 0.f, 0.f};
  for (int k0 = 0; k0 < Kp; k0 += 32) {
    for (int u = tid; u < BM * 4; u += NW * 64) {
      const int row = u >> 2, seg = u & 3;
      *reinterpret_cast<uint4*>(&Asm[row][seg * 8]) =
          *reinterpret_cast<const uint4*>(&Ab[(size_t)(m0 + row) * Kp + k0 + seg * 8]);
    }
    for (int u = tid; u < 64 * 4; u += NW * 64) {
      const int row = u >> 2, seg = u & 3;
      *reinterpret_cast<uint4*>(&Bsm[row][seg * 8]) =
          *reinterpret_cast<const uint4*>(&Bb[(size_t)(n0 + row) * Kp + k0 + seg * 8]);
    }
    __syncthreads();
    const int koff = (lane >> 4) * 8;
    bf16x8 af[4], bfr[NF];
#pragma unroll
    for (int mf = 0; mf < 4; mf++)
      af[mf] = *reinterpret_cast<const bf16x8*>(&Asm[wr * 64 + mf * 16 + (lane & 15)][koff]);
#pragma unroll
    for (int nf = 0; nf < NF; nf++)
      bfr[nf] = *reinterpret_cast<const bf16x8*>(&Bsm[wc * NF * 16 + nf * 16 + (lane & 15)][koff]);
#pragma unroll
    for (int mf = 0; mf < 4; mf++)
#pragma unroll
      for (int nf = 0; nf < NF; nf++)
        acc[mf][nf] = __builtin_amdgcn_mfma_f32_16x16x32_bf16(af[mf], bfr[nf], acc[mf][nf], 0, 0, 0);
    __syncthreads();
  }
#pragma unroll
  for (int mf = 0; mf < 4; mf++) {
    const int mbase = m0 + wr * 64 + mf * 16 + ((lane >> 4) * 4);
#pragma unroll
    for (int nf = 0; nf < NF; nf++) {
      const int gn = n0 + wc * NF * 16 + nf * 16 + (lane & 15);
      if (EPI == 0) {
#pragma unroll
        for (int rr = 0; rr < 4; rr++) {
          const int m = mbase + rr;
          if (gn < Np) {
            ushort v = (gn < N) ? f2bf(acc[mf][nf][rr] + bias[m]) : (ushort)0;
            outBf[((size_t)b * CM + m) * Np + gn] = v;
          }
        }
      } else {
#pragma unroll
        for (int rr = 0; rr < 4; rr++) {
          if (gn < N)
            outF[((size_t)b * CM + mbase + rr) * N + gn] = acc[mf][nf][rr];
        }
      }
    }
  }
  (void)NR;
}

// ---------------------------------------------------------------------------
// fused energy (K=32)
// ---------------------------------------------------------------------------
__global__ __launch_bounds__(256) void energy_fused_kernel(
    const float* __restrict__ qkS, ushort* __restrict__ SS, int NS_, int NpS_,
    const float* __restrict__ qkT, ushort* __restrict__ ST, int NT_, int NpT_) {
  __shared__ ushort Aq[64][40];
  __shared__ ushort Bk[64][40];
  int bx, by, bz; bool isT;
  if (!fdecode(4096, 16, 16, 4, 4, bx, by, bz, isT)) return;
  const float* qk = isT ? qkT : qkS;
  ushort* Sbf = isT ? ST : SS;
  const int N = isT ? NT_ : NS_, Np = isT ? NpT_ : NpS_;
  const int m0 = bx * 64, n0 = by * 64, b = bz;
  const float* qb = qk + (size_t)b * 64 * N;
  const float* kb = qb + (size_t)32 * N;
  const int tid = threadIdx.x, lane = tid & 63, w = tid >> 6;
  for (int u = tid; u < 2048; u += 256) {
    const int c = u >> 6, nn = u & 63;
    const int gn = n0 + nn, gm = m0 + nn;
    Aq[nn][c] = (gn < N) ? f2bf(qb[(size_t)c * N + gn]) : (ushort)0;
    Bk[nn][c] = (gm < N) ? f2bf(kb[(size_t)c * N + gm]) : (ushort)0;
  }
  __syncthreads();
  const int koff = (lane >> 4) * 8;
  const bf16x8 af = *reinterpret_cast<const bf16x8*>(&Aq[w * 16 + (lane & 15)][koff]);
  f32x4 acc[4];
#pragma unroll
  for (int j = 0; j < 4; j++) {
    const bf16x8 bf = *reinterpret_cast<const bf16x8*>(&Bk[j * 16 + (lane & 15)][koff]);
    acc[j] = __builtin_amdgcn_mfma_f32_16x16x32_bf16(af, bf, (f32x4){0.f, 0.f, 0.f, 0.f}, 0, 0, 0);
  }
#pragma unroll
  for (int j = 0; j < 4; j++) {
    const int m = m0 + j * 16 + (lane & 15);
    if (m >= Np) continue;
#pragma unroll
    for (int r = 0; r < 4; r++) {
      const int n = n0 + w * 16 + (lane >> 4) * 4 + r;
      if (n < N) Sbf[((size_t)b * N + n) * Np + m] = (m < N) ? f2bf(acc[j][r]) : (ushort)0;
    }
  }
}

// ---------------------------------------------------------------------------
// fused bf16 row softmax (spatial scores)
// ---------------------------------------------------------------------------
__global__ __launch_bounds__(256) void softmax_bf16_fused_kernel(
    ushort* __restrict__ Ss, int Ns, int Nps, ushort* __restrict__ St, int Nt,
    int Npt, int rowsS) {
  __shared__ float buf[992];
  __shared__ float red[4];
  const int row = blockIdx.x;
  ushort* r;
  int N;
  if (row < rowsS) {
    r = Ss + (size_t)row * Nps;
    N = Ns;
  } else {
    r = St + (size_t)(row - rowsS) * Npt;
    N = Nt;
  }
  const int tid = threadIdx.x;
  float mx = -1e30f;
  for (int i = tid; i < N; i += 256) {
    float f = bf2f(r[i]);
    buf[i] = f;
    mx = fmaxf(mx, f);
  }
#pragma unroll
  for (int off = 32; off; off >>= 1) mx = fmaxf(mx, __shfl_xor(mx, off, 64));
  if ((tid & 63) == 0) red[tid >> 6] = mx;
  __syncthreads();
  if (tid == 0) {
    float m2 = red[0];
    for (int i = 1; i < 4; i++) m2 = fmaxf(m2, red[i]);
    red[0] = m2;
  }
  __syncthreads();
  mx = red[0];
  __syncthreads();
  float s = 0.f;
  for (int i = tid; i < N; i += 256) {
    float v = __expf(buf[i] - mx);
    buf[i] = v;
    s += v;
  }
#pragma unroll
  for (int off = 32; off; off >>= 1) s += __shfl_xor(s, off, 64);
  if ((tid & 63) == 0) red[tid >> 6] = s;
  __syncthreads();
  if (tid == 0) {
    float t = 0.f;
    for (int i = 0; i < 4; i++) t += red[i];
    red[0] = t;
  }
  __syncthreads();
  const float inv = 1.f / red[0];
  for (int i = tid; i < N; i += 256) r[i] = f2bf(buf[i] * inv);
}

// ---------------------------------------------------------------------------
// fused PV+CHAN merged GEMM (BM=128): acc = PV(v@S^T); acc *= g;
// acc += Mc@xT; out_xsT = bf16(x + acc).
// ---------------------------------------------------------------------------
__global__ __launch_bounds__(256) void pv_chan_fused_kernel(
    const ushort* __restrict__ vS, const ushort* __restrict__ SS,
    const ushort* __restrict__ McS, const ushort* __restrict__ xTS,
    const float* __restrict__ xS, const float* __restrict__ gS,
    ushort* __restrict__ xsTS, int NS_, int NpS_, int NRS_,
    const ushort* __restrict__ vT, const ushort* __restrict__ ST,
    const ushort* __restrict__ McT, const ushort* __restrict__ xTT,
    const float* __restrict__ xT_, const float* __restrict__ gT,
    ushort* __restrict__ xsTT, int NT_, int NpT_, int NRT_) {
  constexpr int C = 256, BM = 128, NW = 4, NF = 2, WN = 2;
  __shared__ ushort Asm[BM][40];
  __shared__ ushort Bsm[64][40];
  int bx, by, bz; bool isT;
  if (!fdecode(512, 16, 2, 4, 2, bx, by, bz, isT)) return;
  const ushort* vbf = isT ? vT : vS;
  const ushort* Sbf = isT ? ST : SS;
  const ushort* Mc = isT ? McT : McS;
  const ushort* xTb = isT ? xTT : xTS;
  const float* x = isT ? xT_ : xS;
  const float* gp = isT ? gT : gS;
  ushort* xsT = isT ? xsTT : xsTS;
  const int N = isT ? NT_ : NS_, Np = isT ? NpT_ : NpS_;
  const int NR = isT ? NRT_ : NRS_;
  const int n0 = bx * 64, m0 = by * BM, b = bz;
  const int tid = threadIdx.x, lane = tid & 63, w = tid >> 6;
  const int wr = w / WN, wc = w % WN;
  f32x4 acc[4][NF];
#pragma unroll
  for (int i = 0; i < 4; i++)
#pragma unroll
    for (int j = 0; j < NF; j++) acc[i][j] = (f32x4){0.f, 0.f, 0.f, 0.f};
  const int koff = (lane >> 4) * 8;
  // phase 1: PV, K = Np
  {
    const ushort* Ab = vbf + (size_t)b * C * Np;
    const ushort* Bb = Sbf + (size_t)b * (size_t)N * Np;
    for (int k0 = 0; k0 < Np; k0 += 32) {
      for (int u = tid; u < BM * 4; u += NW * 64) {
        const int row = u >> 2, seg = u & 3;
        *reinterpret_cast<uint4*>(&Asm[row][seg * 8]) =
            *reinterpret_cast<const uint4*>(&Ab[(size_t)(m0 + row) * Np + k0 + seg * 8]);
      }
      for (int u = tid; u < 64 * 4; u += NW * 64) {
        const int row = u >> 2, seg = u & 3;
        const int gn = n0 + row;
        uint4 val;
        if (gn < N)
          val = *reinterpret_cast<const uint4*>(&Bb[(size_t)gn * Np + k0 + seg * 8]);
        else
          val = make_uint4(0, 0, 0, 0);
        *reinterpret_cast<uint4*>(&Bsm[row][seg * 8]) = val;
      }
      __syncthreads();
      bf16x8 af[4], bfr[NF];
#pragma unroll
      for (int mf = 0; mf < 4; mf++)
        af[mf] = *reinterpret_cast<const bf16x8*>(&Asm[wr * 64 + mf * 16 + (lane & 15)][koff]);
#pragma unroll
      for (int nf = 0; nf < NF; nf++)
        bfr[nf] = *reinterpret_cast<const bf16x8*>(&Bsm[wc * NF * 16 + nf * 16 + (lane & 15)][koff]);
#pragma unroll
      for (int mf = 0; mf < 4; mf++)
#pragma unroll
        for (int nf = 0; nf < NF; nf++)
          acc[mf][nf] = __builtin_amdgcn_mfma_f32_16x16x32_bf16(af[mf], bfr[nf], acc[mf][nf], 0, 0, 0);
      __syncthreads();
    }
  }
  const float g = *gp;
#pragma unroll
  for (int mf = 0; mf < 4; mf++)
#pragma unroll
    for (int nf = 0; nf < NF; nf++)
#pragma unroll
      for (int rr = 0; rr < 4; rr++) acc[mf][nf][rr] *= g;
  // phase 2: chan, K = C
  {
    const ushort* Ab = Mc + (size_t)b * C * C;
    const ushort* Bb = xTb + (size_t)b * NR * C;
    for (int k0 = 0; k0 < C; k0 += 32) {
      for (int u = tid; u < BM * 4; u += NW * 64) {
        const int row = u >> 2, seg = u & 3;
        *reinterpret_cast<uint4*>(&Asm[row][seg * 8]) =
            *reinterpret_cast<const uint4*>(&Ab[(size_t)(m0 + row) * C + k0 + seg * 8]);
      }
      for (int u = tid; u < 64 * 4; u += NW * 64) {
        const int row = u >> 2, seg = u & 3;
        *reinterpret_cast<uint4*>(&Bsm[row][seg * 8]) =
            *reinterpret_cast<const uint4*>(&Bb[(size_t)(n0 + row) * C + k0 + seg * 8]);
      }
      __syncthreads();
      bf16x8 af[4], bfr[NF];
#pragma unroll
      for (int mf = 0; mf < 4; mf++)
        af[mf] = *reinterpret_cast<const bf16x8*>(&Asm[wr * 64 + mf * 16 + (lane & 15)][koff]);
#pragma unroll
      for (int nf = 0; nf < NF; nf++)
        bfr[nf] = *reinterpret_cast<const bf16x8*>(&Bsm[wc * NF * 16 + nf * 16 + (lane & 15)][koff]);
#pragma unroll
      for (int mf = 0; mf < 4; mf++)
#pragma unroll
        for (int nf = 0; nf < NF; nf++)
          acc[mf][nf] = __builtin_amdgcn_mfma_f32_16x16x32_bf16(af[mf], bfr[nf], acc[mf][nf], 0, 0, 0);
      __syncthreads();
    }
  }
#pragma unroll
  for (int mf = 0; mf < 4; mf++) {
    const int mbase = m0 + wr * 64 + mf * 16 + ((lane >> 4) * 4);
#pragma unroll
    for (int nf = 0; nf < NF; nf++) {
      const int gn = n0 + wc * NF * 16 + nf * 16 + (lane & 15);
      if (gn < N) {
        float s[4];
#pragma unroll
        for (int rr = 0; rr < 4; rr++)
          s[rr] = x[((size_t)b * C + mbase + rr) * N + gn] + acc[mf][nf][rr];
        uint lo = (uint)f2bf(s[0]) | ((uint)f2bf(s[1]) << 16);
        uint hi = (uint)f2bf(s[2]) | ((uint)f2bf(s[3]) << 16);
        *reinterpret_cast<uint2*>(&xsT[((size_t)b * NR + gn) * C + mbase]) =
            make_uint2(lo, hi);
      }
    }
  }
}

// ---------------------------------------------------------------------------
// fused offconv via MFMA on xsT, WITH FUSED gather-table prep
// ---------------------------------------------------------------------------
__global__ __launch_bounds__(256) void offconv_prep_fused_kernel(
    const ushort* __restrict__ xS, const ushort* __restrict__ owS,
    const float* __restrict__ obS, uint4* __restrict__ prS, int HS_, int WS_,
    int NS_, int NRS_,
    const ushort* __restrict__ xT, const ushort* __restrict__ owT,
    const float* __restrict__ obT, uint4* __restrict__ prT, int HT_, int WT_,
    int NT_, int NRT_) {
  __shared__ ushort Asm[32][136];
  __shared__ ushort Bsm[64][136];
  __shared__ int qsrc[64];
  __shared__ float som[27][65];
  int bx, by, bz; bool isT;
  if (!fdecode(256, 16, 1, 4, 1, bx, by, bz, isT)) return;
  const ushort* xsT = isT ? xT : xS;
  const ushort* owb = isT ? owT : owS;
  const float* ob = isT ? obT : obS;
  uint4* prep = isT ? prT : prS;
  const int H = isT ? HT_ : HS_, Wd = isT ? WT_ : WS_;
  const int N = isT ? NT_ : NS_, NR = isT ? NRT_ : NRS_;
  const int n0 = bx * 64, b = bz;
  const int tid = threadIdx.x, lane = tid & 63, w = tid >> 6;
  const ushort* xb = xsT + (size_t)b * NR * 256;
  f32x4 acc[2];
  acc[0] = (f32x4){0.f, 0.f, 0.f, 0.f};
  acc[1] = (f32x4){0.f, 0.f, 0.f, 0.f};
  for (int tap = 0; tap < 9; ++tap) {
    const int dy = tap / 3 - 1, dx = tap - (tap / 3) * 3 - 1;
    if (tid < 64) {
      const int p = n0 + tid;
      int q = -1;
      if (p < N) {
        const int h = p / Wd, ww = p - (p / Wd) * Wd;
        const int yy = h + dy, xx = ww + dx;
        if (yy >= 0 && yy < H && xx >= 0 && xx < Wd) q = yy * Wd + xx;
      }
      qsrc[tid] = q;
    }
    __syncthreads();
#pragma unroll
    for (int half = 0; half < 2; ++half) {
      const int k0 = tap * 256 + half * 128;
      for (int u = tid; u < 512; u += 256) {
        const int row = u >> 4, seg = u & 15;
        *reinterpret_cast<uint4*>(&Asm[row][seg * 8]) =
            *reinterpret_cast<const uint4*>(&owb[(size_t)row * 2304 + k0 + seg * 8]);
      }
      for (int u = tid; u < 1024; u += 256) {
        const int row = u >> 4, seg = u & 15;
        const int q = qsrc[row];
        uint4 val = make_uint4(0, 0, 0, 0);
        if (q >= 0)
          val = *reinterpret_cast<const uint4*>(&xb[(size_t)q * 256 + half * 128 + seg * 8]);
        *reinterpret_cast<uint4*>(&Bsm[row][seg * 8]) = val;
      }
      __syncthreads();
#pragma unroll
      for (int sub = 0; sub < 4; ++sub) {
        const int koff = sub * 32 + (lane >> 4) * 8;
        const bf16x8 b0 = *reinterpret_cast<const bf16x8*>(&Bsm[w * 16 + (lane & 15)][koff]);
#pragma unroll
        for (int mf = 0; mf < 2; ++mf) {
          const bf16x8 a0 = *reinterpret_cast<const bf16x8*>(&Asm[mf * 16 + (lane & 15)][koff]);
          acc[mf] = __builtin_amdgcn_mfma_f32_16x16x32_bf16(a0, b0, acc[mf], 0, 0, 0);
        }
      }
      __syncthreads();
    }
  }
#pragma unroll
  for (int mf = 0; mf < 2; ++mf) {
#pragma unroll
    for (int r = 0; r < 4; ++r) {
      const int o = mf * 16 + (lane >> 4) * 4 + r;
      const int n = w * 16 + (lane & 15);
      if (o < 27) som[o][n] = acc[mf][r] + ob[o];
    }
  }
  __syncthreads();
  for (int u = tid; u < 576; u += 256) {
    const int tap = u / 64, pp = u - (u / 64) * 64;
    const int p = n0 + pp;
    if (p >= N) continue;
    const float offy = som[tap][pp];
    const float offx = som[9 + tap][pp];
    const float mraw = som[18 + tap][pp];
    const float mval = 1.f / (1.f + __expf(-mraw));
    const int ky = tap / 3, kx = tap - (tap / 3) * 3;
    const int h = p / Wd, ww = p - (p / Wd) * Wd;
    const float py = offy + (float)(h + ky - 1);
    const float px = offx + (float)(ww + kx - 1);
    const float y0f = floorf(py), x0f = floorf(px);
    const float wy = py - y0f, wx = px - x0f;
    const int y0 = (int)y0f, x0 = (int)x0f;
    const int ys0 = min(max(y0, 0), H - 2);
    const int xs0 = min(max(x0, 0), Wd - 2);
    const float wr0 = (ys0 == y0) ? (1.f - wy) : ((ys0 == y0 + 1) ? wy : 0.f);
    const float wr1 = (ys0 + 1 == y0) ? (1.f - wy) : ((ys0 + 1 == y0 + 1) ? wy : 0.f);
    const float wc0 = (xs0 == x0) ? (1.f - wx) : ((xs0 == x0 + 1) ? wx : 0.f);
    const float wc1 = (xs0 + 1 == x0) ? (1.f - wx) : ((xs0 + 1 == x0 + 1) ? wx : 0.f);
    const float w00 = wr0 * wc0 * mval, w01 = wr0 * wc1 * mval;
    const float w10 = wr1 * wc0 * mval, w11 = wr1 * wc1 * mval;
    uint4 pk;
    pk.x = (uint)(ys0 * Wd + xs0);
    pk.y = (uint)f2bf(w00) | ((uint)f2bf(w01) << 16);
    pk.z = (uint)f2bf(w10) | ((uint)f2bf(w11) << 16);
    pk.w = 0;
    prep[((size_t)b * 9 + tap) * N + p] = pk;
  }
}

// ---------------------------------------------------------------------------
// fused DCN via MFMA (r14 best config)
// ---------------------------------------------------------------------------
__global__ __launch_bounds__(512) void dcn_fused_kernel(
    const ushort* __restrict__ xS, const uint4* __restrict__ prS,
    const ushort* __restrict__ AwS, const float* __restrict__ biS,
    float* __restrict__ oS, int NS_, int WS_, int NRS_,
    const ushort* __restrict__ xT, const uint4* __restrict__ prT,
    const ushort* __restrict__ AwT, const float* __restrict__ biT,
    float* __restrict__ oT, int NT_, int WT_, int NRT_) {
  constexpr int C = 256, MF = 4;
  __shared__ ushort Bsm[32][72];
  __shared__ int sq[32];
  __shared__ float swl[4][32];
  int bx, by, bz; bool isT;
  if (!fdecode(512, 32, 1, 8, 1, bx, by, bz, isT)) return;
  const ushort* xsT = isT ? xT : xS;
  const uint4* prep = isT ? prT : prS;
  const ushort* Awb = isT ? AwT : AwS;
  const float* bias = isT ? biT : biS;
  float* out = isT ? oT : oS;
  const int N = isT ? NT_ : NS_, Wd = isT ? WT_ : WS_, NR = isT ? NRT_ : NRS_;
  const int n0 = bx * 32, b = bz;
  const int tid = threadIdx.x, lane = tid & 63, w = tid >> 6;
  const int wr = w >> 1, wc = w & 1;
  const ushort* xb = xsT + (size_t)b * NR * C;
  const int un0 = tid >> 5;
  const int un1 = un0 + 16;
  const int kk2 = (tid & 31) * 2;
  f32x4 acc[MF];
#pragma unroll
  for (int i = 0; i < MF; i++) acc[i] = (f32x4){0.f, 0.f, 0.f, 0.f};
  uint bReg[2][4];
  int sqr0 = 0, sqr1 = 0;
  float w0a[4], w1a[4];
  const size_t rowYp = (size_t)Wd * C;
  for (int tap = 0; tap < 9; ++tap) {
    if (tid < 32) {
      const int p = n0 + tid;
      if (p < N) {
        const uint4 pk = prep[((size_t)b * 9 + tap) * N + p];
        sq[tid] = (int)pk.x * C;
        swl[0][tid] = bf2f((ushort)(pk.y & 0xffff));
        swl[1][tid] = bf2f((ushort)(pk.y >> 16));
        swl[2][tid] = bf2f((ushort)(pk.z & 0xffff));
        swl[3][tid] = bf2f((ushort)(pk.z >> 16));
      } else {
        sq[tid] = 0;
        swl[0][tid] = swl[1][tid] = swl[2][tid] = swl[3][tid] = 0.f;
      }
    }
    __syncthreads();
    sqr0 = sq[un0];
    sqr1 = sq[un1];
#pragma unroll
    for (int q = 0; q < 4; q++) {
      w0a[q] = swl[q][un0];
      w1a[q] = swl[q][un1];
    }
    {
      const ushort* pA = xb + sqr0 + kk2;
      bReg[0][0] = *reinterpret_cast<const uint*>(pA);
      bReg[0][1] = *reinterpret_cast<const uint*>(pA + C);
      bReg[0][2] = *reinterpret_cast<const uint*>(pA + rowYp);
      bReg[0][3] = *reinterpret_cast<const uint*>(pA + rowYp + C);
      const ushort* pB = xb + sqr1 + kk2;
      bReg[1][0] = *reinterpret_cast<const uint*>(pB);
      bReg[1][1] = *reinterpret_cast<const uint*>(pB + C);
      bReg[1][2] = *reinterpret_cast<const uint*>(pB + rowYp);
      bReg[1][3] = *reinterpret_cast<const uint*>(pB + rowYp + C);
    }
#pragma unroll
    for (int ks = 0; ks < 4; ++ks) {
      bf16x8 afr[2][4];
      const int ktb = tap * 8 + ks * 2;
#pragma unroll
      for (int sub = 0; sub < 2; ++sub)
#pragma unroll
        for (int mf = 0; mf < 4; ++mf)
          afr[sub][mf] = *reinterpret_cast<const bf16x8*>(
              Awb + ((((size_t)(wr * 4 + mf) * 72) + ktb + sub) << 9) + lane * 8);
      {
        const float vlo0 = w0a[0] * bflo(bReg[0][0]) + w0a[1] * bflo(bReg[0][1]) +
                           w0a[2] * bflo(bReg[0][2]) + w0a[3] * bflo(bReg[0][3]);
        const float vhi0 = w0a[0] * bfhi(bReg[0][0]) + w0a[1] * bfhi(bReg[0][1]) +
                           w0a[2] * bfhi(bReg[0][2]) + w0a[3] * bfhi(bReg[0][3]);
        *reinterpret_cast<uint*>(&Bsm[un0][kk2]) =
            (uint)f2bf(vlo0) | ((uint)f2bf(vhi0) << 16);
        const float vlo1 = w1a[0] * bflo(bReg[1][0]) + w1a[1] * bflo(bReg[1][1]) +
                           w1a[2] * bflo(bReg[1][2]) + w1a[3] * bflo(bReg[1][3]);
        const float vhi1 = w1a[0] * bfhi(bReg[1][0]) + w1a[1] * bfhi(bReg[1][1]) +
                           w1a[2] * bfhi(bReg[1][2]) + w1a[3] * bfhi(bReg[1][3]);
        *reinterpret_cast<uint*>(&Bsm[un1][kk2]) =
            (uint)f2bf(vlo1) | ((uint)f2bf(vhi1) << 16);
      }
      __syncthreads();
      if (ks < 3) {
        const int c1 = (ks + 1) * 64;
        const ushort* pA = xb + sqr0 + c1 + kk2;
        bReg[0][0] = *reinterpret_cast<const uint*>(pA);
        bReg[0][1] = *reinterpret_cast<const uint*>(pA + C);
        bReg[0][2] = *reinterpret_cast<const uint*>(pA + rowYp);
        bReg[0][3] = *reinterpret_cast<const uint*>(pA + rowYp + C);
        const ushort* pB = xb + sqr1 + c1 + kk2;
        bReg[1][0] = *reinterpret_cast<const uint*>(pB);
        bReg[1][1] = *reinterpret_cast<const uint*>(pB + C);
        bReg[1][2] = *reinterpret_cast<const uint*>(pB + rowYp);
        bReg[1][3] = *reinterpret_cast<const uint*>(pB + rowYp + C);
      }
#pragma unroll
      for (int sub = 0; sub < 2; ++sub) {
        const int koff = sub * 32 + (lane >> 4) * 8;
        const bf16x8 bfv = *reinterpret_cast<const bf16x8*>(&Bsm[wc * 16 + (lane & 15)][koff]);
#pragma unroll
        for (int mf = 0; mf < MF; mf++)
          acc[mf] = __builtin_amdgcn_mfma_f32_16x16x32_bf16(afr[sub][mf], bfv, acc[mf], 0, 0, 0);
      }
      __syncthreads();
    }
  }
  const int gn = n0 + wc * 16 + (lane & 15);
#pragma unroll
  for (int mf = 0; mf < MF; mf++) {
    const int mbase = wr * 64 + mf * 16 + ((lane >> 4) * 4);
    if (gn < N) {
#pragma unroll
      for (int rr = 0; rr < 4; rr++)
        out[((size_t)b * C + mbase + rr) * N + gn] = acc[mf][rr] + bias[mbase + rr];
    }
  }
}

// ---------------------------------------------------------------------------
extern "C" void kernel_launch(void* const* d_in, const int* in_sizes, int n_in,
                              void* d_out, int out_size, void* d_ws, size_t ws_size,
                              hipStream_t stream) {
  const float* t_in = (const float*)d_in[0];
  const float* s_in = (const float*)d_in[1];
  const float* t_qw = (const float*)d_in[2];
  const float* t_qb = (const float*)d_in[3];
  const float* t_kw = (const float*)d_in[4];
  const float* t_kb = (const float*)d_in[5];
  const float* t_vw = (const float*)d_in[6];
  const float* t_vb = (const float*)d_in[7];
  const float* t_g = (const float*)d_in[8];
  const float* s_qw = (const float*)d_in[9];
  const float* s_qb = (const float*)d_in[10];
  const float* s_kw = (const float*)d_in[11];
  const float* s_kb = (const float*)d_in[12];
  const float* s_vw = (const float*)d_in[13];
  const float* s_vb = (const float*)d_in[14];
  const float* s_g = (const float*)d_in[15];
  const float* w_t_ch = (const float*)d_in[16];
  const float* w_s_ch = (const float*)d_in[17];
  const float* w_s2t = (const float*)d_in[18];
  const float* w_t2s = (const float*)d_in[19];
  const float* t_off_w = (const float*)d_in[20];
  const float* t_off_b = (const float*)d_in[21];
  const float* t_dcn_w = (const float*)d_in[22];
  const float* t_dcn_b = (const float*)d_in[23];
  const float* s_off_w = (const float*)d_in[24];
  const float* s_off_b = (const float*)d_in[25];
  const float* s_dcn_w = (const float*)d_in[26];
  const float* s_dcn_b = (const float*)d_in[27];
  (void)in_sizes; (void)n_in; (void)out_size; (void)ws_size;

  constexpr int Bn = 16, C = 256;
  constexpr int HT = 15, WT = 15, NT = HT * WT;    // 225
  constexpr int HS = 31, WS2 = 31, NS = HS * WS2;  // 961
  constexpr int NpT = 256, NpS = 992;
  constexpr int NRT = 256, NRS = 1024;

  float* ws = (float*)d_ws;
  size_t off = 0;
  auto alloc = [&](size_t n) {
    n = (n + 3) & ~(size_t)3;
    float* p = ws + off; off += n; return p;
  };
  auto allocU = [&](size_t nu) { return (ushort*)alloc((nu + 1) / 2); };

  float* qk_t = alloc((size_t)Bn * 64 * NT);
  float* qk_s = alloc((size_t)Bn * 64 * NS);
  ushort* Wall_t = allocU((size_t)320 * C);
  ushort* Wall_s = allocU((size_t)320 * C);
  float* biasAll_t = alloc(320);
  float* biasAll_s = alloc(320);
  ushort* xT_t = allocU((size_t)Bn * NRT * C);
  ushort* xT_s = allocU((size_t)Bn * NRS * C);
  ushort* xbf_t = allocU((size_t)Bn * C * NpT);
  ushort* xbf_s = allocU((size_t)Bn * C * NpS);
  ushort* v_tbf = allocU((size_t)Bn * C * NpT);
  ushort* v_sbf = allocU((size_t)Bn * C * NpS);
  ushort* S_t = allocU((size_t)Bn * NT * NpT);
  ushort* S_s = allocU((size_t)Bn * NS * NpS);
  ushort* xsT_t = allocU((size_t)Bn * NRT * C);
  ushort* xsT_s = allocU((size_t)Bn * NRS * C);
  float* Atc = alloc((size_t)Bn * C * C);
  float* Asc = alloc((size_t)Bn * C * C);
  ushort* Mc_t = allocU((size_t)Bn * C * C);
  ushort* Mc_s = allocU((size_t)Bn * C * C);
  ushort* owb_t = allocU((size_t)32 * 2304);
  ushort* owb_s = allocU((size_t)32 * 2304);
  ushort* Awb_t = allocU((size_t)256 * 2304);
  ushort* Awb_s = allocU((size_t)256 * 2304);
  uint4* prep_t = (uint4*)alloc((size_t)Bn * 9 * NT * 4);
  uint4* prep_s = (uint4*)alloc((size_t)Bn * 9 * NS * 4);

  dim3 blk(256);

  // 1. fused weight prep (Wall + biasAll + offconv + DCN fragment-major)
  prep_weights_kernel<<<dim3((1491584 + 255) / 256), blk, 0, stream>>>(
      t_qw, t_qb, t_kw, t_kb, s_qw, s_qb, s_kw, s_kb,
      t_vw, t_vb, s_vw, s_vb, t_off_w, s_off_w, t_dcn_w, s_dcn_w,
      Wall_t, Wall_s, biasAll_t, biasAll_s, owb_t, owb_s, Awb_t, Awb_s);

  // 2. fused cast+transpose+pad (one x read -> xT and xbf)
  cast_transpose_fused_kernel<<<dim3(1280), blk, 0, stream>>>(
      s_in, xT_s, xbf_s, NS, NRS, NpS, t_in, xT_t, xbf_t, NT, NRT, NpT);

  // 3. combined projection GEMM (v bf16 + q|k fp32), replaces conv1x1 + v-GEMM
  proj_fused_kernel<<<dim3(1600), blk, 0, stream>>>(
      Wall_s, biasAll_s, xT_s, v_sbf, qk_s, NS, NpS, NRS,
      Wall_t, biasAll_t, xT_t, v_tbf, qk_t, NT, NpT, NRT);

  // 4. fused energy
  energy_fused_kernel<<<dim3(4352), blk, 0, stream>>>(
      qk_s, S_s, NS, NpS, qk_t, S_t, NT, NpT);

  // 5. fused spatial softmax
  softmax_bf16_fused_kernel<<<dim3(Bn * NS + Bn * NT), blk, 0, stream>>>(
      S_s, NS, NpS, S_t, NT, NpT, Bn * NS);

  // 6. fused gram (EPI=2)
  gemm_fused_kernel<2><<<dim3(256), blk, 0, stream>>>(
      xbf_s, 1, xbf_s, nullptr, nullptr, Asc, C, C, C, NpS,
      xbf_t, 1, xbf_t, nullptr, nullptr, Atc, C, C, C, NpT,
      128, 4, 4);

  // 7. fused channel softmax + mcomb
  softmax_mcomb_kernel<<<dim3(Bn * C), blk, 0, stream>>>(
      Atc, Asc, w_t_ch, w_s2t, w_s_ch, w_t2s, Mc_t, Mc_s);

  // 8. merged PV + chan GEMM -> xsT
  pv_chan_fused_kernel<<<dim3(640), blk, 0, stream>>>(
      v_sbf, S_s, Mc_s, xT_s, s_in, s_g, xsT_s, NS, NpS, NRS,
      v_tbf, S_t, Mc_t, xT_t, t_in, t_g, xsT_t, NT, NpT, NRT);

  // 9. fused offconv + gather-table prep
  offconv_prep_fused_kernel<<<dim3(320), blk, 0, stream>>>(
      xsT_s, owb_s, s_off_b, prep_s, HS, WS2, NS, NRS,
      xsT_t, owb_t, t_off_b, prep_t, HT, WT, NT, NRT);

  // 10. fused DCN (r14 best config)
  float* out_t = (float*)d_out;
  float* out_s = out_t + (size_t)Bn * C * NT;
  dcn_fused_kernel<<<dim3(640), dim3(512), 0, stream>>>(
      xsT_s, prep_s, Awb_s, s_dcn_b, out_s, NS, WS2, NRS,
      xsT_t, prep_t, Awb_t, t_dcn_b, out_t, NT, WT, NRT);
}

// Round 20
// 273.297 us; speedup vs baseline: 1.3139x; 1.0612x over previous
//
#include <hip/hip_runtime.h>
#include <hip/hip_bf16.h>
#include <cmath>

typedef __attribute__((ext_vector_type(8))) short bf16x8;
typedef __attribute__((ext_vector_type(4))) float f32x4;

__device__ inline ushort f2bf(float f) {
  __hip_bfloat16 h = __float2bfloat16(f);
  return *reinterpret_cast<ushort*>(&h);
}
__device__ inline float bf2f(ushort u) {
  return __uint_as_float((uint)u << 16);
}
__device__ inline float bflo(uint x) { return __uint_as_float(x << 16); }
__device__ inline float bfhi(uint x) { return __uint_as_float(x & 0xffff0000u); }

// Fused-side decode with XCD-aware bijective chunking (physical grid).
__device__ inline bool fdecode(int totalS, int gxS, int gyS, int gxT, int gyT,
                               int& bx, int& by, int& bz, bool& isT) {
  const int total = gridDim.x;
  const int id = blockIdx.x;
  int wid = (id & 7) * (total >> 3) + (id >> 3);
  const int totalT = gxT * gyT * 16;
  if (wid >= totalS + totalT) return false;
  isT = wid >= totalS;
  int lid = isT ? wid - totalS : wid;
  const int gx = isT ? gxT : gxS;
  const int gy = isT ? gyT : gyS;
  bx = lid % gx;
  lid /= gx;
  by = lid % gy;
  bz = lid / gy;
  return true;
}

// Virtual-grid variant for unioned kernels: v in [0, vtotal), vtotal % 8 == 0.
__device__ inline void vdecode(int v, int vtotal, int totalS, int gxS, int gyS,
                               int gxT, int gyT, int& bx, int& by, int& bz,
                               bool& isT) {
  int wid = (v & 7) * (vtotal >> 3) + (v >> 3);
  isT = wid >= totalS;
  int lid = isT ? wid - totalS : wid;
  const int gx = isT ? gxT : gxS;
  const int gy = isT ? gyT : gyS;
  bx = lid % gx;
  lid /= gx;
  by = lid % gy;
  bz = lid / gy;
}

// ---------------------------------------------------------------------------
// UNION A: weight prep (virtual blocks [0,5832)) + cast/transpose/pad
// (virtual blocks [5832, 5832+1280)).
// ---------------------------------------------------------------------------
__global__ __launch_bounds__(256) void prep_cast_fused_kernel(
    const float* __restrict__ t_qw, const float* __restrict__ t_qb,
    const float* __restrict__ t_kw, const float* __restrict__ t_kb,
    const float* __restrict__ s_qw, const float* __restrict__ s_qb,
    const float* __restrict__ s_kw, const float* __restrict__ s_kb,
    const float* __restrict__ t_vw, const float* __restrict__ t_vb,
    const float* __restrict__ s_vw, const float* __restrict__ s_vb,
    const float* __restrict__ t_off_w, const float* __restrict__ s_off_w,
    const float* __restrict__ t_dcn_w, const float* __restrict__ s_dcn_w,
    ushort* __restrict__ Wall_t, ushort* __restrict__ Wall_s,
    float* __restrict__ biasAll_t, float* __restrict__ biasAll_s,
    ushort* __restrict__ owb_t, ushort* __restrict__ owb_s,
    ushort* __restrict__ Awb_t, ushort* __restrict__ Awb_s,
    const float* __restrict__ xS, ushort* __restrict__ oS,
    ushort* __restrict__ pS, int NS_, int NRS_, int NpS_,
    const float* __restrict__ xT, ushort* __restrict__ oT,
    ushort* __restrict__ pT, int NT_, int NRT_, int NpT_) {
  __shared__ float T[64][65];
  const int tid = threadIdx.x;
  const int vid = blockIdx.x;
  if (vid < 5832) {
    // ---- weight prep path ----
    int i = vid * 256 + tid;
    if (i < 81920) {
      const int r = i >> 8, c = i & 255;
      float v;
      if (r < 256) v = t_vw[(size_t)r * 256 + c];
      else if (r < 288) v = t_qw[(size_t)(r - 256) * 256 + c];
      else v = t_kw[(size_t)(r - 288) * 256 + c];
      Wall_t[i] = f2bf(v);
      return;
    }
    i -= 81920;
    if (i < 81920) {
      const int r = i >> 8, c = i & 255;
      float v;
      if (r < 256) v = s_vw[(size_t)r * 256 + c];
      else if (r < 288) v = s_qw[(size_t)(r - 256) * 256 + c];
      else v = s_kw[(size_t)(r - 288) * 256 + c];
      Wall_s[i] = f2bf(v);
      return;
    }
    i -= 81920;
    if (i < 320) {
      biasAll_t[i] = (i < 256) ? t_vb[i] : ((i < 288) ? t_qb[i - 256] : t_kb[i - 288]);
      return;
    }
    i -= 320;
    if (i < 320) {
      biasAll_s[i] = (i < 256) ? s_vb[i] : ((i < 288) ? s_qb[i - 256] : s_kb[i - 288]);
      return;
    }
    i -= 320;
    if (i < 73728) {
      const int o = i / 2304, k = i % 2304, tap = k >> 8, c = k & 255;
      owb_t[i] = (o < 27) ? f2bf(t_off_w[(size_t)o * 2304 + c * 9 + tap]) : (ushort)0;
      return;
    }
    i -= 73728;
    if (i < 73728) {
      const int o = i / 2304, k = i % 2304, tap = k >> 8, c = k & 255;
      owb_s[i] = (o < 27) ? f2bf(s_off_w[(size_t)o * 2304 + c * 9 + tap]) : (ushort)0;
      return;
    }
    i -= 73728;
    if (i < 589824) {
      const int frag = i >> 9, within = i & 511;
      const int lane = within >> 3, j = within & 7;
      const int mt = frag / 72, kt = frag % 72;
      const int o = mt * 16 + (lane & 15);
      const int k = kt * 32 + (lane >> 4) * 8 + j;
      const int tap = k >> 8, c = k & 255;
      Awb_t[i] = f2bf(t_dcn_w[(size_t)o * 2304 + c * 9 + tap]);
      return;
    }
    i -= 589824;
    if (i < 589824) {
      const int frag = i >> 9, within = i & 511;
      const int lane = within >> 3, j = within & 7;
      const int mt = frag / 72, kt = frag % 72;
      const int o = mt * 16 + (lane & 15);
      const int k = kt * 32 + (lane >> 4) * 8 + j;
      const int tap = k >> 8, c = k & 255;
      Awb_s[i] = f2bf(s_dcn_w[(size_t)o * 2304 + c * 9 + tap]);
    }
    return;
  }
  // ---- cast+transpose+pad path ----
  constexpr int C = 256;
  int bx, by, bz; bool isT;
  vdecode(vid - 5832, 1280, 1024, 16, 4, 4, 4, bx, by, bz, isT);
  const float* x = isT ? xT : xS;
  ushort* xTo = isT ? oT : oS;
  ushort* xbf = isT ? pT : pS;
  const int N = isT ? NT_ : NS_;
  const int NR = isT ? NRT_ : NRS_;
  const int Np = isT ? NpT_ : NpS_;
  const int b = bz;
  const int n0 = bx * 64, c0 = by * 64;
  const float* xb = x + (size_t)b * C * N;
  for (int u = tid; u < 4096; u += 256) {
    const int cc = u >> 6, nn = u & 63;
    const int gn = n0 + nn;
    T[cc][nn] = (gn < N) ? xb[(size_t)(c0 + cc) * N + gn] : 0.f;
  }
  __syncthreads();
  ushort* ob = xTo + (size_t)b * NR * C;
  for (int u = tid; u < 4096; u += 256) {
    const int nn = u >> 6, cc = u & 63;
    ob[(size_t)(n0 + nn) * C + c0 + cc] = f2bf(T[cc][nn]);
  }
  ushort* pb = xbf + (size_t)b * C * Np;
  for (int u = tid; u < 4096; u += 256) {
    const int cc = u >> 6, nn = u & 63;
    const int gn = n0 + nn;
    if (gn < Np) pb[(size_t)(c0 + cc) * Np + gn] = f2bf(T[cc][nn]);
  }
}

// ---------------------------------------------------------------------------
// UNION B: combined projection GEMM (virtual [0,1600)) + gram GEMM
// (virtual [1600, 1600+256)). Shared LDS: Asm[128][40] (proj uses rows 0-63).
// ---------------------------------------------------------------------------
__global__ __launch_bounds__(256) void proj_gram_fused_kernel(
    const ushort* __restrict__ WallS, const float* __restrict__ bS,
    const ushort* __restrict__ BtS, ushort* __restrict__ vS,
    float* __restrict__ qkS, int NS_, int NpS_, int NRS_,
    const ushort* __restrict__ WallT, const float* __restrict__ bT,
    const ushort* __restrict__ BtT, ushort* __restrict__ vT,
    float* __restrict__ qkT, int NT_, int NpT_, int NRT_,
    const ushort* __restrict__ xbfS, float* __restrict__ AscP, int KpS_,
    const ushort* __restrict__ xbfT, float* __restrict__ AtcP, int KpT_) {
  constexpr int C = 256;
  __shared__ ushort Asm[128][40];
  __shared__ ushort Bsm[64][40];
  const int tid = threadIdx.x, lane = tid & 63, w = tid >> 6;
  const int vid = blockIdx.x;
  if (vid < 1600) {
    // ---- proj path ----
    int bx, by, bz; bool isT;
    vdecode(vid, 1600, 1280, 16, 5, 4, 5, bx, by, bz, isT);
    const ushort* Wall = isT ? WallT : WallS;
    const float* bias = isT ? bT : bS;
    const ushort* Bt = isT ? BtT : BtS;
    ushort* vbf = isT ? vT : vS;
    float* qk = isT ? qkT : qkS;
    const int N = isT ? NT_ : NS_, Np = isT ? NpT_ : NpS_, NR = isT ? NRT_ : NRS_;
    const int n0 = bx * 64, m0 = by * 64, b = bz;
    const ushort* Ab = Wall + (size_t)m0 * C;
    const ushort* Bb = Bt + (size_t)b * NR * C;
    f32x4 acc[4];
#pragma unroll
    for (int i = 0; i < 4; i++) acc[i] = (f32x4){0.f, 0.f, 0.f, 0.f};
    for (int k0 = 0; k0 < C; k0 += 32) {
      {
        const int row = tid >> 2, seg = tid & 3;
        *reinterpret_cast<uint4*>(&Asm[row][seg * 8]) =
            *reinterpret_cast<const uint4*>(&Ab[(size_t)row * C + k0 + seg * 8]);
        *reinterpret_cast<uint4*>(&Bsm[row][seg * 8]) =
            *reinterpret_cast<const uint4*>(&Bb[(size_t)(n0 + row) * C + k0 + seg * 8]);
      }
      __syncthreads();
      const int koff = (lane >> 4) * 8;
      const bf16x8 bfr = *reinterpret_cast<const bf16x8*>(&Bsm[w * 16 + (lane & 15)][koff]);
#pragma unroll
      for (int mf = 0; mf < 4; mf++) {
        const bf16x8 af = *reinterpret_cast<const bf16x8*>(&Asm[mf * 16 + (lane & 15)][koff]);
        acc[mf] = __builtin_amdgcn_mfma_f32_16x16x32_bf16(af, bfr, acc[mf], 0, 0, 0);
      }
      __syncthreads();
    }
    const int gn = n0 + w * 16 + (lane & 15);
#pragma unroll
    for (int mf = 0; mf < 4; mf++) {
      const int mbase = m0 + mf * 16 + ((lane >> 4) * 4);
#pragma unroll
      for (int rr = 0; rr < 4; rr++) {
        const int m = mbase + rr;
        if (m < 256) {
          if (gn < Np) {
            ushort v = (gn < N) ? f2bf(acc[mf][rr] + bias[m]) : (ushort)0;
            vbf[((size_t)b * 256 + m) * Np + gn] = v;
          }
        } else {
          if (gn < N)
            qk[((size_t)b * 64 + (m - 256)) * N + gn] = acc[mf][rr] + bias[m];
        }
      }
    }
    return;
  }
  // ---- gram path (BM=128, NW=4, NF=2, WN=2; N=Np=NR=256) ----
  {
    constexpr int BM = 128, NW = 4, NF = 2, WN = 2;
    int bx, by, bz; bool isT;
    vdecode(vid - 1600, 256, 128, 4, 2, 4, 2, bx, by, bz, isT);
    const ushort* A = isT ? xbfT : xbfS;
    float* outF = isT ? AtcP : AscP;
    const int Kp = isT ? KpT_ : KpS_;
    const int n0 = bx * 64, m0 = by * BM, b = bz;
    const ushort* Ab = A + (size_t)b * C * Kp;
    const int wr = w / WN, wc = w % WN;
    f32x4 acc[4][NF];
#pragma unroll
    for (int i = 0; i < 4; i++)
#pragma unroll
      for (int j = 0; j < NF; j++) acc[i][j] = (f32x4){0.f, 0.f, 0.f, 0.f};
    for (int k0 = 0; k0 < Kp; k0 += 32) {
      for (int u = tid; u < BM * 4; u += NW * 64) {
        const int row = u >> 2, seg = u & 3;
        *reinterpret_cast<uint4*>(&Asm[row][seg * 8]) =
            *reinterpret_cast<const uint4*>(&Ab[(size_t)(m0 + row) * Kp + k0 + seg * 8]);
      }
      for (int u = tid; u < 64 * 4; u += NW * 64) {
        const int row = u >> 2, seg = u & 3;
        *reinterpret_cast<uint4*>(&Bsm[row][seg * 8]) =
            *reinterpret_cast<const uint4*>(&Ab[(size_t)(n0 + row) * Kp + k0 + seg * 8]);
      }
      __syncthreads();
      const int koff = (lane >> 4) * 8;
      bf16x8 af[4], bfr[NF];
#pragma unroll
      for (int mf = 0; mf < 4; mf++)
        af[mf] = *reinterpret_cast<const bf16x8*>(&Asm[wr * 64 + mf * 16 + (lane & 15)][koff]);
#pragma unroll
      for (int nf = 0; nf < NF; nf++)
        bfr[nf] = *reinterpret_cast<const bf16x8*>(&Bsm[wc * NF * 16 + nf * 16 + (lane & 15)][koff]);
#pragma unroll
      for (int mf = 0; mf < 4; mf++)
#pragma unroll
        for (int nf = 0; nf < NF; nf++)
          acc[mf][nf] = __builtin_amdgcn_mfma_f32_16x16x32_bf16(af[mf], bfr[nf], acc[mf][nf], 0, 0, 0);
      __syncthreads();
    }
#pragma unroll
    for (int mf = 0; mf < 4; mf++) {
      const int mbase = m0 + wr * 64 + mf * 16 + ((lane >> 4) * 4);
#pragma unroll
      for (int nf = 0; nf < NF; nf++) {
        const int gn = n0 + wc * NF * 16 + nf * 16 + (lane & 15);
#pragma unroll
        for (int rr = 0; rr < 4; rr++)
          outF[((size_t)b * C + mbase + rr) * C + gn] = acc[mf][nf][rr];
      }
    }
  }
}

// ---------------------------------------------------------------------------
// UNION C: energy (virtual [0,4352)) + channel softmax/mcomb
// (virtual [4352, 4352+4096)).
// ---------------------------------------------------------------------------
__global__ __launch_bounds__(256) void energy_mcomb_fused_kernel(
    const float* __restrict__ qkS, ushort* __restrict__ SS, int NS_, int NpS_,
    const float* __restrict__ qkT, ushort* __restrict__ ST, int NT_, int NpT_,
    const float* __restrict__ Atc, const float* __restrict__ Asc,
    const float* __restrict__ w_t_ch, const float* __restrict__ w_s2t,
    const float* __restrict__ w_s_ch, const float* __restrict__ w_t2s,
    ushort* __restrict__ Mc_t, ushort* __restrict__ Mc_s) {
  __shared__ ushort Aq[64][40];
  __shared__ ushort Bk[64][40];
  __shared__ float red[8];
  const int tid = threadIdx.x;
  const int vid = blockIdx.x;
  if (vid < 4352) {
    // ---- energy path ----
    int bx, by, bz; bool isT;
    vdecode(vid, 4352, 4096, 16, 16, 4, 4, bx, by, bz, isT);
    const float* qk = isT ? qkT : qkS;
    ushort* Sbf = isT ? ST : SS;
    const int N = isT ? NT_ : NS_, Np = isT ? NpT_ : NpS_;
    const int m0 = bx * 64, n0 = by * 64, b = bz;
    const float* qb = qk + (size_t)b * 64 * N;
    const float* kb = qb + (size_t)32 * N;
    const int lane = tid & 63, w = tid >> 6;
    for (int u = tid; u < 2048; u += 256) {
      const int c = u >> 6, nn = u & 63;
      const int gn = n0 + nn, gm = m0 + nn;
      Aq[nn][c] = (gn < N) ? f2bf(qb[(size_t)c * N + gn]) : (ushort)0;
      Bk[nn][c] = (gm < N) ? f2bf(kb[(size_t)c * N + gm]) : (ushort)0;
    }
    __syncthreads();
    const int koff = (lane >> 4) * 8;
    const bf16x8 af = *reinterpret_cast<const bf16x8*>(&Aq[w * 16 + (lane & 15)][koff]);
    f32x4 acc[4];
#pragma unroll
    for (int j = 0; j < 4; j++) {
      const bf16x8 bf = *reinterpret_cast<const bf16x8*>(&Bk[j * 16 + (lane & 15)][koff]);
      acc[j] = __builtin_amdgcn_mfma_f32_16x16x32_bf16(af, bf, (f32x4){0.f, 0.f, 0.f, 0.f}, 0, 0, 0);
    }
#pragma unroll
    for (int j = 0; j < 4; j++) {
      const int m = m0 + j * 16 + (lane & 15);
      if (m >= Np) continue;
#pragma unroll
      for (int r = 0; r < 4; r++) {
        const int n = n0 + w * 16 + (lane >> 4) * 4 + r;
        if (n < N) Sbf[((size_t)b * N + n) * Np + m] = (m < N) ? f2bf(acc[j][r]) : (ushort)0;
      }
    }
    return;
  }
  // ---- channel softmax + mcomb path ----
  {
    const int row = vid - 4352;
    const size_t idx = (size_t)row * 256 + tid;
    const float a = -Atc[idx];
    const float s = -Asc[idx];
    float ma = a, ms = s;
#pragma unroll
    for (int off = 32; off; off >>= 1) {
      ma = fmaxf(ma, __shfl_xor(ma, off, 64));
      ms = fmaxf(ms, __shfl_xor(ms, off, 64));
    }
    if ((tid & 63) == 0) { red[tid >> 6] = ma; red[4 + (tid >> 6)] = ms; }
    __syncthreads();
    if (tid == 0) {
      float m1 = red[0], m2 = red[4];
      for (int i = 1; i < 4; i++) { m1 = fmaxf(m1, red[i]); m2 = fmaxf(m2, red[4 + i]); }
      red[0] = m1; red[4] = m2;
    }
    __syncthreads();
    ma = red[0]; ms = red[4];
    __syncthreads();
    const float ea = __expf(a - ma), es = __expf(s - ms);
    float sa = ea, ss = es;
#pragma unroll
    for (int off = 32; off; off >>= 1) {
      sa += __shfl_xor(sa, off, 64);
      ss += __shfl_xor(ss, off, 64);
    }
    if ((tid & 63) == 0) { red[tid >> 6] = sa; red[4 + (tid >> 6)] = ss; }
    __syncthreads();
    if (tid == 0) {
      float t1 = 0.f, t2 = 0.f;
      for (int i = 0; i < 4; i++) { t1 += red[i]; t2 += red[4 + i]; }
      red[0] = t1; red[4] = t2;
    }
    __syncthreads();
    const float Pa = ea / red[0], Ps = es / red[4];
    Mc_t[idx] = f2bf(w_t_ch[0] * Pa + w_s2t[0] * Ps);
    Mc_s[idx] = f2bf(w_s_ch[0] * Ps + w_t2s[0] * Pa);
  }
}

// ---------------------------------------------------------------------------
// fused bf16 row softmax (spatial scores)
// ---------------------------------------------------------------------------
__global__ __launch_bounds__(256) void softmax_bf16_fused_kernel(
    ushort* __restrict__ Ss, int Ns, int Nps, ushort* __restrict__ St, int Nt,
    int Npt, int rowsS) {
  __shared__ float buf[992];
  __shared__ float red[4];
  const int row = blockIdx.x;
  ushort* r;
  int N;
  if (row < rowsS) {
    r = Ss + (size_t)row * Nps;
    N = Ns;
  } else {
    r = St + (size_t)(row - rowsS) * Npt;
    N = Nt;
  }
  const int tid = threadIdx.x;
  float mx = -1e30f;
  for (int i = tid; i < N; i += 256) {
    float f = bf2f(r[i]);
    buf[i] = f;
    mx = fmaxf(mx, f);
  }
#pragma unroll
  for (int off = 32; off; off >>= 1) mx = fmaxf(mx, __shfl_xor(mx, off, 64));
  if ((tid & 63) == 0) red[tid >> 6] = mx;
  __syncthreads();
  if (tid == 0) {
    float m2 = red[0];
    for (int i = 1; i < 4; i++) m2 = fmaxf(m2, red[i]);
    red[0] = m2;
  }
  __syncthreads();
  mx = red[0];
  __syncthreads();
  float s = 0.f;
  for (int i = tid; i < N; i += 256) {
    float v = __expf(buf[i] - mx);
    buf[i] = v;
    s += v;
  }
#pragma unroll
  for (int off = 32; off; off >>= 1) s += __shfl_xor(s, off, 64);
  if ((tid & 63) == 0) red[tid >> 6] = s;
  __syncthreads();
  if (tid == 0) {
    float t = 0.f;
    for (int i = 0; i < 4; i++) t += red[i];
    red[0] = t;
  }
  __syncthreads();
  const float inv = 1.f / red[0];
  for (int i = tid; i < N; i += 256) r[i] = f2bf(buf[i] * inv);
}

// ---------------------------------------------------------------------------
// fused PV+CHAN merged GEMM (BM=128): acc = PV(v@S^T); acc *= g;
// acc += Mc@xT; out_xsT = bf16(x + acc).
// ---------------------------------------------------------------------------
__global__ __launch_bounds__(256) void pv_chan_fused_kernel(
    const ushort* __restrict__ vS, const ushort* __restrict__ SS,
    const ushort* __restrict__ McS, const ushort* __restrict__ xTS,
    const float* __restrict__ xS, const float* __restrict__ gS,
    ushort* __restrict__ xsTS, int NS_, int NpS_, int NRS_,
    const ushort* __restrict__ vT, const ushort* __restrict__ ST,
    const ushort* __restrict__ McT, const ushort* __restrict__ xTT,
    const float* __restrict__ xT_, const float* __restrict__ gT,
    ushort* __restrict__ xsTT, int NT_, int NpT_, int NRT_) {
  constexpr int C = 256, BM = 128, NW = 4, NF = 2, WN = 2;
  __shared__ ushort Asm[BM][40];
  __shared__ ushort Bsm[64][40];
  int bx, by, bz; bool isT;
  if (!fdecode(512, 16, 2, 4, 2, bx, by, bz, isT)) return;
  const ushort* vbf = isT ? vT : vS;
  const ushort* Sbf = isT ? ST : SS;
  const ushort* Mc = isT ? McT : McS;
  const ushort* xTb = isT ? xTT : xTS;
  const float* x = isT ? xT_ : xS;
  const float* gp = isT ? gT : gS;
  ushort* xsT = isT ? xsTT : xsTS;
  const int N = isT ? NT_ : NS_, Np = isT ? NpT_ : NpS_;
  const int NR = isT ? NRT_ : NRS_;
  const int n0 = bx * 64, m0 = by * BM, b = bz;
  const int tid = threadIdx.x, lane = tid & 63, w = tid >> 6;
  const int wr = w / WN, wc = w % WN;
  f32x4 acc[4][NF];
#pragma unroll
  for (int i = 0; i < 4; i++)
#pragma unroll
    for (int j = 0; j < NF; j++) acc[i][j] = (f32x4){0.f, 0.f, 0.f, 0.f};
  const int koff = (lane >> 4) * 8;
  // phase 1: PV, K = Np
  {
    const ushort* Ab = vbf + (size_t)b * C * Np;
    const ushort* Bb = Sbf + (size_t)b * (size_t)N * Np;
    for (int k0 = 0; k0 < Np; k0 += 32) {
      for (int u = tid; u < BM * 4; u += NW * 64) {
        const int row = u >> 2, seg = u & 3;
        *reinterpret_cast<uint4*>(&Asm[row][seg * 8]) =
            *reinterpret_cast<const uint4*>(&Ab[(size_t)(m0 + row) * Np + k0 + seg * 8]);
      }
      for (int u = tid; u < 64 * 4; u += NW * 64) {
        const int row = u >> 2, seg = u & 3;
        const int gn = n0 + row;
        uint4 val;
        if (gn < N)
          val = *reinterpret_cast<const uint4*>(&Bb[(size_t)gn * Np + k0 + seg * 8]);
        else
          val = make_uint4(0, 0, 0, 0);
        *reinterpret_cast<uint4*>(&Bsm[row][seg * 8]) = val;
      }
      __syncthreads();
      bf16x8 af[4], bfr[NF];
#pragma unroll
      for (int mf = 0; mf < 4; mf++)
        af[mf] = *reinterpret_cast<const bf16x8*>(&Asm[wr * 64 + mf * 16 + (lane & 15)][koff]);
#pragma unroll
      for (int nf = 0; nf < NF; nf++)
        bfr[nf] = *reinterpret_cast<const bf16x8*>(&Bsm[wc * NF * 16 + nf * 16 + (lane & 15)][koff]);
#pragma unroll
      for (int mf = 0; mf < 4; mf++)
#pragma unroll
        for (int nf = 0; nf < NF; nf++)
          acc[mf][nf] = __builtin_amdgcn_mfma_f32_16x16x32_bf16(af[mf], bfr[nf], acc[mf][nf], 0, 0, 0);
      __syncthreads();
    }
  }
  const float g = *gp;
#pragma unroll
  for (int mf = 0; mf < 4; mf++)
#pragma unroll
    for (int nf = 0; nf < NF; nf++)
#pragma unroll
      for (int rr = 0; rr < 4; rr++) acc[mf][nf][rr] *= g;
  // phase 2: chan, K = C
  {
    const ushort* Ab = Mc + (size_t)b * C * C;
    const ushort* Bb = xTb + (size_t)b * NR * C;
    for (int k0 = 0; k0 < C; k0 += 32) {
      for (int u = tid; u < BM * 4; u += NW * 64) {
        const int row = u >> 2, seg = u & 3;
        *reinterpret_cast<uint4*>(&Asm[row][seg * 8]) =
            *reinterpret_cast<const uint4*>(&Ab[(size_t)(m0 + row) * C + k0 + seg * 8]);
      }
      for (int u = tid; u < 64 * 4; u += NW * 64) {
        const int row = u >> 2, seg = u & 3;
        *reinterpret_cast<uint4*>(&Bsm[row][seg * 8]) =
            *reinterpret_cast<const uint4*>(&Bb[(size_t)(n0 + row) * C + k0 + seg * 8]);
      }
      __syncthreads();
      bf16x8 af[4], bfr[NF];
#pragma unroll
      for (int mf = 0; mf < 4; mf++)
        af[mf] = *reinterpret_cast<const bf16x8*>(&Asm[wr * 64 + mf * 16 + (lane & 15)][koff]);
#pragma unroll
      for (int nf = 0; nf < NF; nf++)
        bfr[nf] = *reinterpret_cast<const bf16x8*>(&Bsm[wc * NF * 16 + nf * 16 + (lane & 15)][koff]);
#pragma unroll
      for (int mf = 0; mf < 4; mf++)
#pragma unroll
        for (int nf = 0; nf < NF; nf++)
          acc[mf][nf] = __builtin_amdgcn_mfma_f32_16x16x32_bf16(af[mf], bfr[nf], acc[mf][nf], 0, 0, 0);
      __syncthreads();
    }
  }
#pragma unroll
  for (int mf = 0; mf < 4; mf++) {
    const int mbase = m0 + wr * 64 + mf * 16 + ((lane >> 4) * 4);
#pragma unroll
    for (int nf = 0; nf < NF; nf++) {
      const int gn = n0 + wc * NF * 16 + nf * 16 + (lane & 15);
      if (gn < N) {
        float s[4];
#pragma unroll
        for (int rr = 0; rr < 4; rr++)
          s[rr] = x[((size_t)b * C + mbase + rr) * N + gn] + acc[mf][nf][rr];
        uint lo = (uint)f2bf(s[0]) | ((uint)f2bf(s[1]) << 16);
        uint hi = (uint)f2bf(s[2]) | ((uint)f2bf(s[3]) << 16);
        *reinterpret_cast<uint2*>(&xsT[((size_t)b * NR + gn) * C + mbase]) =
            make_uint2(lo, hi);
      }
    }
  }
}

// ---------------------------------------------------------------------------
// fused offconv via MFMA on xsT, WITH FUSED gather-table prep
// ---------------------------------------------------------------------------
__global__ __launch_bounds__(256) void offconv_prep_fused_kernel(
    const ushort* __restrict__ xS, const ushort* __restrict__ owS,
    const float* __restrict__ obS, uint4* __restrict__ prS, int HS_, int WS_,
    int NS_, int NRS_,
    const ushort* __restrict__ xT, const ushort* __restrict__ owT,
    const float* __restrict__ obT, uint4* __restrict__ prT, int HT_, int WT_,
    int NT_, int NRT_) {
  __shared__ ushort Asm[32][136];
  __shared__ ushort Bsm[64][136];
  __shared__ int qsrc[64];
  __shared__ float som[27][65];
  int bx, by, bz; bool isT;
  if (!fdecode(256, 16, 1, 4, 1, bx, by, bz, isT)) return;
  const ushort* xsT = isT ? xT : xS;
  const ushort* owb = isT ? owT : owS;
  const float* ob = isT ? obT : obS;
  uint4* prep = isT ? prT : prS;
  const int H = isT ? HT_ : HS_, Wd = isT ? WT_ : WS_;
  const int N = isT ? NT_ : NS_, NR = isT ? NRT_ : NRS_;
  const int n0 = bx * 64, b = bz;
  const int tid = threadIdx.x, lane = tid & 63, w = tid >> 6;
  const ushort* xb = xsT + (size_t)b * NR * 256;
  f32x4 acc[2];
  acc[0] = (f32x4){0.f, 0.f, 0.f, 0.f};
  acc[1] = (f32x4){0.f, 0.f, 0.f, 0.f};
  for (int tap = 0; tap < 9; ++tap) {
    const int dy = tap / 3 - 1, dx = tap - (tap / 3) * 3 - 1;
    if (tid < 64) {
      const int p = n0 + tid;
      int q = -1;
      if (p < N) {
        const int h = p / Wd, ww = p - (p / Wd) * Wd;
        const int yy = h + dy, xx = ww + dx;
        if (yy >= 0 && yy < H && xx >= 0 && xx < Wd) q = yy * Wd + xx;
      }
      qsrc[tid] = q;
    }
    __syncthreads();
#pragma unroll
    for (int half = 0; half < 2; ++half) {
      const int k0 = tap * 256 + half * 128;
      for (int u = tid; u < 512; u += 256) {
        const int row = u >> 4, seg = u & 15;
        *reinterpret_cast<uint4*>(&Asm[row][seg * 8]) =
            *reinterpret_cast<const uint4*>(&owb[(size_t)row * 2304 + k0 + seg * 8]);
      }
      for (int u = tid; u < 1024; u += 256) {
        const int row = u >> 4, seg = u & 15;
        const int q = qsrc[row];
        uint4 val = make_uint4(0, 0, 0, 0);
        if (q >= 0)
          val = *reinterpret_cast<const uint4*>(&xb[(size_t)q * 256 + half * 128 + seg * 8]);
        *reinterpret_cast<uint4*>(&Bsm[row][seg * 8]) = val;
      }
      __syncthreads();
#pragma unroll
      for (int sub = 0; sub < 4; ++sub) {
        const int koff = sub * 32 + (lane >> 4) * 8;
        const bf16x8 b0 = *reinterpret_cast<const bf16x8*>(&Bsm[w * 16 + (lane & 15)][koff]);
#pragma unroll
        for (int mf = 0; mf < 2; ++mf) {
          const bf16x8 a0 = *reinterpret_cast<const bf16x8*>(&Asm[mf * 16 + (lane & 15)][koff]);
          acc[mf] = __builtin_amdgcn_mfma_f32_16x16x32_bf16(a0, b0, acc[mf], 0, 0, 0);
        }
      }
      __syncthreads();
    }
  }
#pragma unroll
  for (int mf = 0; mf < 2; ++mf) {
#pragma unroll
    for (int r = 0; r < 4; ++r) {
      const int o = mf * 16 + (lane >> 4) * 4 + r;
      const int n = w * 16 + (lane & 15);
      if (o < 27) som[o][n] = acc[mf][r] + ob[o];
    }
  }
  __syncthreads();
  for (int u = tid; u < 576; u += 256) {
    const int tap = u / 64, pp = u - (u / 64) * 64;
    const int p = n0 + pp;
    if (p >= N) continue;
    const float offy = som[tap][pp];
    const float offx = som[9 + tap][pp];
    const float mraw = som[18 + tap][pp];
    const float mval = 1.f / (1.f + __expf(-mraw));
    const int ky = tap / 3, kx = tap - (tap / 3) * 3;
    const int h = p / Wd, ww = p - (p / Wd) * Wd;
    const float py = offy + (float)(h + ky - 1);
    const float px = offx + (float)(ww + kx - 1);
    const float y0f = floorf(py), x0f = floorf(px);
    const float wy = py - y0f, wx = px - x0f;
    const int y0 = (int)y0f, x0 = (int)x0f;
    const int ys0 = min(max(y0, 0), H - 2);
    const int xs0 = min(max(x0, 0), Wd - 2);
    const float wr0 = (ys0 == y0) ? (1.f - wy) : ((ys0 == y0 + 1) ? wy : 0.f);
    const float wr1 = (ys0 + 1 == y0) ? (1.f - wy) : ((ys0 + 1 == y0 + 1) ? wy : 0.f);
    const float wc0 = (xs0 == x0) ? (1.f - wx) : ((xs0 == x0 + 1) ? wx : 0.f);
    const float wc1 = (xs0 + 1 == x0) ? (1.f - wx) : ((xs0 + 1 == x0 + 1) ? wx : 0.f);
    const float w00 = wr0 * wc0 * mval, w01 = wr0 * wc1 * mval;
    const float w10 = wr1 * wc0 * mval, w11 = wr1 * wc1 * mval;
    uint4 pk;
    pk.x = (uint)(ys0 * Wd + xs0);
    pk.y = (uint)f2bf(w00) | ((uint)f2bf(w01) << 16);
    pk.z = (uint)f2bf(w10) | ((uint)f2bf(w11) << 16);
    pk.w = 0;
    prep[((size_t)b * 9 + tap) * N + p] = pk;
  }
}

// ---------------------------------------------------------------------------
// fused DCN via MFMA (r14 best config)
// ---------------------------------------------------------------------------
__global__ __launch_bounds__(512) void dcn_fused_kernel(
    const ushort* __restrict__ xS, const uint4* __restrict__ prS,
    const ushort* __restrict__ AwS, const float* __restrict__ biS,
    float* __restrict__ oS, int NS_, int WS_, int NRS_,
    const ushort* __restrict__ xT, const uint4* __restrict__ prT,
    const ushort* __restrict__ AwT, const float* __restrict__ biT,
    float* __restrict__ oT, int NT_, int WT_, int NRT_) {
  constexpr int C = 256, MF = 4;
  __shared__ ushort Bsm[32][72];
  __shared__ int sq[32];
  __shared__ float swl[4][32];
  int bx, by, bz; bool isT;
  if (!fdecode(512, 32, 1, 8, 1, bx, by, bz, isT)) return;
  const ushort* xsT = isT ? xT : xS;
  const uint4* prep = isT ? prT : prS;
  const ushort* Awb = isT ? AwT : AwS;
  const float* bias = isT ? biT : biS;
  float* out = isT ? oT : oS;
  const int N = isT ? NT_ : NS_, Wd = isT ? WT_ : WS_, NR = isT ? NRT_ : NRS_;
  const int n0 = bx * 32, b = bz;
  const int tid = threadIdx.x, lane = tid & 63, w = tid >> 6;
  const int wr = w >> 1, wc = w & 1;
  const ushort* xb = xsT + (size_t)b * NR * C;
  const int un0 = tid >> 5;
  const int un1 = un0 + 16;
  const int kk2 = (tid & 31) * 2;
  f32x4 acc[MF];
#pragma unroll
  for (int i = 0; i < MF; i++) acc[i] = (f32x4){0.f, 0.f, 0.f, 0.f};
  uint bReg[2][4];
  int sqr0 = 0, sqr1 = 0;
  float w0a[4], w1a[4];
  const size_t rowYp = (size_t)Wd * C;
  for (int tap = 0; tap < 9; ++tap) {
    if (tid < 32) {
      const int p = n0 + tid;
      if (p < N) {
        const uint4 pk = prep[((size_t)b * 9 + tap) * N + p];
        sq[tid] = (int)pk.x * C;
        swl[0][tid] = bf2f((ushort)(pk.y & 0xffff));
        swl[1][tid] = bf2f((ushort)(pk.y >> 16));
        swl[2][tid] = bf2f((ushort)(pk.z & 0xffff));
        swl[3][tid] = bf2f((ushort)(pk.z >> 16));
      } else {
        sq[tid] = 0;
        swl[0][tid] = swl[1][tid] = swl[2][tid] = swl[3][tid] = 0.f;
      }
    }
    __syncthreads();
    sqr0 = sq[un0];
    sqr1 = sq[un1];
#pragma unroll
    for (int q = 0; q < 4; q++) {
      w0a[q] = swl[q][un0];
      w1a[q] = swl[q][un1];
    }
    {
      const ushort* pA = xb + sqr0 + kk2;
      bReg[0][0] = *reinterpret_cast<const uint*>(pA);
      bReg[0][1] = *reinterpret_cast<const uint*>(pA + C);
      bReg[0][2] = *reinterpret_cast<const uint*>(pA + rowYp);
      bReg[0][3] = *reinterpret_cast<const uint*>(pA + rowYp + C);
      const ushort* pB = xb + sqr1 + kk2;
      bReg[1][0] = *reinterpret_cast<const uint*>(pB);
      bReg[1][1] = *reinterpret_cast<const uint*>(pB + C);
      bReg[1][2] = *reinterpret_cast<const uint*>(pB + rowYp);
      bReg[1][3] = *reinterpret_cast<const uint*>(pB + rowYp + C);
    }
#pragma unroll
    for (int ks = 0; ks < 4; ++ks) {
      bf16x8 afr[2][4];
      const int ktb = tap * 8 + ks * 2;
#pragma unroll
      for (int sub = 0; sub < 2; ++sub)
#pragma unroll
        for (int mf = 0; mf < 4; ++mf)
          afr[sub][mf] = *reinterpret_cast<const bf16x8*>(
              Awb + ((((size_t)(wr * 4 + mf) * 72) + ktb + sub) << 9) + lane * 8);
      {
        const float vlo0 = w0a[0] * bflo(bReg[0][0]) + w0a[1] * bflo(bReg[0][1]) +
                           w0a[2] * bflo(bReg[0][2]) + w0a[3] * bflo(bReg[0][3]);
        const float vhi0 = w0a[0] * bfhi(bReg[0][0]) + w0a[1] * bfhi(bReg[0][1]) +
                           w0a[2] * bfhi(bReg[0][2]) + w0a[3] * bfhi(bReg[0][3]);
        *reinterpret_cast<uint*>(&Bsm[un0][kk2]) =
            (uint)f2bf(vlo0) | ((uint)f2bf(vhi0) << 16);
        const float vlo1 = w1a[0] * bflo(bReg[1][0]) + w1a[1] * bflo(bReg[1][1]) +
                           w1a[2] * bflo(bReg[1][2]) + w1a[3] * bflo(bReg[1][3]);
        const float vhi1 = w1a[0] * bfhi(bReg[1][0]) + w1a[1] * bfhi(bReg[1][1]) +
                           w1a[2] * bfhi(bReg[1][2]) + w1a[3] * bfhi(bReg[1][3]);
        *reinterpret_cast<uint*>(&Bsm[un1][kk2]) =
            (uint)f2bf(vlo1) | ((uint)f2bf(vhi1) << 16);
      }
      __syncthreads();
      if (ks < 3) {
        const int c1 = (ks + 1) * 64;
        const ushort* pA = xb + sqr0 + c1 + kk2;
        bReg[0][0] = *reinterpret_cast<const uint*>(pA);
        bReg[0][1] = *reinterpret_cast<const uint*>(pA + C);
        bReg[0][2] = *reinterpret_cast<const uint*>(pA + rowYp);
        bReg[0][3] = *reinterpret_cast<const uint*>(pA + rowYp + C);
        const ushort* pB = xb + sqr1 + c1 + kk2;
        bReg[1][0] = *reinterpret_cast<const uint*>(pB);
        bReg[1][1] = *reinterpret_cast<const uint*>(pB + C);
        bReg[1][2] = *reinterpret_cast<const uint*>(pB + rowYp);
        bReg[1][3] = *reinterpret_cast<const uint*>(pB + rowYp + C);
      }
#pragma unroll
      for (int sub = 0; sub < 2; ++sub) {
        const int koff = sub * 32 + (lane >> 4) * 8;
        const bf16x8 bfv = *reinterpret_cast<const bf16x8*>(&Bsm[wc * 16 + (lane & 15)][koff]);
#pragma unroll
        for (int mf = 0; mf < MF; mf++)
          acc[mf] = __builtin_amdgcn_mfma_f32_16x16x32_bf16(afr[sub][mf], bfv, acc[mf], 0, 0, 0);
      }
      __syncthreads();
    }
  }
  const int gn = n0 + wc * 16 + (lane & 15);
#pragma unroll
  for (int mf = 0; mf < MF; mf++) {
    const int mbase = wr * 64 + mf * 16 + ((lane >> 4) * 4);
    if (gn < N) {
#pragma unroll
      for (int rr = 0; rr < 4; rr++)
        out[((size_t)b * C + mbase + rr) * N + gn] = acc[mf][rr] + bias[mbase + rr];
    }
  }
}

// ---------------------------------------------------------------------------
extern "C" void kernel_launch(void* const* d_in, const int* in_sizes, int n_in,
                              void* d_out, int out_size, void* d_ws, size_t ws_size,
                              hipStream_t stream) {
  const float* t_in = (const float*)d_in[0];
  const float* s_in = (const float*)d_in[1];
  const float* t_qw = (const float*)d_in[2];
  const float* t_qb = (const float*)d_in[3];
  const float* t_kw = (const float*)d_in[4];
  const float* t_kb = (const float*)d_in[5];
  const float* t_vw = (const float*)d_in[6];
  const float* t_vb = (const float*)d_in[7];
  const float* t_g = (const float*)d_in[8];
  const float* s_qw = (const float*)d_in[9];
  const float* s_qb = (const float*)d_in[10];
  const float* s_kw = (const float*)d_in[11];
  const float* s_kb = (const float*)d_in[12];
  const float* s_vw = (const float*)d_in[13];
  const float* s_vb = (const float*)d_in[14];
  const float* s_g = (const float*)d_in[15];
  const float* w_t_ch = (const float*)d_in[16];
  const float* w_s_ch = (const float*)d_in[17];
  const float* w_s2t = (const float*)d_in[18];
  const float* w_t2s = (const float*)d_in[19];
  const float* t_off_w = (const float*)d_in[20];
  const float* t_off_b = (const float*)d_in[21];
  const float* t_dcn_w = (const float*)d_in[22];
  const float* t_dcn_b = (const float*)d_in[23];
  const float* s_off_w = (const float*)d_in[24];
  const float* s_off_b = (const float*)d_in[25];
  const float* s_dcn_w = (const float*)d_in[26];
  const float* s_dcn_b = (const float*)d_in[27];
  (void)in_sizes; (void)n_in; (void)out_size; (void)ws_size;

  constexpr int Bn = 16, C = 256;
  constexpr int HT = 15, WT = 15, NT = HT * WT;    // 225
  constexpr int HS = 31, WS2 = 31, NS = HS * WS2;  // 961
  constexpr int NpT = 256, NpS = 992;
  constexpr int NRT = 256, NRS = 1024;

  float* ws = (float*)d_ws;
  size_t off = 0;
  auto alloc = [&](size_t n) {
    n = (n + 3) & ~(size_t)3;
    float* p = ws + off; off += n; return p;
  };
  auto allocU = [&](size_t nu) { return (ushort*)alloc((nu + 1) / 2); };

  float* qk_t = alloc((size_t)Bn * 64 * NT);
  float* qk_s = alloc((size_t)Bn * 64 * NS);
  ushort* Wall_t = allocU((size_t)320 * C);
  ushort* Wall_s = allocU((size_t)320 * C);
  float* biasAll_t = alloc(320);
  float* biasAll_s = alloc(320);
  ushort* xT_t = allocU((size_t)Bn * NRT * C);
  ushort* xT_s = allocU((size_t)Bn * NRS * C);
  ushort* xbf_t = allocU((size_t)Bn * C * NpT);
  ushort* xbf_s = allocU((size_t)Bn * C * NpS);
  ushort* v_tbf = allocU((size_t)Bn * C * NpT);
  ushort* v_sbf = allocU((size_t)Bn * C * NpS);
  ushort* S_t = allocU((size_t)Bn * NT * NpT);
  ushort* S_s = allocU((size_t)Bn * NS * NpS);
  ushort* xsT_t = allocU((size_t)Bn * NRT * C);
  ushort* xsT_s = allocU((size_t)Bn * NRS * C);
  float* Atc = alloc((size_t)Bn * C * C);
  float* Asc = alloc((size_t)Bn * C * C);
  ushort* Mc_t = allocU((size_t)Bn * C * C);
  ushort* Mc_s = allocU((size_t)Bn * C * C);
  ushort* owb_t = allocU((size_t)32 * 2304);
  ushort* owb_s = allocU((size_t)32 * 2304);
  ushort* Awb_t = allocU((size_t)256 * 2304);
  ushort* Awb_s = allocU((size_t)256 * 2304);
  uint4* prep_t = (uint4*)alloc((size_t)Bn * 9 * NT * 4);
  uint4* prep_s = (uint4*)alloc((size_t)Bn * 9 * NS * 4);

  dim3 blk(256);

  // 1. UNION A: weight prep (5832) + cast/transpose/pad (1280)
  prep_cast_fused_kernel<<<dim3(5832 + 1280), blk, 0, stream>>>(
      t_qw, t_qb, t_kw, t_kb, s_qw, s_qb, s_kw, s_kb,
      t_vw, t_vb, s_vw, s_vb, t_off_w, s_off_w, t_dcn_w, s_dcn_w,
      Wall_t, Wall_s, biasAll_t, biasAll_s, owb_t, owb_s, Awb_t, Awb_s,
      s_in, xT_s, xbf_s, NS, NRS, NpS, t_in, xT_t, xbf_t, NT, NRT, NpT);

  // 2. UNION B: combined projection GEMM (1600) + gram GEMM (256)
  proj_gram_fused_kernel<<<dim3(1600 + 256), blk, 0, stream>>>(
      Wall_s, biasAll_s, xT_s, v_sbf, qk_s, NS, NpS, NRS,
      Wall_t, biasAll_t, xT_t, v_tbf, qk_t, NT, NpT, NRT,
      xbf_s, Asc, NpS, xbf_t, Atc, NpT);

  // 3. UNION C: energy (4352) + channel softmax/mcomb (4096)
  energy_mcomb_fused_kernel<<<dim3(4352 + 4096), blk, 0, stream>>>(
      qk_s, S_s, NS, NpS, qk_t, S_t, NT, NpT,
      Atc, Asc, w_t_ch, w_s2t, w_s_ch, w_t2s, Mc_t, Mc_s);

  // 4. fused spatial softmax
  softmax_bf16_fused_kernel<<<dim3(Bn * NS + Bn * NT), blk, 0, stream>>>(
      S_s, NS, NpS, S_t, NT, NpT, Bn * NS);

  // 5. merged PV + chan GEMM -> xsT
  pv_chan_fused_kernel<<<dim3(640), blk, 0, stream>>>(
      v_sbf, S_s, Mc_s, xT_s, s_in, s_g, xsT_s, NS, NpS, NRS,
      v_tbf, S_t, Mc_t, xT_t, t_in, t_g, xsT_t, NT, NpT, NRT);

  // 6. fused offconv + gather-table prep
  offconv_prep_fused_kernel<<<dim3(320), blk, 0, stream>>>(
      xsT_s, owb_s, s_off_b, prep_s, HS, WS2, NS, NRS,
      xsT_t, owb_t, t_off_b, prep_t, HT, WT, NT, NRT);

  // 7. fused DCN (r14 best config)
  float* out_t = (float*)d_out;
  float* out_s = out_t + (size_t)Bn * C * NT;
  dcn_fused_kernel<<<dim3(640), dim3(512), 0, stream>>>(
      xsT_s, prep_s, Awb_s, s_dcn_b, out_s, NS, WS2, NRS,
      xsT_t, prep_t, Awb_t, t_dcn_b, out_t, NT, WT, NRT);
}

// Round 21
// 256.746 us; speedup vs baseline: 1.3986x; 1.0645x over previous
//
#include <hip/hip_runtime.h>
#include <hip/hip_bf16.h>
#include <cmath>

typedef __attribute__((ext_vector_type(8))) short bf16x8;
typedef __attribute__((ext_vector_type(4))) float f32x4;

__device__ inline ushort f2bf(float f) {
  __hip_bfloat16 h = __float2bfloat16(f);
  return *reinterpret_cast<ushort*>(&h);
}
__device__ inline float bf2f(ushort u) {
  return __uint_as_float((uint)u << 16);
}
__device__ inline float bflo(uint x) { return __uint_as_float(x << 16); }
__device__ inline float bfhi(uint x) { return __uint_as_float(x & 0xffff0000u); }

// Fused-side decode with XCD-aware bijective chunking (physical grid).
__device__ inline bool fdecode(int totalS, int gxS, int gyS, int gxT, int gyT,
                               int& bx, int& by, int& bz, bool& isT) {
  const int total = gridDim.x;
  const int id = blockIdx.x;
  int wid = (id & 7) * (total >> 3) + (id >> 3);
  const int totalT = gxT * gyT * 16;
  if (wid >= totalS + totalT) return false;
  isT = wid >= totalS;
  int lid = isT ? wid - totalS : wid;
  const int gx = isT ? gxT : gxS;
  const int gy = isT ? gyT : gyS;
  bx = lid % gx;
  lid /= gx;
  by = lid % gy;
  bz = lid / gy;
  return true;
}

// Virtual-grid variant for unioned kernels: v in [0, vtotal), vtotal % 8 == 0.
__device__ inline void vdecode(int v, int vtotal, int totalS, int gxS, int gyS,
                               int gxT, int gyT, int& bx, int& by, int& bz,
                               bool& isT) {
  int wid = (v & 7) * (vtotal >> 3) + (v >> 3);
  isT = wid >= totalS;
  int lid = isT ? wid - totalS : wid;
  const int gx = isT ? gxT : gxS;
  const int gy = isT ? gyT : gyS;
  bx = lid % gx;
  lid /= gx;
  by = lid % gy;
  bz = lid / gy;
}

// ---------------------------------------------------------------------------
// UNION A: weight prep (virtual [0,5832)) + cast/transpose/pad
// (virtual [5832, 7112)) + rowsum zero (virtual [7112, 7187)).
// ---------------------------------------------------------------------------
__global__ __launch_bounds__(256) void prep_cast_fused_kernel(
    const float* __restrict__ t_qw, const float* __restrict__ t_qb,
    const float* __restrict__ t_kw, const float* __restrict__ t_kb,
    const float* __restrict__ s_qw, const float* __restrict__ s_qb,
    const float* __restrict__ s_kw, const float* __restrict__ s_kb,
    const float* __restrict__ t_vw, const float* __restrict__ t_vb,
    const float* __restrict__ s_vw, const float* __restrict__ s_vb,
    const float* __restrict__ t_off_w, const float* __restrict__ s_off_w,
    const float* __restrict__ t_dcn_w, const float* __restrict__ s_dcn_w,
    ushort* __restrict__ Wall_t, ushort* __restrict__ Wall_s,
    float* __restrict__ biasAll_t, float* __restrict__ biasAll_s,
    ushort* __restrict__ owb_t, ushort* __restrict__ owb_s,
    ushort* __restrict__ Awb_t, ushort* __restrict__ Awb_s,
    const float* __restrict__ xS, ushort* __restrict__ oS,
    ushort* __restrict__ pS, int NS_, int NRS_, int NpS_,
    const float* __restrict__ xT, ushort* __restrict__ oT,
    ushort* __restrict__ pT, int NT_, int NRT_, int NpT_,
    float* __restrict__ rsS, float* __restrict__ rsT) {
  __shared__ float T[64][65];
  const int tid = threadIdx.x;
  const int vid = blockIdx.x;
  if (vid < 5832) {
    // ---- weight prep path ----
    int i = vid * 256 + tid;
    if (i < 81920) {
      const int r = i >> 8, c = i & 255;
      float v;
      if (r < 256) v = t_vw[(size_t)r * 256 + c];
      else if (r < 288) v = t_qw[(size_t)(r - 256) * 256 + c];
      else v = t_kw[(size_t)(r - 288) * 256 + c];
      Wall_t[i] = f2bf(v);
      return;
    }
    i -= 81920;
    if (i < 81920) {
      const int r = i >> 8, c = i & 255;
      float v;
      if (r < 256) v = s_vw[(size_t)r * 256 + c];
      else if (r < 288) v = s_qw[(size_t)(r - 256) * 256 + c];
      else v = s_kw[(size_t)(r - 288) * 256 + c];
      Wall_s[i] = f2bf(v);
      return;
    }
    i -= 81920;
    if (i < 320) {
      biasAll_t[i] = (i < 256) ? t_vb[i] : ((i < 288) ? t_qb[i - 256] : t_kb[i - 288]);
      return;
    }
    i -= 320;
    if (i < 320) {
      biasAll_s[i] = (i < 256) ? s_vb[i] : ((i < 288) ? s_qb[i - 256] : s_kb[i - 288]);
      return;
    }
    i -= 320;
    if (i < 73728) {
      const int o = i / 2304, k = i % 2304, tap = k >> 8, c = k & 255;
      owb_t[i] = (o < 27) ? f2bf(t_off_w[(size_t)o * 2304 + c * 9 + tap]) : (ushort)0;
      return;
    }
    i -= 73728;
    if (i < 73728) {
      const int o = i / 2304, k = i % 2304, tap = k >> 8, c = k & 255;
      owb_s[i] = (o < 27) ? f2bf(s_off_w[(size_t)o * 2304 + c * 9 + tap]) : (ushort)0;
      return;
    }
    i -= 73728;
    if (i < 589824) {
      const int frag = i >> 9, within = i & 511;
      const int lane = within >> 3, j = within & 7;
      const int mt = frag / 72, kt = frag % 72;
      const int o = mt * 16 + (lane & 15);
      const int k = kt * 32 + (lane >> 4) * 8 + j;
      const int tap = k >> 8, c = k & 255;
      Awb_t[i] = f2bf(t_dcn_w[(size_t)o * 2304 + c * 9 + tap]);
      return;
    }
    i -= 589824;
    if (i < 589824) {
      const int frag = i >> 9, within = i & 511;
      const int lane = within >> 3, j = within & 7;
      const int mt = frag / 72, kt = frag % 72;
      const int o = mt * 16 + (lane & 15);
      const int k = kt * 32 + (lane >> 4) * 8 + j;
      const int tap = k >> 8, c = k & 255;
      Awb_s[i] = f2bf(s_dcn_w[(size_t)o * 2304 + c * 9 + tap]);
    }
    return;
  }
  if (vid >= 7112) {
    // ---- rowsum zero path ----
    int i = (vid - 7112) * 256 + tid;
    if (i < 15376) rsS[i] = 0.f;
    else if (i < 18976) rsT[i - 15376] = 0.f;
    return;
  }
  // ---- cast+transpose+pad path ----
  constexpr int C = 256;
  int bx, by, bz; bool isT;
  vdecode(vid - 5832, 1280, 1024, 16, 4, 4, 4, bx, by, bz, isT);
  const float* x = isT ? xT : xS;
  ushort* xTo = isT ? oT : oS;
  ushort* xbf = isT ? pT : pS;
  const int N = isT ? NT_ : NS_;
  const int NR = isT ? NRT_ : NRS_;
  const int Np = isT ? NpT_ : NpS_;
  const int b = bz;
  const int n0 = bx * 64, c0 = by * 64;
  const float* xb = x + (size_t)b * C * N;
  for (int u = tid; u < 4096; u += 256) {
    const int cc = u >> 6, nn = u & 63;
    const int gn = n0 + nn;
    T[cc][nn] = (gn < N) ? xb[(size_t)(c0 + cc) * N + gn] : 0.f;
  }
  __syncthreads();
  ushort* ob = xTo + (size_t)b * NR * C;
  for (int u = tid; u < 4096; u += 256) {
    const int nn = u >> 6, cc = u & 63;
    ob[(size_t)(n0 + nn) * C + c0 + cc] = f2bf(T[cc][nn]);
  }
  ushort* pb = xbf + (size_t)b * C * Np;
  for (int u = tid; u < 4096; u += 256) {
    const int cc = u >> 6, nn = u & 63;
    const int gn = n0 + nn;
    if (gn < Np) pb[(size_t)(c0 + cc) * Np + gn] = f2bf(T[cc][nn]);
  }
}

// ---------------------------------------------------------------------------
// UNION B: combined projection GEMM (virtual [0,1600)) + gram GEMM
// (virtual [1600, 1600+256)). Shared LDS: Asm[128][40].
// ---------------------------------------------------------------------------
__global__ __launch_bounds__(256) void proj_gram_fused_kernel(
    const ushort* __restrict__ WallS, const float* __restrict__ bS,
    const ushort* __restrict__ BtS, ushort* __restrict__ vS,
    float* __restrict__ qkS, int NS_, int NpS_, int NRS_,
    const ushort* __restrict__ WallT, const float* __restrict__ bT,
    const ushort* __restrict__ BtT, ushort* __restrict__ vT,
    float* __restrict__ qkT, int NT_, int NpT_, int NRT_,
    const ushort* __restrict__ xbfS, float* __restrict__ AscP, int KpS_,
    const ushort* __restrict__ xbfT, float* __restrict__ AtcP, int KpT_) {
  constexpr int C = 256;
  __shared__ ushort Asm[128][40];
  __shared__ ushort Bsm[64][40];
  const int tid = threadIdx.x, lane = tid & 63, w = tid >> 6;
  const int vid = blockIdx.x;
  if (vid < 1600) {
    // ---- proj path ----
    int bx, by, bz; bool isT;
    vdecode(vid, 1600, 1280, 16, 5, 4, 5, bx, by, bz, isT);
    const ushort* Wall = isT ? WallT : WallS;
    const float* bias = isT ? bT : bS;
    const ushort* Bt = isT ? BtT : BtS;
    ushort* vbf = isT ? vT : vS;
    float* qk = isT ? qkT : qkS;
    const int N = isT ? NT_ : NS_, Np = isT ? NpT_ : NpS_, NR = isT ? NRT_ : NRS_;
    const int n0 = bx * 64, m0 = by * 64, b = bz;
    const ushort* Ab = Wall + (size_t)m0 * C;
    const ushort* Bb = Bt + (size_t)b * NR * C;
    f32x4 acc[4];
#pragma unroll
    for (int i = 0; i < 4; i++) acc[i] = (f32x4){0.f, 0.f, 0.f, 0.f};
    for (int k0 = 0; k0 < C; k0 += 32) {
      {
        const int row = tid >> 2, seg = tid & 3;
        *reinterpret_cast<uint4*>(&Asm[row][seg * 8]) =
            *reinterpret_cast<const uint4*>(&Ab[(size_t)row * C + k0 + seg * 8]);
        *reinterpret_cast<uint4*>(&Bsm[row][seg * 8]) =
            *reinterpret_cast<const uint4*>(&Bb[(size_t)(n0 + row) * C + k0 + seg * 8]);
      }
      __syncthreads();
      const int koff = (lane >> 4) * 8;
      const bf16x8 bfr = *reinterpret_cast<const bf16x8*>(&Bsm[w * 16 + (lane & 15)][koff]);
#pragma unroll
      for (int mf = 0; mf < 4; mf++) {
        const bf16x8 af = *reinterpret_cast<const bf16x8*>(&Asm[mf * 16 + (lane & 15)][koff]);
        acc[mf] = __builtin_amdgcn_mfma_f32_16x16x32_bf16(af, bfr, acc[mf], 0, 0, 0);
      }
      __syncthreads();
    }
    const int gn = n0 + w * 16 + (lane & 15);
#pragma unroll
    for (int mf = 0; mf < 4; mf++) {
      const int mbase = m0 + mf * 16 + ((lane >> 4) * 4);
#pragma unroll
      for (int rr = 0; rr < 4; rr++) {
        const int m = mbase + rr;
        if (m < 256) {
          if (gn < Np) {
            ushort v = (gn < N) ? f2bf(acc[mf][rr] + bias[m]) : (ushort)0;
            vbf[((size_t)b * 256 + m) * Np + gn] = v;
          }
        } else {
          if (gn < N)
            qk[((size_t)b * 64 + (m - 256)) * N + gn] = acc[mf][rr] + bias[m];
        }
      }
    }
    return;
  }
  // ---- gram path ----
  {
    constexpr int BM = 128, NW = 4, NF = 2, WN = 2;
    int bx, by, bz; bool isT;
    vdecode(vid - 1600, 256, 128, 4, 2, 4, 2, bx, by, bz, isT);
    const ushort* A = isT ? xbfT : xbfS;
    float* outF = isT ? AtcP : AscP;
    const int Kp = isT ? KpT_ : KpS_;
    const int n0 = bx * 64, m0 = by * BM, b = bz;
    const ushort* Ab = A + (size_t)b * C * Kp;
    const int wr = w / WN, wc = w % WN;
    f32x4 acc[4][NF];
#pragma unroll
    for (int i = 0; i < 4; i++)
#pragma unroll
      for (int j = 0; j < NF; j++) acc[i][j] = (f32x4){0.f, 0.f, 0.f, 0.f};
    for (int k0 = 0; k0 < Kp; k0 += 32) {
      for (int u = tid; u < BM * 4; u += NW * 64) {
        const int row = u >> 2, seg = u & 3;
        *reinterpret_cast<uint4*>(&Asm[row][seg * 8]) =
            *reinterpret_cast<const uint4*>(&Ab[(size_t)(m0 + row) * Kp + k0 + seg * 8]);
      }
      for (int u = tid; u < 64 * 4; u += NW * 64) {
        const int row = u >> 2, seg = u & 3;
        *reinterpret_cast<uint4*>(&Bsm[row][seg * 8]) =
            *reinterpret_cast<const uint4*>(&Ab[(size_t)(n0 + row) * Kp + k0 + seg * 8]);
      }
      __syncthreads();
      const int koff = (lane >> 4) * 8;
      bf16x8 af[4], bfr[NF];
#pragma unroll
      for (int mf = 0; mf < 4; mf++)
        af[mf] = *reinterpret_cast<const bf16x8*>(&Asm[wr * 64 + mf * 16 + (lane & 15)][koff]);
#pragma unroll
      for (int nf = 0; nf < NF; nf++)
        bfr[nf] = *reinterpret_cast<const bf16x8*>(&Bsm[wc * NF * 16 + nf * 16 + (lane & 15)][koff]);
#pragma unroll
      for (int mf = 0; mf < 4; mf++)
#pragma unroll
        for (int nf = 0; nf < NF; nf++)
          acc[mf][nf] = __builtin_amdgcn_mfma_f32_16x16x32_bf16(af[mf], bfr[nf], acc[mf][nf], 0, 0, 0);
      __syncthreads();
    }
#pragma unroll
    for (int mf = 0; mf < 4; mf++) {
      const int mbase = m0 + wr * 64 + mf * 16 + ((lane >> 4) * 4);
#pragma unroll
      for (int nf = 0; nf < NF; nf++) {
        const int gn = n0 + wc * NF * 16 + nf * 16 + (lane & 15);
#pragma unroll
        for (int rr = 0; rr < 4; rr++)
          outF[((size_t)b * C + mbase + rr) * C + gn] = acc[mf][nf][rr];
      }
    }
  }
}

// ---------------------------------------------------------------------------
// UNION C: energy+exp+rowsum (virtual [0,4352)) + channel softmax/mcomb
// (virtual [4352, 4352+4096)). Energy stores E = exp(s) un-normalized in bf16
// and accumulates per-row sums via shuffle-reduce + atomicAdd; spatial
// softmax kernel is eliminated (pv_chan divides by rowsum).
// ---------------------------------------------------------------------------
__global__ __launch_bounds__(256) void energy_mcomb_fused_kernel(
    const float* __restrict__ qkS, ushort* __restrict__ SS, int NS_, int NpS_,
    const float* __restrict__ qkT, ushort* __restrict__ ST, int NT_, int NpT_,
    float* __restrict__ rsS, float* __restrict__ rsT,
    const float* __restrict__ Atc, const float* __restrict__ Asc,
    const float* __restrict__ w_t_ch, const float* __restrict__ w_s2t,
    const float* __restrict__ w_s_ch, const float* __restrict__ w_t2s,
    ushort* __restrict__ Mc_t, ushort* __restrict__ Mc_s) {
  __shared__ ushort Aq[64][40];
  __shared__ ushort Bk[64][40];
  __shared__ float red[8];
  const int tid = threadIdx.x;
  const int vid = blockIdx.x;
  if (vid < 4352) {
    // ---- energy + exp + rowsum path ----
    int bx, by, bz; bool isT;
    vdecode(vid, 4352, 4096, 16, 16, 4, 4, bx, by, bz, isT);
    const float* qk = isT ? qkT : qkS;
    ushort* Sbf = isT ? ST : SS;
    float* rowsum = isT ? rsT : rsS;
    const int N = isT ? NT_ : NS_, Np = isT ? NpT_ : NpS_;
    const int m0 = bx * 64, n0 = by * 64, b = bz;
    const float* qb = qk + (size_t)b * 64 * N;
    const float* kb = qb + (size_t)32 * N;
    const int lane = tid & 63, w = tid >> 6;
    for (int u = tid; u < 2048; u += 256) {
      const int c = u >> 6, nn = u & 63;
      const int gn = n0 + nn, gm = m0 + nn;
      Aq[nn][c] = (gn < N) ? f2bf(qb[(size_t)c * N + gn]) : (ushort)0;
      Bk[nn][c] = (gm < N) ? f2bf(kb[(size_t)c * N + gm]) : (ushort)0;
    }
    __syncthreads();
    const int koff = (lane >> 4) * 8;
    const bf16x8 af = *reinterpret_cast<const bf16x8*>(&Aq[w * 16 + (lane & 15)][koff]);
    f32x4 acc[4];
#pragma unroll
    for (int j = 0; j < 4; j++) {
      const bf16x8 bf = *reinterpret_cast<const bf16x8*>(&Bk[j * 16 + (lane & 15)][koff]);
      acc[j] = __builtin_amdgcn_mfma_f32_16x16x32_bf16(af, bf, (f32x4){0.f, 0.f, 0.f, 0.f}, 0, 0, 0);
    }
    float psum[4] = {0.f, 0.f, 0.f, 0.f};
#pragma unroll
    for (int j = 0; j < 4; j++) {
      const int m = m0 + j * 16 + (lane & 15);
#pragma unroll
      for (int r = 0; r < 4; r++) {
        const int n = n0 + w * 16 + (lane >> 4) * 4 + r;
        float e = 0.f;
        if (m < N) e = __expf(acc[j][r]);
        if (m < Np && n < N) Sbf[((size_t)b * N + n) * Np + m] = f2bf(e);
        psum[r] += e;
      }
    }
    // reduce psum over the 16 lanes of each quarter-wave (they vary m)
#pragma unroll
    for (int d = 1; d < 16; d <<= 1) {
#pragma unroll
      for (int r = 0; r < 4; r++) psum[r] += __shfl_xor(psum[r], d, 64);
    }
    if ((lane & 15) == 0) {
#pragma unroll
      for (int r = 0; r < 4; r++) {
        const int n = n0 + w * 16 + (lane >> 4) * 4 + r;
        if (n < N) atomicAdd(&rowsum[(size_t)b * N + n], psum[r]);
      }
    }
    return;
  }
  // ---- channel softmax + mcomb path ----
  {
    const int row = vid - 4352;
    const size_t idx = (size_t)row * 256 + tid;
    const float a = -Atc[idx];
    const float s = -Asc[idx];
    float ma = a, ms = s;
#pragma unroll
    for (int off = 32; off; off >>= 1) {
      ma = fmaxf(ma, __shfl_xor(ma, off, 64));
      ms = fmaxf(ms, __shfl_xor(ms, off, 64));
    }
    if ((tid & 63) == 0) { red[tid >> 6] = ma; red[4 + (tid >> 6)] = ms; }
    __syncthreads();
    if (tid == 0) {
      float m1 = red[0], m2 = red[4];
      for (int i = 1; i < 4; i++) { m1 = fmaxf(m1, red[i]); m2 = fmaxf(m2, red[4 + i]); }
      red[0] = m1; red[4] = m2;
    }
    __syncthreads();
    ma = red[0]; ms = red[4];
    __syncthreads();
    const float ea = __expf(a - ma), es = __expf(s - ms);
    float sa = ea, ss = es;
#pragma unroll
    for (int off = 32; off; off >>= 1) {
      sa += __shfl_xor(sa, off, 64);
      ss += __shfl_xor(ss, off, 64);
    }
    if ((tid & 63) == 0) { red[tid >> 6] = sa; red[4 + (tid >> 6)] = ss; }
    __syncthreads();
    if (tid == 0) {
      float t1 = 0.f, t2 = 0.f;
      for (int i = 0; i < 4; i++) { t1 += red[i]; t2 += red[4 + i]; }
      red[0] = t1; red[4] = t2;
    }
    __syncthreads();
    const float Pa = ea / red[0], Ps = es / red[4];
    Mc_t[idx] = f2bf(w_t_ch[0] * Pa + w_s2t[0] * Ps);
    Mc_s[idx] = f2bf(w_s_ch[0] * Ps + w_t2s[0] * Pa);
  }
}

// ---------------------------------------------------------------------------
// fused PV+CHAN merged GEMM (BM=128): acc = PV(v@E^T); acc *= g/rowsum[n];
// acc += Mc@xT; out_xsT = bf16(x + acc).
// ---------------------------------------------------------------------------
__global__ __launch_bounds__(256) void pv_chan_fused_kernel(
    const ushort* __restrict__ vS, const ushort* __restrict__ SS,
    const float* __restrict__ rsS, const ushort* __restrict__ McS,
    const ushort* __restrict__ xTS, const float* __restrict__ xS,
    const float* __restrict__ gS, ushort* __restrict__ xsTS, int NS_,
    int NpS_, int NRS_,
    const ushort* __restrict__ vT, const ushort* __restrict__ ST,
    const float* __restrict__ rsT, const ushort* __restrict__ McT,
    const ushort* __restrict__ xTT, const float* __restrict__ xT_,
    const float* __restrict__ gT, ushort* __restrict__ xsTT, int NT_,
    int NpT_, int NRT_) {
  constexpr int C = 256, BM = 128, NW = 4, NF = 2, WN = 2;
  __shared__ ushort Asm[BM][40];
  __shared__ ushort Bsm[64][40];
  int bx, by, bz; bool isT;
  if (!fdecode(512, 16, 2, 4, 2, bx, by, bz, isT)) return;
  const ushort* vbf = isT ? vT : vS;
  const ushort* Sbf = isT ? ST : SS;
  const float* rowsum = isT ? rsT : rsS;
  const ushort* Mc = isT ? McT : McS;
  const ushort* xTb = isT ? xTT : xTS;
  const float* x = isT ? xT_ : xS;
  const float* gp = isT ? gT : gS;
  ushort* xsT = isT ? xsTT : xsTS;
  const int N = isT ? NT_ : NS_, Np = isT ? NpT_ : NpS_;
  const int NR = isT ? NRT_ : NRS_;
  const int n0 = bx * 64, m0 = by * BM, b = bz;
  const int tid = threadIdx.x, lane = tid & 63, w = tid >> 6;
  const int wr = w / WN, wc = w % WN;
  f32x4 acc[4][NF];
#pragma unroll
  for (int i = 0; i < 4; i++)
#pragma unroll
    for (int j = 0; j < NF; j++) acc[i][j] = (f32x4){0.f, 0.f, 0.f, 0.f};
  const int koff = (lane >> 4) * 8;
  // phase 1: PV, K = Np  (B operand = un-normalized E)
  {
    const ushort* Ab = vbf + (size_t)b * C * Np;
    const ushort* Bb = Sbf + (size_t)b * (size_t)N * Np;
    for (int k0 = 0; k0 < Np; k0 += 32) {
      for (int u = tid; u < BM * 4; u += NW * 64) {
        const int row = u >> 2, seg = u & 3;
        *reinterpret_cast<uint4*>(&Asm[row][seg * 8]) =
            *reinterpret_cast<const uint4*>(&Ab[(size_t)(m0 + row) * Np + k0 + seg * 8]);
      }
      for (int u = tid; u < 64 * 4; u += NW * 64) {
        const int row = u >> 2, seg = u & 3;
        const int gn = n0 + row;
        uint4 val;
        if (gn < N)
          val = *reinterpret_cast<const uint4*>(&Bb[(size_t)gn * Np + k0 + seg * 8]);
        else
          val = make_uint4(0, 0, 0, 0);
        *reinterpret_cast<uint4*>(&Bsm[row][seg * 8]) = val;
      }
      __syncthreads();
      bf16x8 af[4], bfr[NF];
#pragma unroll
      for (int mf = 0; mf < 4; mf++)
        af[mf] = *reinterpret_cast<const bf16x8*>(&Asm[wr * 64 + mf * 16 + (lane & 15)][koff]);
#pragma unroll
      for (int nf = 0; nf < NF; nf++)
        bfr[nf] = *reinterpret_cast<const bf16x8*>(&Bsm[wc * NF * 16 + nf * 16 + (lane & 15)][koff]);
#pragma unroll
      for (int mf = 0; mf < 4; mf++)
#pragma unroll
        for (int nf = 0; nf < NF; nf++)
          acc[mf][nf] = __builtin_amdgcn_mfma_f32_16x16x32_bf16(af[mf], bfr[nf], acc[mf][nf], 0, 0, 0);
      __syncthreads();
    }
  }
  // deferred softmax normalization + gamma
  const float g = *gp;
  float fac[NF];
#pragma unroll
  for (int nf = 0; nf < NF; nf++) {
    const int gn = n0 + wc * NF * 16 + nf * 16 + (lane & 15);
    const float rs = (gn < N) ? rowsum[(size_t)b * N + gn] : 1.f;
    fac[nf] = g / rs;
  }
#pragma unroll
  for (int mf = 0; mf < 4; mf++)
#pragma unroll
    for (int nf = 0; nf < NF; nf++)
#pragma unroll
      for (int rr = 0; rr < 4; rr++) acc[mf][nf][rr] *= fac[nf];
  // phase 2: chan, K = C
  {
    const ushort* Ab = Mc + (size_t)b * C * C;
    const ushort* Bb = xTb + (size_t)b * NR * C;
    for (int k0 = 0; k0 < C; k0 += 32) {
      for (int u = tid; u < BM * 4; u += NW * 64) {
        const int row = u >> 2, seg = u & 3;
        *reinterpret_cast<uint4*>(&Asm[row][seg * 8]) =
            *reinterpret_cast<const uint4*>(&Ab[(size_t)(m0 + row) * C + k0 + seg * 8]);
      }
      for (int u = tid; u < 64 * 4; u += NW * 64) {
        const int row = u >> 2, seg = u & 3;
        *reinterpret_cast<uint4*>(&Bsm[row][seg * 8]) =
            *reinterpret_cast<const uint4*>(&Bb[(size_t)(n0 + row) * C + k0 + seg * 8]);
      }
      __syncthreads();
      bf16x8 af[4], bfr[NF];
#pragma unroll
      for (int mf = 0; mf < 4; mf++)
        af[mf] = *reinterpret_cast<const bf16x8*>(&Asm[wr * 64 + mf * 16 + (lane & 15)][koff]);
#pragma unroll
      for (int nf = 0; nf < NF; nf++)
        bfr[nf] = *reinterpret_cast<const bf16x8*>(&Bsm[wc * NF * 16 + nf * 16 + (lane & 15)][koff]);
#pragma unroll
      for (int mf = 0; mf < 4; mf++)
#pragma unroll
        for (int nf = 0; nf < NF; nf++)
          acc[mf][nf] = __builtin_amdgcn_mfma_f32_16x16x32_bf16(af[mf], bfr[nf], acc[mf][nf], 0, 0, 0);
      __syncthreads();
    }
  }
#pragma unroll
  for (int mf = 0; mf < 4; mf++) {
    const int mbase = m0 + wr * 64 + mf * 16 + ((lane >> 4) * 4);
#pragma unroll
    for (int nf = 0; nf < NF; nf++) {
      const int gn = n0 + wc * NF * 16 + nf * 16 + (lane & 15);
      if (gn < N) {
        float s[4];
#pragma unroll
        for (int rr = 0; rr < 4; rr++)
          s[rr] = x[((size_t)b * C + mbase + rr) * N + gn] + acc[mf][nf][rr];
        uint lo = (uint)f2bf(s[0]) | ((uint)f2bf(s[1]) << 16);
        uint hi = (uint)f2bf(s[2]) | ((uint)f2bf(s[3]) << 16);
        *reinterpret_cast<uint2*>(&xsT[((size_t)b * NR + gn) * C + mbase]) =
            make_uint2(lo, hi);
      }
    }
  }
}

// ---------------------------------------------------------------------------
// fused offconv via MFMA on xsT, WITH FUSED gather-table prep
// ---------------------------------------------------------------------------
__global__ __launch_bounds__(256) void offconv_prep_fused_kernel(
    const ushort* __restrict__ xS, const ushort* __restrict__ owS,
    const float* __restrict__ obS, uint4* __restrict__ prS, int HS_, int WS_,
    int NS_, int NRS_,
    const ushort* __restrict__ xT, const ushort* __restrict__ owT,
    const float* __restrict__ obT, uint4* __restrict__ prT, int HT_, int WT_,
    int NT_, int NRT_) {
  __shared__ ushort Asm[32][136];
  __shared__ ushort Bsm[64][136];
  __shared__ int qsrc[64];
  __shared__ float som[27][65];
  int bx, by, bz; bool isT;
  if (!fdecode(256, 16, 1, 4, 1, bx, by, bz, isT)) return;
  const ushort* xsT = isT ? xT : xS;
  const ushort* owb = isT ? owT : owS;
  const float* ob = isT ? obT : obS;
  uint4* prep = isT ? prT : prS;
  const int H = isT ? HT_ : HS_, Wd = isT ? WT_ : WS_;
  const int N = isT ? NT_ : NS_, NR = isT ? NRT_ : NRS_;
  const int n0 = bx * 64, b = bz;
  const int tid = threadIdx.x, lane = tid & 63, w = tid >> 6;
  const ushort* xb = xsT + (size_t)b * NR * 256;
  f32x4 acc[2];
  acc[0] = (f32x4){0.f, 0.f, 0.f, 0.f};
  acc[1] = (f32x4){0.f, 0.f, 0.f, 0.f};
  for (int tap = 0; tap < 9; ++tap) {
    const int dy = tap / 3 - 1, dx = tap - (tap / 3) * 3 - 1;
    if (tid < 64) {
      const int p = n0 + tid;
      int q = -1;
      if (p < N) {
        const int h = p / Wd, ww = p - (p / Wd) * Wd;
        const int yy = h + dy, xx = ww + dx;
        if (yy >= 0 && yy < H && xx >= 0 && xx < Wd) q = yy * Wd + xx;
      }
      qsrc[tid] = q;
    }
    __syncthreads();
#pragma unroll
    for (int half = 0; half < 2; ++half) {
      const int k0 = tap * 256 + half * 128;
      for (int u = tid; u < 512; u += 256) {
        const int row = u >> 4, seg = u & 15;
        *reinterpret_cast<uint4*>(&Asm[row][seg * 8]) =
            *reinterpret_cast<const uint4*>(&owb[(size_t)row * 2304 + k0 + seg * 8]);
      }
      for (int u = tid; u < 1024; u += 256) {
        const int row = u >> 4, seg = u & 15;
        const int q = qsrc[row];
        uint4 val = make_uint4(0, 0, 0, 0);
        if (q >= 0)
          val = *reinterpret_cast<const uint4*>(&xb[(size_t)q * 256 + half * 128 + seg * 8]);
        *reinterpret_cast<uint4*>(&Bsm[row][seg * 8]) = val;
      }
      __syncthreads();
#pragma unroll
      for (int sub = 0; sub < 4; ++sub) {
        const int koff = sub * 32 + (lane >> 4) * 8;
        const bf16x8 b0 = *reinterpret_cast<const bf16x8*>(&Bsm[w * 16 + (lane & 15)][koff]);
#pragma unroll
        for (int mf = 0; mf < 2; ++mf) {
          const bf16x8 a0 = *reinterpret_cast<const bf16x8*>(&Asm[mf * 16 + (lane & 15)][koff]);
          acc[mf] = __builtin_amdgcn_mfma_f32_16x16x32_bf16(a0, b0, acc[mf], 0, 0, 0);
        }
      }
      __syncthreads();
    }
  }
#pragma unroll
  for (int mf = 0; mf < 2; ++mf) {
#pragma unroll
    for (int r = 0; r < 4; ++r) {
      const int o = mf * 16 + (lane >> 4) * 4 + r;
      const int n = w * 16 + (lane & 15);
      if (o < 27) som[o][n] = acc[mf][r] + ob[o];
    }
  }
  __syncthreads();
  for (int u = tid; u < 576; u += 256) {
    const int tap = u / 64, pp = u - (u / 64) * 64;
    const int p = n0 + pp;
    if (p >= N) continue;
    const float offy = som[tap][pp];
    const float offx = som[9 + tap][pp];
    const float mraw = som[18 + tap][pp];
    const float mval = 1.f / (1.f + __expf(-mraw));
    const int ky = tap / 3, kx = tap - (tap / 3) * 3;
    const int h = p / Wd, ww = p - (p / Wd) * Wd;
    const float py = offy + (float)(h + ky - 1);
    const float px = offx + (float)(ww + kx - 1);
    const float y0f = floorf(py), x0f = floorf(px);
    const float wy = py - y0f, wx = px - x0f;
    const int y0 = (int)y0f, x0 = (int)x0f;
    const int ys0 = min(max(y0, 0), H - 2);
    const int xs0 = min(max(x0, 0), Wd - 2);
    const float wr0 = (ys0 == y0) ? (1.f - wy) : ((ys0 == y0 + 1) ? wy : 0.f);
    const float wr1 = (ys0 + 1 == y0) ? (1.f - wy) : ((ys0 + 1 == y0 + 1) ? wy : 0.f);
    const float wc0 = (xs0 == x0) ? (1.f - wx) : ((xs0 == x0 + 1) ? wx : 0.f);
    const float wc1 = (xs0 + 1 == x0) ? (1.f - wx) : ((xs0 + 1 == x0 + 1) ? wx : 0.f);
    const float w00 = wr0 * wc0 * mval, w01 = wr0 * wc1 * mval;
    const float w10 = wr1 * wc0 * mval, w11 = wr1 * wc1 * mval;
    uint4 pk;
    pk.x = (uint)(ys0 * Wd + xs0);
    pk.y = (uint)f2bf(w00) | ((uint)f2bf(w01) << 16);
    pk.z = (uint)f2bf(w10) | ((uint)f2bf(w11) << 16);
    pk.w = 0;
    prep[((size_t)b * 9 + tap) * N + p] = pk;
  }
}

// ---------------------------------------------------------------------------
// fused DCN via MFMA (r14 best config)
// ---------------------------------------------------------------------------
__global__ __launch_bounds__(512) void dcn_fused_kernel(
    const ushort* __restrict__ xS, const uint4* __restrict__ prS,
    const ushort* __restrict__ AwS, const float* __restrict__ biS,
    float* __restrict__ oS, int NS_, int WS_, int NRS_,
    const ushort* __restrict__ xT, const uint4* __restrict__ prT,
    const ushort* __restrict__ AwT, const float* __restrict__ biT,
    float* __restrict__ oT, int NT_, int WT_, int NRT_) {
  constexpr int C = 256, MF = 4;
  __shared__ ushort Bsm[32][72];
  __shared__ int sq[32];
  __shared__ float swl[4][32];
  int bx, by, bz; bool isT;
  if (!fdecode(512, 32, 1, 8, 1, bx, by, bz, isT)) return;
  const ushort* xsT = isT ? xT : xS;
  const uint4* prep = isT ? prT : prS;
  const ushort* Awb = isT ? AwT : AwS;
  const float* bias = isT ? biT : biS;
  float* out = isT ? oT : oS;
  const int N = isT ? NT_ : NS_, Wd = isT ? WT_ : WS_, NR = isT ? NRT_ : NRS_;
  const int n0 = bx * 32, b = bz;
  const int tid = threadIdx.x, lane = tid & 63, w = tid >> 6;
  const int wr = w >> 1, wc = w & 1;
  const ushort* xb = xsT + (size_t)b * NR * C;
  const int un0 = tid >> 5;
  const int un1 = un0 + 16;
  const int kk2 = (tid & 31) * 2;
  f32x4 acc[MF];
#pragma unroll
  for (int i = 0; i < MF; i++) acc[i] = (f32x4){0.f, 0.f, 0.f, 0.f};
  uint bReg[2][4];
  int sqr0 = 0, sqr1 = 0;
  float w0a[4], w1a[4];
  const size_t rowYp = (size_t)Wd * C;
  for (int tap = 0; tap < 9; ++tap) {
    if (tid < 32) {
      const int p = n0 + tid;
      if (p < N) {
        const uint4 pk = prep[((size_t)b * 9 + tap) * N + p];
        sq[tid] = (int)pk.x * C;
        swl[0][tid] = bf2f((ushort)(pk.y & 0xffff));
        swl[1][tid] = bf2f((ushort)(pk.y >> 16));
        swl[2][tid] = bf2f((ushort)(pk.z & 0xffff));
        swl[3][tid] = bf2f((ushort)(pk.z >> 16));
      } else {
        sq[tid] = 0;
        swl[0][tid] = swl[1][tid] = swl[2][tid] = swl[3][tid] = 0.f;
      }
    }
    __syncthreads();
    sqr0 = sq[un0];
    sqr1 = sq[un1];
#pragma unroll
    for (int q = 0; q < 4; q++) {
      w0a[q] = swl[q][un0];
      w1a[q] = swl[q][un1];
    }
    {
      const ushort* pA = xb + sqr0 + kk2;
      bReg[0][0] = *reinterpret_cast<const uint*>(pA);
      bReg[0][1] = *reinterpret_cast<const uint*>(pA + C);
      bReg[0][2] = *reinterpret_cast<const uint*>(pA + rowYp);
      bReg[0][3] = *reinterpret_cast<const uint*>(pA + rowYp + C);
      const ushort* pB = xb + sqr1 + kk2;
      bReg[1][0] = *reinterpret_cast<const uint*>(pB);
      bReg[1][1] = *reinterpret_cast<const uint*>(pB + C);
      bReg[1][2] = *reinterpret_cast<const uint*>(pB + rowYp);
      bReg[1][3] = *reinterpret_cast<const uint*>(pB + rowYp + C);
    }
#pragma unroll
    for (int ks = 0; ks < 4; ++ks) {
      bf16x8 afr[2][4];
      const int ktb = tap * 8 + ks * 2;
#pragma unroll
      for (int sub = 0; sub < 2; ++sub)
#pragma unroll
        for (int mf = 0; mf < 4; ++mf)
          afr[sub][mf] = *reinterpret_cast<const bf16x8*>(
              Awb + ((((size_t)(wr * 4 + mf) * 72) + ktb + sub) << 9) + lane * 8);
      {
        const float vlo0 = w0a[0] * bflo(bReg[0][0]) + w0a[1] * bflo(bReg[0][1]) +
                           w0a[2] * bflo(bReg[0][2]) + w0a[3] * bflo(bReg[0][3]);
        const float vhi0 = w0a[0] * bfhi(bReg[0][0]) + w0a[1] * bfhi(bReg[0][1]) +
                           w0a[2] * bfhi(bReg[0][2]) + w0a[3] * bfhi(bReg[0][3]);
        *reinterpret_cast<uint*>(&Bsm[un0][kk2]) =
            (uint)f2bf(vlo0) | ((uint)f2bf(vhi0) << 16);
        const float vlo1 = w1a[0] * bflo(bReg[1][0]) + w1a[1] * bflo(bReg[1][1]) +
                           w1a[2] * bflo(bReg[1][2]) + w1a[3] * bflo(bReg[1][3]);
        const float vhi1 = w1a[0] * bfhi(bReg[1][0]) + w1a[1] * bfhi(bReg[1][1]) +
                           w1a[2] * bfhi(bReg[1][2]) + w1a[3] * bfhi(bReg[1][3]);
        *reinterpret_cast<uint*>(&Bsm[un1][kk2]) =
            (uint)f2bf(vlo1) | ((uint)f2bf(vhi1) << 16);
      }
      __syncthreads();
      if (ks < 3) {
        const int c1 = (ks + 1) * 64;
        const ushort* pA = xb + sqr0 + c1 + kk2;
        bReg[0][0] = *reinterpret_cast<const uint*>(pA);
        bReg[0][1] = *reinterpret_cast<const uint*>(pA + C);
        bReg[0][2] = *reinterpret_cast<const uint*>(pA + rowYp);
        bReg[0][3] = *reinterpret_cast<const uint*>(pA + rowYp + C);
        const ushort* pB = xb + sqr1 + c1 + kk2;
        bReg[1][0] = *reinterpret_cast<const uint*>(pB);
        bReg[1][1] = *reinterpret_cast<const uint*>(pB + C);
        bReg[1][2] = *reinterpret_cast<const uint*>(pB + rowYp);
        bReg[1][3] = *reinterpret_cast<const uint*>(pB + rowYp + C);
      }
#pragma unroll
      for (int sub = 0; sub < 2; ++sub) {
        const int koff = sub * 32 + (lane >> 4) * 8;
        const bf16x8 bfv = *reinterpret_cast<const bf16x8*>(&Bsm[wc * 16 + (lane & 15)][koff]);
#pragma unroll
        for (int mf = 0; mf < MF; mf++)
          acc[mf] = __builtin_amdgcn_mfma_f32_16x16x32_bf16(afr[sub][mf], bfv, acc[mf], 0, 0, 0);
      }
      __syncthreads();
    }
  }
  const int gn = n0 + wc * 16 + (lane & 15);
#pragma unroll
  for (int mf = 0; mf < MF; mf++) {
    const int mbase = wr * 64 + mf * 16 + ((lane >> 4) * 4);
    if (gn < N) {
#pragma unroll
      for (int rr = 0; rr < 4; rr++)
        out[((size_t)b * C + mbase + rr) * N + gn] = acc[mf][rr] + bias[mbase + rr];
    }
  }
}

// ---------------------------------------------------------------------------
extern "C" void kernel_launch(void* const* d_in, const int* in_sizes, int n_in,
                              void* d_out, int out_size, void* d_ws, size_t ws_size,
                              hipStream_t stream) {
  const float* t_in = (const float*)d_in[0];
  const float* s_in = (const float*)d_in[1];
  const float* t_qw = (const float*)d_in[2];
  const float* t_qb = (const float*)d_in[3];
  const float* t_kw = (const float*)d_in[4];
  const float* t_kb = (const float*)d_in[5];
  const float* t_vw = (const float*)d_in[6];
  const float* t_vb = (const float*)d_in[7];
  const float* t_g = (const float*)d_in[8];
  const float* s_qw = (const float*)d_in[9];
  const float* s_qb = (const float*)d_in[10];
  const float* s_kw = (const float*)d_in[11];
  const float* s_kb = (const float*)d_in[12];
  const float* s_vw = (const float*)d_in[13];
  const float* s_vb = (const float*)d_in[14];
  const float* s_g = (const float*)d_in[15];
  const float* w_t_ch = (const float*)d_in[16];
  const float* w_s_ch = (const float*)d_in[17];
  const float* w_s2t = (const float*)d_in[18];
  const float* w_t2s = (const float*)d_in[19];
  const float* t_off_w = (const float*)d_in[20];
  const float* t_off_b = (const float*)d_in[21];
  const float* t_dcn_w = (const float*)d_in[22];
  const float* t_dcn_b = (const float*)d_in[23];
  const float* s_off_w = (const float*)d_in[24];
  const float* s_off_b = (const float*)d_in[25];
  const float* s_dcn_w = (const float*)d_in[26];
  const float* s_dcn_b = (const float*)d_in[27];
  (void)in_sizes; (void)n_in; (void)out_size; (void)ws_size;

  constexpr int Bn = 16, C = 256;
  constexpr int HT = 15, WT = 15, NT = HT * WT;    // 225
  constexpr int HS = 31, WS2 = 31, NS = HS * WS2;  // 961
  constexpr int NpT = 256, NpS = 992;
  constexpr int NRT = 256, NRS = 1024;

  float* ws = (float*)d_ws;
  size_t off = 0;
  auto alloc = [&](size_t n) {
    n = (n + 3) & ~(size_t)3;
    float* p = ws + off; off += n; return p;
  };
  auto allocU = [&](size_t nu) { return (ushort*)alloc((nu + 1) / 2); };

  float* qk_t = alloc((size_t)Bn * 64 * NT);
  float* qk_s = alloc((size_t)Bn * 64 * NS);
  ushort* Wall_t = allocU((size_t)320 * C);
  ushort* Wall_s = allocU((size_t)320 * C);
  float* biasAll_t = alloc(320);
  float* biasAll_s = alloc(320);
  ushort* xT_t = allocU((size_t)Bn * NRT * C);
  ushort* xT_s = allocU((size_t)Bn * NRS * C);
  ushort* xbf_t = allocU((size_t)Bn * C * NpT);
  ushort* xbf_s = allocU((size_t)Bn * C * NpS);
  ushort* v_tbf = allocU((size_t)Bn * C * NpT);
  ushort* v_sbf = allocU((size_t)Bn * C * NpS);
  ushort* S_t = allocU((size_t)Bn * NT * NpT);
  ushort* S_s = allocU((size_t)Bn * NS * NpS);
  float* rs_t = alloc((size_t)Bn * NT);
  float* rs_s = alloc((size_t)Bn * NS);
  ushort* xsT_t = allocU((size_t)Bn * NRT * C);
  ushort* xsT_s = allocU((size_t)Bn * NRS * C);
  float* Atc = alloc((size_t)Bn * C * C);
  float* Asc = alloc((size_t)Bn * C * C);
  ushort* Mc_t = allocU((size_t)Bn * C * C);
  ushort* Mc_s = allocU((size_t)Bn * C * C);
  ushort* owb_t = allocU((size_t)32 * 2304);
  ushort* owb_s = allocU((size_t)32 * 2304);
  ushort* Awb_t = allocU((size_t)256 * 2304);
  ushort* Awb_s = allocU((size_t)256 * 2304);
  uint4* prep_t = (uint4*)alloc((size_t)Bn * 9 * NT * 4);
  uint4* prep_s = (uint4*)alloc((size_t)Bn * 9 * NS * 4);

  dim3 blk(256);

  // 1. UNION A: weight prep (5832) + cast/transpose/pad (1280) + rowsum zero (75)
  prep_cast_fused_kernel<<<dim3(5832 + 1280 + 75), blk, 0, stream>>>(
      t_qw, t_qb, t_kw, t_kb, s_qw, s_qb, s_kw, s_kb,
      t_vw, t_vb, s_vw, s_vb, t_off_w, s_off_w, t_dcn_w, s_dcn_w,
      Wall_t, Wall_s, biasAll_t, biasAll_s, owb_t, owb_s, Awb_t, Awb_s,
      s_in, xT_s, xbf_s, NS, NRS, NpS, t_in, xT_t, xbf_t, NT, NRT, NpT,
      rs_s, rs_t);

  // 2. UNION B: combined projection GEMM (1600) + gram GEMM (256)
  proj_gram_fused_kernel<<<dim3(1600 + 256), blk, 0, stream>>>(
      Wall_s, biasAll_s, xT_s, v_sbf, qk_s, NS, NpS, NRS,
      Wall_t, biasAll_t, xT_t, v_tbf, qk_t, NT, NpT, NRT,
      xbf_s, Asc, NpS, xbf_t, Atc, NpT);

  // 3. UNION C: energy+exp+rowsum (4352) + channel softmax/mcomb (4096)
  energy_mcomb_fused_kernel<<<dim3(4352 + 4096), blk, 0, stream>>>(
      qk_s, S_s, NS, NpS, qk_t, S_t, NT, NpT, rs_s, rs_t,
      Atc, Asc, w_t_ch, w_s2t, w_s_ch, w_t2s, Mc_t, Mc_s);

  // 4. merged PV + chan GEMM -> xsT (deferred softmax normalization)
  pv_chan_fused_kernel<<<dim3(640), blk, 0, stream>>>(
      v_sbf, S_s, rs_s, Mc_s, xT_s, s_in, s_g, xsT_s, NS, NpS, NRS,
      v_tbf, S_t, rs_t, Mc_t, xT_t, t_in, t_g, xsT_t, NT, NpT, NRT);

  // 5. fused offconv + gather-table prep
  offconv_prep_fused_kernel<<<dim3(320), blk, 0, stream>>>(
      xsT_s, owb_s, s_off_b, prep_s, HS, WS2, NS, NRS,
      xsT_t, owb_t, t_off_b, prep_t, HT, WT, NT, NRT);

  // 6. fused DCN (r14 best config)
  float* out_t = (float*)d_out;
  float* out_s = out_t + (size_t)Bn * C * NT;
  dcn_fused_kernel<<<dim3(640), dim3(512), 0, stream>>>(
      xsT_s, prep_s, Awb_s, s_dcn_b, out_s, NS, WS2, NRS,
      xsT_t, prep_t, Awb_t, t_dcn_b, out_t, NT, WT, NRT);
}

// Round 22
// 255.200 us; speedup vs baseline: 1.4070x; 1.0061x over previous
//
#include <hip/hip_runtime.h>
#include <hip/hip_bf16.h>
#include <cmath>

typedef __attribute__((ext_vector_type(8))) short bf16x8;
typedef __attribute__((ext_vector_type(4))) float f32x4;

__device__ inline ushort f2bf(float f) {
  __hip_bfloat16 h = __float2bfloat16(f);
  return *reinterpret_cast<ushort*>(&h);
}
__device__ inline float bf2f(ushort u) {
  return __uint_as_float((uint)u << 16);
}
__device__ inline float bflo(uint x) { return __uint_as_float(x << 16); }
__device__ inline float bfhi(uint x) { return __uint_as_float(x & 0xffff0000u); }

// Fused-side decode with XCD-aware bijective chunking (physical grid).
__device__ inline bool fdecode(int totalS, int gxS, int gyS, int gxT, int gyT,
                               int& bx, int& by, int& bz, bool& isT) {
  const int total = gridDim.x;
  const int id = blockIdx.x;
  int wid = (id & 7) * (total >> 3) + (id >> 3);
  const int totalT = gxT * gyT * 16;
  if (wid >= totalS + totalT) return false;
  isT = wid >= totalS;
  int lid = isT ? wid - totalS : wid;
  const int gx = isT ? gxT : gxS;
  const int gy = isT ? gyT : gyS;
  bx = lid % gx;
  lid /= gx;
  by = lid % gy;
  bz = lid / gy;
  return true;
}

// Virtual-grid variant for unioned kernels: v in [0, vtotal), vtotal % 8 == 0.
__device__ inline void vdecode(int v, int vtotal, int totalS, int gxS, int gyS,
                               int gxT, int gyT, int& bx, int& by, int& bz,
                               bool& isT) {
  int wid = (v & 7) * (vtotal >> 3) + (v >> 3);
  isT = wid >= totalS;
  int lid = isT ? wid - totalS : wid;
  const int gx = isT ? gxT : gxS;
  const int gy = isT ? gyT : gyS;
  bx = lid % gx;
  lid /= gx;
  by = lid % gy;
  bz = lid / gy;
}

// ---------------------------------------------------------------------------
// UNION A: weight prep (virtual [0,5832)) + cast/transpose/pad
// (virtual [5832, 7112)).
// ---------------------------------------------------------------------------
__global__ __launch_bounds__(256) void prep_cast_fused_kernel(
    const float* __restrict__ t_qw, const float* __restrict__ t_qb,
    const float* __restrict__ t_kw, const float* __restrict__ t_kb,
    const float* __restrict__ s_qw, const float* __restrict__ s_qb,
    const float* __restrict__ s_kw, const float* __restrict__ s_kb,
    const float* __restrict__ t_vw, const float* __restrict__ t_vb,
    const float* __restrict__ s_vw, const float* __restrict__ s_vb,
    const float* __restrict__ t_off_w, const float* __restrict__ s_off_w,
    const float* __restrict__ t_dcn_w, const float* __restrict__ s_dcn_w,
    ushort* __restrict__ Wall_t, ushort* __restrict__ Wall_s,
    float* __restrict__ biasAll_t, float* __restrict__ biasAll_s,
    ushort* __restrict__ owb_t, ushort* __restrict__ owb_s,
    ushort* __restrict__ Awb_t, ushort* __restrict__ Awb_s,
    const float* __restrict__ xS, ushort* __restrict__ oS,
    ushort* __restrict__ pS, int NS_, int NRS_, int NpS_,
    const float* __restrict__ xT, ushort* __restrict__ oT,
    ushort* __restrict__ pT, int NT_, int NRT_, int NpT_) {
  __shared__ float T[64][65];
  const int tid = threadIdx.x;
  const int vid = blockIdx.x;
  if (vid < 5832) {
    // ---- weight prep path ----
    int i = vid * 256 + tid;
    if (i < 81920) {
      const int r = i >> 8, c = i & 255;
      float v;
      if (r < 256) v = t_vw[(size_t)r * 256 + c];
      else if (r < 288) v = t_qw[(size_t)(r - 256) * 256 + c];
      else v = t_kw[(size_t)(r - 288) * 256 + c];
      Wall_t[i] = f2bf(v);
      return;
    }
    i -= 81920;
    if (i < 81920) {
      const int r = i >> 8, c = i & 255;
      float v;
      if (r < 256) v = s_vw[(size_t)r * 256 + c];
      else if (r < 288) v = s_qw[(size_t)(r - 256) * 256 + c];
      else v = s_kw[(size_t)(r - 288) * 256 + c];
      Wall_s[i] = f2bf(v);
      return;
    }
    i -= 81920;
    if (i < 320) {
      biasAll_t[i] = (i < 256) ? t_vb[i] : ((i < 288) ? t_qb[i - 256] : t_kb[i - 288]);
      return;
    }
    i -= 320;
    if (i < 320) {
      biasAll_s[i] = (i < 256) ? s_vb[i] : ((i < 288) ? s_qb[i - 256] : s_kb[i - 288]);
      return;
    }
    i -= 320;
    if (i < 73728) {
      const int o = i / 2304, k = i % 2304, tap = k >> 8, c = k & 255;
      owb_t[i] = (o < 27) ? f2bf(t_off_w[(size_t)o * 2304 + c * 9 + tap]) : (ushort)0;
      return;
    }
    i -= 73728;
    if (i < 73728) {
      const int o = i / 2304, k = i % 2304, tap = k >> 8, c = k & 255;
      owb_s[i] = (o < 27) ? f2bf(s_off_w[(size_t)o * 2304 + c * 9 + tap]) : (ushort)0;
      return;
    }
    i -= 73728;
    if (i < 589824) {
      const int frag = i >> 9, within = i & 511;
      const int lane = within >> 3, j = within & 7;
      const int mt = frag / 72, kt = frag % 72;
      const int o = mt * 16 + (lane & 15);
      const int k = kt * 32 + (lane >> 4) * 8 + j;
      const int tap = k >> 8, c = k & 255;
      Awb_t[i] = f2bf(t_dcn_w[(size_t)o * 2304 + c * 9 + tap]);
      return;
    }
    i -= 589824;
    if (i < 589824) {
      const int frag = i >> 9, within = i & 511;
      const int lane = within >> 3, j = within & 7;
      const int mt = frag / 72, kt = frag % 72;
      const int o = mt * 16 + (lane & 15);
      const int k = kt * 32 + (lane >> 4) * 8 + j;
      const int tap = k >> 8, c = k & 255;
      Awb_s[i] = f2bf(s_dcn_w[(size_t)o * 2304 + c * 9 + tap]);
    }
    return;
  }
  // ---- cast+transpose+pad path ----
  constexpr int C = 256;
  int bx, by, bz; bool isT;
  vdecode(vid - 5832, 1280, 1024, 16, 4, 4, 4, bx, by, bz, isT);
  const float* x = isT ? xT : xS;
  ushort* xTo = isT ? oT : oS;
  ushort* xbf = isT ? pT : pS;
  const int N = isT ? NT_ : NS_;
  const int NR = isT ? NRT_ : NRS_;
  const int Np = isT ? NpT_ : NpS_;
  const int b = bz;
  const int n0 = bx * 64, c0 = by * 64;
  const float* xb = x + (size_t)b * C * N;
  for (int u = tid; u < 4096; u += 256) {
    const int cc = u >> 6, nn = u & 63;
    const int gn = n0 + nn;
    T[cc][nn] = (gn < N) ? xb[(size_t)(c0 + cc) * N + gn] : 0.f;
  }
  __syncthreads();
  ushort* ob = xTo + (size_t)b * NR * C;
  for (int u = tid; u < 4096; u += 256) {
    const int nn = u >> 6, cc = u & 63;
    ob[(size_t)(n0 + nn) * C + c0 + cc] = f2bf(T[cc][nn]);
  }
  ushort* pb = xbf + (size_t)b * C * Np;
  for (int u = tid; u < 4096; u += 256) {
    const int cc = u >> 6, nn = u & 63;
    const int gn = n0 + nn;
    if (gn < Np) pb[(size_t)(c0 + cc) * Np + gn] = f2bf(T[cc][nn]);
  }
}

// ---------------------------------------------------------------------------
// UNION B: combined projection GEMM (virtual [0,1600)) + gram GEMM
// (virtual [1600, 1600+256)). Shared LDS: Asm[128][40].
// ---------------------------------------------------------------------------
__global__ __launch_bounds__(256) void proj_gram_fused_kernel(
    const ushort* __restrict__ WallS, const float* __restrict__ bS,
    const ushort* __restrict__ BtS, ushort* __restrict__ vS,
    float* __restrict__ qkS, int NS_, int NpS_, int NRS_,
    const ushort* __restrict__ WallT, const float* __restrict__ bT,
    const ushort* __restrict__ BtT, ushort* __restrict__ vT,
    float* __restrict__ qkT, int NT_, int NpT_, int NRT_,
    const ushort* __restrict__ xbfS, float* __restrict__ AscP, int KpS_,
    const ushort* __restrict__ xbfT, float* __restrict__ AtcP, int KpT_) {
  constexpr int C = 256;
  __shared__ ushort Asm[128][40];
  __shared__ ushort Bsm[64][40];
  const int tid = threadIdx.x, lane = tid & 63, w = tid >> 6;
  const int vid = blockIdx.x;
  if (vid < 1600) {
    // ---- proj path ----
    int bx, by, bz; bool isT;
    vdecode(vid, 1600, 1280, 16, 5, 4, 5, bx, by, bz, isT);
    const ushort* Wall = isT ? WallT : WallS;
    const float* bias = isT ? bT : bS;
    const ushort* Bt = isT ? BtT : BtS;
    ushort* vbf = isT ? vT : vS;
    float* qk = isT ? qkT : qkS;
    const int N = isT ? NT_ : NS_, Np = isT ? NpT_ : NpS_, NR = isT ? NRT_ : NRS_;
    const int n0 = bx * 64, m0 = by * 64, b = bz;
    const ushort* Ab = Wall + (size_t)m0 * C;
    const ushort* Bb = Bt + (size_t)b * NR * C;
    f32x4 acc[4];
#pragma unroll
    for (int i = 0; i < 4; i++) acc[i] = (f32x4){0.f, 0.f, 0.f, 0.f};
    for (int k0 = 0; k0 < C; k0 += 32) {
      {
        const int row = tid >> 2, seg = tid & 3;
        *reinterpret_cast<uint4*>(&Asm[row][seg * 8]) =
            *reinterpret_cast<const uint4*>(&Ab[(size_t)row * C + k0 + seg * 8]);
        *reinterpret_cast<uint4*>(&Bsm[row][seg * 8]) =
            *reinterpret_cast<const uint4*>(&Bb[(size_t)(n0 + row) * C + k0 + seg * 8]);
      }
      __syncthreads();
      const int koff = (lane >> 4) * 8;
      const bf16x8 bfr = *reinterpret_cast<const bf16x8*>(&Bsm[w * 16 + (lane & 15)][koff]);
#pragma unroll
      for (int mf = 0; mf < 4; mf++) {
        const bf16x8 af = *reinterpret_cast<const bf16x8*>(&Asm[mf * 16 + (lane & 15)][koff]);
        acc[mf] = __builtin_amdgcn_mfma_f32_16x16x32_bf16(af, bfr, acc[mf], 0, 0, 0);
      }
      __syncthreads();
    }
    const int gn = n0 + w * 16 + (lane & 15);
#pragma unroll
    for (int mf = 0; mf < 4; mf++) {
      const int mbase = m0 + mf * 16 + ((lane >> 4) * 4);
#pragma unroll
      for (int rr = 0; rr < 4; rr++) {
        const int m = mbase + rr;
        if (m < 256) {
          if (gn < Np) {
            ushort v = (gn < N) ? f2bf(acc[mf][rr] + bias[m]) : (ushort)0;
            vbf[((size_t)b * 256 + m) * Np + gn] = v;
          }
        } else {
          if (gn < N)
            qk[((size_t)b * 64 + (m - 256)) * N + gn] = acc[mf][rr] + bias[m];
        }
      }
    }
    return;
  }
  // ---- gram path ----
  {
    constexpr int BM = 128, NW = 4, NF = 2, WN = 2;
    int bx, by, bz; bool isT;
    vdecode(vid - 1600, 256, 128, 4, 2, 4, 2, bx, by, bz, isT);
    const ushort* A = isT ? xbfT : xbfS;
    float* outF = isT ? AtcP : AscP;
    const int Kp = isT ? KpT_ : KpS_;
    const int n0 = bx * 64, m0 = by * BM, b = bz;
    const ushort* Ab = A + (size_t)b * C * Kp;
    const int wr = w / WN, wc = w % WN;
    f32x4 acc[4][NF];
#pragma unroll
    for (int i = 0; i < 4; i++)
#pragma unroll
      for (int j = 0; j < NF; j++) acc[i][j] = (f32x4){0.f, 0.f, 0.f, 0.f};
    for (int k0 = 0; k0 < Kp; k0 += 32) {
      for (int u = tid; u < BM * 4; u += NW * 64) {
        const int row = u >> 2, seg = u & 3;
        *reinterpret_cast<uint4*>(&Asm[row][seg * 8]) =
            *reinterpret_cast<const uint4*>(&Ab[(size_t)(m0 + row) * Kp + k0 + seg * 8]);
      }
      for (int u = tid; u < 64 * 4; u += NW * 64) {
        const int row = u >> 2, seg = u & 3;
        *reinterpret_cast<uint4*>(&Bsm[row][seg * 8]) =
            *reinterpret_cast<const uint4*>(&Ab[(size_t)(n0 + row) * Kp + k0 + seg * 8]);
      }
      __syncthreads();
      const int koff = (lane >> 4) * 8;
      bf16x8 af[4], bfr[NF];
#pragma unroll
      for (int mf = 0; mf < 4; mf++)
        af[mf] = *reinterpret_cast<const bf16x8*>(&Asm[wr * 64 + mf * 16 + (lane & 15)][koff]);
#pragma unroll
      for (int nf = 0; nf < NF; nf++)
        bfr[nf] = *reinterpret_cast<const bf16x8*>(&Bsm[wc * NF * 16 + nf * 16 + (lane & 15)][koff]);
#pragma unroll
      for (int mf = 0; mf < 4; mf++)
#pragma unroll
        for (int nf = 0; nf < NF; nf++)
          acc[mf][nf] = __builtin_amdgcn_mfma_f32_16x16x32_bf16(af[mf], bfr[nf], acc[mf][nf], 0, 0, 0);
      __syncthreads();
    }
#pragma unroll
    for (int mf = 0; mf < 4; mf++) {
      const int mbase = m0 + wr * 64 + mf * 16 + ((lane >> 4) * 4);
#pragma unroll
      for (int nf = 0; nf < NF; nf++) {
        const int gn = n0 + wc * NF * 16 + nf * 16 + (lane & 15);
#pragma unroll
        for (int rr = 0; rr < 4; rr++)
          outF[((size_t)b * C + mbase + rr) * C + gn] = acc[mf][nf][rr];
      }
    }
  }
}

// ---------------------------------------------------------------------------
// UNION C: flash spatial attention (virtual [0,640)) + channel softmax/mcomb
// (virtual [640, 640+4096)).
// Flash: per (b, 64-col n-tile, 128-chan half): loop m-tiles {stage k-tile,
// energy MFMA, exp->Es LDS + reg rowsum, PV MFMA w/ direct-global v frags}.
// Then pvbT[b][n][256] = bf16(g * PV / rowsum). S matrix never materialized.
// ---------------------------------------------------------------------------
__global__ __launch_bounds__(256) void flash_mcomb_fused_kernel(
    const float* __restrict__ qkS, const ushort* __restrict__ vS,
    const float* __restrict__ gS, ushort* __restrict__ pvS, int NS_, int NpS_,
    const float* __restrict__ qkT, const ushort* __restrict__ vT,
    const float* __restrict__ gT, ushort* __restrict__ pvT, int NT_, int NpT_,
    const float* __restrict__ Atc, const float* __restrict__ Asc,
    const float* __restrict__ w_t_ch, const float* __restrict__ w_s2t,
    const float* __restrict__ w_s_ch, const float* __restrict__ w_t2s,
    ushort* __restrict__ Mc_t, ushort* __restrict__ Mc_s) {
  __shared__ ushort Aq[64][40];
  __shared__ ushort Bk[64][40];
  __shared__ ushort Es[64][72];
  __shared__ float rsL[64];
  __shared__ float red[8];
  const int tid = threadIdx.x;
  const int vid = blockIdx.x;
  if (vid < 640) {
    // ---- flash path ----
    int bx, by, bz; bool isT;
    vdecode(vid, 640, 512, 16, 2, 4, 2, bx, by, bz, isT);
    const float* qk = isT ? qkT : qkS;
    const ushort* vbf = isT ? vT : vS;
    const float* gp = isT ? gT : gS;
    ushort* pvb = isT ? pvT : pvS;
    const int N = isT ? NT_ : NS_, Np = isT ? NpT_ : NpS_;
    const int n0 = bx * 64, c0 = by * 128, b = bz;
    const float* qb = qk + (size_t)b * 64 * N;
    const float* kb = qb + (size_t)32 * N;
    const int lane = tid & 63, w = tid >> 6;
    const int koffE = (lane >> 4) * 8;
    // stage q tile (transposed): Aq[n][c]
    for (int u = tid; u < 2048; u += 256) {
      const int c = u >> 6, nn = u & 63;
      const int gn = n0 + nn;
      Aq[nn][c] = (gn < N) ? f2bf(qb[(size_t)c * N + gn]) : (ushort)0;
    }
    f32x4 acc[2][4];
#pragma unroll
    for (int i = 0; i < 2; i++)
#pragma unroll
      for (int j = 0; j < 4; j++) acc[i][j] = (f32x4){0.f, 0.f, 0.f, 0.f};
    float psum[4] = {0.f, 0.f, 0.f, 0.f};
    const int msteps = Np >> 6;
    const size_t vrow0 = ((size_t)b * 256 + c0 + w * 32 + (lane & 15)) * Np;
    for (int ms = 0; ms < msteps; ++ms) {
      const int m0 = ms * 64;
      // stage k tile (transposed): Bk[m][c]
      for (int u = tid; u < 2048; u += 256) {
        const int c = u >> 6, nn = u & 63;
        const int gm = m0 + nn;
        Bk[nn][c] = (gm < N) ? f2bf(kb[(size_t)c * N + gm]) : (ushort)0;
      }
      __syncthreads();  // BAR-A: Bk (and Aq) ready; prev PV done
      // energy: wave w computes rows n = w*16.., all 64 m
      const bf16x8 afq = *reinterpret_cast<const bf16x8*>(&Aq[w * 16 + (lane & 15)][koffE]);
      f32x4 eacc[4];
#pragma unroll
      for (int j = 0; j < 4; j++) {
        const bf16x8 bfk = *reinterpret_cast<const bf16x8*>(&Bk[j * 16 + (lane & 15)][koffE]);
        eacc[j] = __builtin_amdgcn_mfma_f32_16x16x32_bf16(afq, bfk, (f32x4){0.f, 0.f, 0.f, 0.f}, 0, 0, 0);
      }
      // exp -> Es + rowsum partials
#pragma unroll
      for (int j = 0; j < 4; j++) {
        const int mloc = j * 16 + (lane & 15);
        const int gm = m0 + mloc;
#pragma unroll
        for (int r = 0; r < 4; r++) {
          float e = (gm < N) ? __expf(eacc[j][r]) : 0.f;
          Es[w * 16 + (lane >> 4) * 4 + r][mloc] = f2bf(e);
          psum[r] += e;
        }
      }
      __syncthreads();  // BAR-B: Es ready
      // PV: A = v (direct global frags), B = Es
#pragma unroll
      for (int sub = 0; sub < 2; ++sub) {
        const int km = m0 + sub * 32 + koffE;
        bf16x8 afv[2];
#pragma unroll
        for (int mf = 0; mf < 2; mf++)
          afv[mf] = *reinterpret_cast<const bf16x8*>(&vbf[vrow0 + (size_t)mf * 16 * Np + km]);
#pragma unroll
        for (int nf = 0; nf < 4; nf++) {
          const bf16x8 bfe = *reinterpret_cast<const bf16x8*>(&Es[nf * 16 + (lane & 15)][sub * 32 + koffE]);
#pragma unroll
          for (int mf = 0; mf < 2; mf++)
            acc[mf][nf] = __builtin_amdgcn_mfma_f32_16x16x32_bf16(afv[mf], bfe, acc[mf][nf], 0, 0, 0);
        }
      }
      __syncthreads();  // protect Es/Bk for next iteration
    }
    // rowsum: reduce over the 16 m-lanes
#pragma unroll
    for (int d = 1; d < 16; d <<= 1) {
#pragma unroll
      for (int r = 0; r < 4; r++) psum[r] += __shfl_xor(psum[r], d, 64);
    }
    if ((lane & 15) == 0) {
#pragma unroll
      for (int r = 0; r < 4; r++) rsL[w * 16 + (lane >> 4) * 4 + r] = psum[r];
    }
    __syncthreads();
    const float g = *gp;
    float fac[4];
#pragma unroll
    for (int nf = 0; nf < 4; nf++) {
      const int nl = nf * 16 + (lane & 15);
      fac[nf] = g / rsL[nl];
    }
    // epilogue: pvbT[b][n][256] packed uint2 (4 channels)
#pragma unroll
    for (int mf = 0; mf < 2; mf++) {
      const int cb = c0 + w * 32 + mf * 16 + ((lane >> 4) * 4);
#pragma unroll
      for (int nf = 0; nf < 4; nf++) {
        const int gn = n0 + nf * 16 + (lane & 15);
        float v0 = acc[mf][nf][0] * fac[nf];
        float v1 = acc[mf][nf][1] * fac[nf];
        float v2 = acc[mf][nf][2] * fac[nf];
        float v3 = acc[mf][nf][3] * fac[nf];
        uint lo = (uint)f2bf(v0) | ((uint)f2bf(v1) << 16);
        uint hi = (uint)f2bf(v2) | ((uint)f2bf(v3) << 16);
        *reinterpret_cast<uint2*>(&pvb[((size_t)b * Np + gn) * 256 + cb]) =
            make_uint2(lo, hi);
      }
    }
    return;
  }
  // ---- channel softmax + mcomb path ----
  {
    const int row = vid - 640;
    const size_t idx = (size_t)row * 256 + tid;
    const float a = -Atc[idx];
    const float s = -Asc[idx];
    float ma = a, ms = s;
#pragma unroll
    for (int off = 32; off; off >>= 1) {
      ma = fmaxf(ma, __shfl_xor(ma, off, 64));
      ms = fmaxf(ms, __shfl_xor(ms, off, 64));
    }
    if ((tid & 63) == 0) { red[tid >> 6] = ma; red[4 + (tid >> 6)] = ms; }
    __syncthreads();
    if (tid == 0) {
      float m1 = red[0], m2 = red[4];
      for (int i = 1; i < 4; i++) { m1 = fmaxf(m1, red[i]); m2 = fmaxf(m2, red[4 + i]); }
      red[0] = m1; red[4] = m2;
    }
    __syncthreads();
    ma = red[0]; ms = red[4];
    __syncthreads();
    const float ea = __expf(a - ma), es = __expf(s - ms);
    float sa = ea, ss = es;
#pragma unroll
    for (int off = 32; off; off >>= 1) {
      sa += __shfl_xor(sa, off, 64);
      ss += __shfl_xor(ss, off, 64);
    }
    if ((tid & 63) == 0) { red[tid >> 6] = sa; red[4 + (tid >> 6)] = ss; }
    __syncthreads();
    if (tid == 0) {
      float t1 = 0.f, t2 = 0.f;
      for (int i = 0; i < 4; i++) { t1 += red[i]; t2 += red[4 + i]; }
      red[0] = t1; red[4] = t2;
    }
    __syncthreads();
    const float Pa = ea / red[0], Ps = es / red[4];
    Mc_t[idx] = f2bf(w_t_ch[0] * Pa + w_s2t[0] * Ps);
    Mc_s[idx] = f2bf(w_s_ch[0] * Ps + w_t2s[0] * Pa);
  }
}

// ---------------------------------------------------------------------------
// fused CHAN GEMM + pv add (BM=128): acc = Mc@xT; out_xsT = bf16(x + pv + acc)
// (pv term precomputed by flash kernel, already scaled by g/rowsum).
// ---------------------------------------------------------------------------
__global__ __launch_bounds__(256) void pv_chan_fused_kernel(
    const ushort* __restrict__ pvSb, const ushort* __restrict__ McS,
    const ushort* __restrict__ xTS, const float* __restrict__ xS,
    ushort* __restrict__ xsTS, int NS_, int NpS_, int NRS_,
    const ushort* __restrict__ pvTb, const ushort* __restrict__ McT,
    const ushort* __restrict__ xTT, const float* __restrict__ xT_,
    ushort* __restrict__ xsTT, int NT_, int NpT_, int NRT_) {
  constexpr int C = 256, BM = 128, NW = 4, NF = 2, WN = 2;
  __shared__ ushort Asm[BM][40];
  __shared__ ushort Bsm[64][40];
  int bx, by, bz; bool isT;
  if (!fdecode(512, 16, 2, 4, 2, bx, by, bz, isT)) return;
  const ushort* pvb = isT ? pvTb : pvSb;
  const ushort* Mc = isT ? McT : McS;
  const ushort* xTb = isT ? xTT : xTS;
  const float* x = isT ? xT_ : xS;
  ushort* xsT = isT ? xsTT : xsTS;
  const int N = isT ? NT_ : NS_, Np = isT ? NpT_ : NpS_;
  const int NR = isT ? NRT_ : NRS_;
  const int n0 = bx * 64, m0 = by * BM, b = bz;
  const int tid = threadIdx.x, lane = tid & 63, w = tid >> 6;
  const int wr = w / WN, wc = w % WN;
  f32x4 acc[4][NF];
#pragma unroll
  for (int i = 0; i < 4; i++)
#pragma unroll
    for (int j = 0; j < NF; j++) acc[i][j] = (f32x4){0.f, 0.f, 0.f, 0.f};
  const int koff = (lane >> 4) * 8;
  // chan GEMM, K = C
  {
    const ushort* Ab = Mc + (size_t)b * C * C;
    const ushort* Bb = xTb + (size_t)b * NR * C;
    for (int k0 = 0; k0 < C; k0 += 32) {
      for (int u = tid; u < BM * 4; u += NW * 64) {
        const int row = u >> 2, seg = u & 3;
        *reinterpret_cast<uint4*>(&Asm[row][seg * 8]) =
            *reinterpret_cast<const uint4*>(&Ab[(size_t)(m0 + row) * C + k0 + seg * 8]);
      }
      for (int u = tid; u < 64 * 4; u += NW * 64) {
        const int row = u >> 2, seg = u & 3;
        *reinterpret_cast<uint4*>(&Bsm[row][seg * 8]) =
            *reinterpret_cast<const uint4*>(&Bb[(size_t)(n0 + row) * C + k0 + seg * 8]);
      }
      __syncthreads();
      bf16x8 af[4], bfr[NF];
#pragma unroll
      for (int mf = 0; mf < 4; mf++)
        af[mf] = *reinterpret_cast<const bf16x8*>(&Asm[wr * 64 + mf * 16 + (lane & 15)][koff]);
#pragma unroll
      for (int nf = 0; nf < NF; nf++)
        bfr[nf] = *reinterpret_cast<const bf16x8*>(&Bsm[wc * NF * 16 + nf * 16 + (lane & 15)][koff]);
#pragma unroll
      for (int mf = 0; mf < 4; mf++)
#pragma unroll
        for (int nf = 0; nf < NF; nf++)
          acc[mf][nf] = __builtin_amdgcn_mfma_f32_16x16x32_bf16(af[mf], bfr[nf], acc[mf][nf], 0, 0, 0);
      __syncthreads();
    }
  }
#pragma unroll
  for (int mf = 0; mf < 4; mf++) {
    const int mbase = m0 + wr * 64 + mf * 16 + ((lane >> 4) * 4);
#pragma unroll
    for (int nf = 0; nf < NF; nf++) {
      const int gn = n0 + wc * NF * 16 + nf * 16 + (lane & 15);
      if (gn < N) {
        const uint2 pvw = *reinterpret_cast<const uint2*>(
            &pvb[((size_t)b * Np + gn) * 256 + mbase]);
        float s[4];
        s[0] = x[((size_t)b * C + mbase + 0) * N + gn] + bflo(pvw.x) + acc[mf][nf][0];
        s[1] = x[((size_t)b * C + mbase + 1) * N + gn] + bfhi(pvw.x) + acc[mf][nf][1];
        s[2] = x[((size_t)b * C + mbase + 2) * N + gn] + bflo(pvw.y) + acc[mf][nf][2];
        s[3] = x[((size_t)b * C + mbase + 3) * N + gn] + bfhi(pvw.y) + acc[mf][nf][3];
        uint lo = (uint)f2bf(s[0]) | ((uint)f2bf(s[1]) << 16);
        uint hi = (uint)f2bf(s[2]) | ((uint)f2bf(s[3]) << 16);
        *reinterpret_cast<uint2*>(&xsT[((size_t)b * NR + gn) * C + mbase]) =
            make_uint2(lo, hi);
      }
    }
  }
}

// ---------------------------------------------------------------------------
// fused offconv via MFMA on xsT, WITH FUSED gather-table prep
// ---------------------------------------------------------------------------
__global__ __launch_bounds__(256) void offconv_prep_fused_kernel(
    const ushort* __restrict__ xS, const ushort* __restrict__ owS,
    const float* __restrict__ obS, uint4* __restrict__ prS, int HS_, int WS_,
    int NS_, int NRS_,
    const ushort* __restrict__ xT, const ushort* __restrict__ owT,
    const float* __restrict__ obT, uint4* __restrict__ prT, int HT_, int WT_,
    int NT_, int NRT_) {
  __shared__ ushort Asm[32][136];
  __shared__ ushort Bsm[64][136];
  __shared__ int qsrc[64];
  __shared__ float som[27][65];
  int bx, by, bz; bool isT;
  if (!fdecode(256, 16, 1, 4, 1, bx, by, bz, isT)) return;
  const ushort* xsT = isT ? xT : xS;
  const ushort* owb = isT ? owT : owS;
  const float* ob = isT ? obT : obS;
  uint4* prep = isT ? prT : prS;
  const int H = isT ? HT_ : HS_, Wd = isT ? WT_ : WS_;
  const int N = isT ? NT_ : NS_, NR = isT ? NRT_ : NRS_;
  const int n0 = bx * 64, b = bz;
  const int tid = threadIdx.x, lane = tid & 63, w = tid >> 6;
  const ushort* xb = xsT + (size_t)b * NR * 256;
  f32x4 acc[2];
  acc[0] = (f32x4){0.f, 0.f, 0.f, 0.f};
  acc[1] = (f32x4){0.f, 0.f, 0.f, 0.f};
  for (int tap = 0; tap < 9; ++tap) {
    const int dy = tap / 3 - 1, dx = tap - (tap / 3) * 3 - 1;
    if (tid < 64) {
      const int p = n0 + tid;
      int q = -1;
      if (p < N) {
        const int h = p / Wd, ww = p - (p / Wd) * Wd;
        const int yy = h + dy, xx = ww + dx;
        if (yy >= 0 && yy < H && xx >= 0 && xx < Wd) q = yy * Wd + xx;
      }
      qsrc[tid] = q;
    }
    __syncthreads();
#pragma unroll
    for (int half = 0; half < 2; ++half) {
      const int k0 = tap * 256 + half * 128;
      for (int u = tid; u < 512; u += 256) {
        const int row = u >> 4, seg = u & 15;
        *reinterpret_cast<uint4*>(&Asm[row][seg * 8]) =
            *reinterpret_cast<const uint4*>(&owb[(size_t)row * 2304 + k0 + seg * 8]);
      }
      for (int u = tid; u < 1024; u += 256) {
        const int row = u >> 4, seg = u & 15;
        const int q = qsrc[row];
        uint4 val = make_uint4(0, 0, 0, 0);
        if (q >= 0)
          val = *reinterpret_cast<const uint4*>(&xb[(size_t)q * 256 + half * 128 + seg * 8]);
        *reinterpret_cast<uint4*>(&Bsm[row][seg * 8]) = val;
      }
      __syncthreads();
#pragma unroll
      for (int sub = 0; sub < 4; ++sub) {
        const int koff = sub * 32 + (lane >> 4) * 8;
        const bf16x8 b0 = *reinterpret_cast<const bf16x8*>(&Bsm[w * 16 + (lane & 15)][koff]);
#pragma unroll
        for (int mf = 0; mf < 2; ++mf) {
          const bf16x8 a0 = *reinterpret_cast<const bf16x8*>(&Asm[mf * 16 + (lane & 15)][koff]);
          acc[mf] = __builtin_amdgcn_mfma_f32_16x16x32_bf16(a0, b0, acc[mf], 0, 0, 0);
        }
      }
      __syncthreads();
    }
  }
#pragma unroll
  for (int mf = 0; mf < 2; ++mf) {
#pragma unroll
    for (int r = 0; r < 4; ++r) {
      const int o = mf * 16 + (lane >> 4) * 4 + r;
      const int n = w * 16 + (lane & 15);
      if (o < 27) som[o][n] = acc[mf][r] + ob[o];
    }
  }
  __syncthreads();
  for (int u = tid; u < 576; u += 256) {
    const int tap = u / 64, pp = u - (u / 64) * 64;
    const int p = n0 + pp;
    if (p >= N) continue;
    const float offy = som[tap][pp];
    const float offx = som[9 + tap][pp];
    const float mraw = som[18 + tap][pp];
    const float mval = 1.f / (1.f + __expf(-mraw));
    const int ky = tap / 3, kx = tap - (tap / 3) * 3;
    const int h = p / Wd, ww = p - (p / Wd) * Wd;
    const float py = offy + (float)(h + ky - 1);
    const float px = offx + (float)(ww + kx - 1);
    const float y0f = floorf(py), x0f = floorf(px);
    const float wy = py - y0f, wx = px - x0f;
    const int y0 = (int)y0f, x0 = (int)x0f;
    const int ys0 = min(max(y0, 0), H - 2);
    const int xs0 = min(max(x0, 0), Wd - 2);
    const float wr0 = (ys0 == y0) ? (1.f - wy) : ((ys0 == y0 + 1) ? wy : 0.f);
    const float wr1 = (ys0 + 1 == y0) ? (1.f - wy) : ((ys0 + 1 == y0 + 1) ? wy : 0.f);
    const float wc0 = (xs0 == x0) ? (1.f - wx) : ((xs0 == x0 + 1) ? wx : 0.f);
    const float wc1 = (xs0 + 1 == x0) ? (1.f - wx) : ((xs0 + 1 == x0 + 1) ? wx : 0.f);
    const float w00 = wr0 * wc0 * mval, w01 = wr0 * wc1 * mval;
    const float w10 = wr1 * wc0 * mval, w11 = wr1 * wc1 * mval;
    uint4 pk;
    pk.x = (uint)(ys0 * Wd + xs0);
    pk.y = (uint)f2bf(w00) | ((uint)f2bf(w01) << 16);
    pk.z = (uint)f2bf(w10) | ((uint)f2bf(w11) << 16);
    pk.w = 0;
    prep[((size_t)b * 9 + tap) * N + p] = pk;
  }
}

// ---------------------------------------------------------------------------
// fused DCN via MFMA (r14 best config)
// ---------------------------------------------------------------------------
__global__ __launch_bounds__(512) void dcn_fused_kernel(
    const ushort* __restrict__ xS, const uint4* __restrict__ prS,
    const ushort* __restrict__ AwS, const float* __restrict__ biS,
    float* __restrict__ oS, int NS_, int WS_, int NRS_,
    const ushort* __restrict__ xT, const uint4* __restrict__ prT,
    const ushort* __restrict__ AwT, const float* __restrict__ biT,
    float* __restrict__ oT, int NT_, int WT_, int NRT_) {
  constexpr int C = 256, MF = 4;
  __shared__ ushort Bsm[32][72];
  __shared__ int sq[32];
  __shared__ float swl[4][32];
  int bx, by, bz; bool isT;
  if (!fdecode(512, 32, 1, 8, 1, bx, by, bz, isT)) return;
  const ushort* xsT = isT ? xT : xS;
  const uint4* prep = isT ? prT : prS;
  const ushort* Awb = isT ? AwT : AwS;
  const float* bias = isT ? biT : biS;
  float* out = isT ? oT : oS;
  const int N = isT ? NT_ : NS_, Wd = isT ? WT_ : WS_, NR = isT ? NRT_ : NRS_;
  const int n0 = bx * 32, b = bz;
  const int tid = threadIdx.x, lane = tid & 63, w = tid >> 6;
  const int wr = w >> 1, wc = w & 1;
  const ushort* xb = xsT + (size_t)b * NR * C;
  const int un0 = tid >> 5;
  const int un1 = un0 + 16;
  const int kk2 = (tid & 31) * 2;
  f32x4 acc[MF];
#pragma unroll
  for (int i = 0; i < MF; i++) acc[i] = (f32x4){0.f, 0.f, 0.f, 0.f};
  uint bReg[2][4];
  int sqr0 = 0, sqr1 = 0;
  float w0a[4], w1a[4];
  const size_t rowYp = (size_t)Wd * C;
  for (int tap = 0; tap < 9; ++tap) {
    if (tid < 32) {
      const int p = n0 + tid;
      if (p < N) {
        const uint4 pk = prep[((size_t)b * 9 + tap) * N + p];
        sq[tid] = (int)pk.x * C;
        swl[0][tid] = bf2f((ushort)(pk.y & 0xffff));
        swl[1][tid] = bf2f((ushort)(pk.y >> 16));
        swl[2][tid] = bf2f((ushort)(pk.z & 0xffff));
        swl[3][tid] = bf2f((ushort)(pk.z >> 16));
      } else {
        sq[tid] = 0;
        swl[0][tid] = swl[1][tid] = swl[2][tid] = swl[3][tid] = 0.f;
      }
    }
    __syncthreads();
    sqr0 = sq[un0];
    sqr1 = sq[un1];
#pragma unroll
    for (int q = 0; q < 4; q++) {
      w0a[q] = swl[q][un0];
      w1a[q] = swl[q][un1];
    }
    {
      const ushort* pA = xb + sqr0 + kk2;
      bReg[0][0] = *reinterpret_cast<const uint*>(pA);
      bReg[0][1] = *reinterpret_cast<const uint*>(pA + C);
      bReg[0][2] = *reinterpret_cast<const uint*>(pA + rowYp);
      bReg[0][3] = *reinterpret_cast<const uint*>(pA + rowYp + C);
      const ushort* pB = xb + sqr1 + kk2;
      bReg[1][0] = *reinterpret_cast<const uint*>(pB);
      bReg[1][1] = *reinterpret_cast<const uint*>(pB + C);
      bReg[1][2] = *reinterpret_cast<const uint*>(pB + rowYp);
      bReg[1][3] = *reinterpret_cast<const uint*>(pB + rowYp + C);
    }
#pragma unroll
    for (int ks = 0; ks < 4; ++ks) {
      bf16x8 afr[2][4];
      const int ktb = tap * 8 + ks * 2;
#pragma unroll
      for (int sub = 0; sub < 2; ++sub)
#pragma unroll
        for (int mf = 0; mf < 4; ++mf)
          afr[sub][mf] = *reinterpret_cast<const bf16x8*>(
              Awb + ((((size_t)(wr * 4 + mf) * 72) + ktb + sub) << 9) + lane * 8);
      {
        const float vlo0 = w0a[0] * bflo(bReg[0][0]) + w0a[1] * bflo(bReg[0][1]) +
                           w0a[2] * bflo(bReg[0][2]) + w0a[3] * bflo(bReg[0][3]);
        const float vhi0 = w0a[0] * bfhi(bReg[0][0]) + w0a[1] * bfhi(bReg[0][1]) +
                           w0a[2] * bfhi(bReg[0][2]) + w0a[3] * bfhi(bReg[0][3]);
        *reinterpret_cast<uint*>(&Bsm[un0][kk2]) =
            (uint)f2bf(vlo0) | ((uint)f2bf(vhi0) << 16);
        const float vlo1 = w1a[0] * bflo(bReg[1][0]) + w1a[1] * bflo(bReg[1][1]) +
                           w1a[2] * bflo(bReg[1][2]) + w1a[3] * bflo(bReg[1][3]);
        const float vhi1 = w1a[0] * bfhi(bReg[1][0]) + w1a[1] * bfhi(bReg[1][1]) +
                           w1a[2] * bfhi(bReg[1][2]) + w1a[3] * bfhi(bReg[1][3]);
        *reinterpret_cast<uint*>(&Bsm[un1][kk2]) =
            (uint)f2bf(vlo1) | ((uint)f2bf(vhi1) << 16);
      }
      __syncthreads();
      if (ks < 3) {
        const int c1 = (ks + 1) * 64;
        const ushort* pA = xb + sqr0 + c1 + kk2;
        bReg[0][0] = *reinterpret_cast<const uint*>(pA);
        bReg[0][1] = *reinterpret_cast<const uint*>(pA + C);
        bReg[0][2] = *reinterpret_cast<const uint*>(pA + rowYp);
        bReg[0][3] = *reinterpret_cast<const uint*>(pA + rowYp + C);
        const ushort* pB = xb + sqr1 + c1 + kk2;
        bReg[1][0] = *reinterpret_cast<const uint*>(pB);
        bReg[1][1] = *reinterpret_cast<const uint*>(pB + C);
        bReg[1][2] = *reinterpret_cast<const uint*>(pB + rowYp);
        bReg[1][3] = *reinterpret_cast<const uint*>(pB + rowYp + C);
      }
#pragma unroll
      for (int sub = 0; sub < 2; ++sub) {
        const int koff = sub * 32 + (lane >> 4) * 8;
        const bf16x8 bfv = *reinterpret_cast<const bf16x8*>(&Bsm[wc * 16 + (lane & 15)][koff]);
#pragma unroll
        for (int mf = 0; mf < MF; mf++)
          acc[mf] = __builtin_amdgcn_mfma_f32_16x16x32_bf16(afr[sub][mf], bfv, acc[mf], 0, 0, 0);
      }
      __syncthreads();
    }
  }
  const int gn = n0 + wc * 16 + (lane & 15);
#pragma unroll
  for (int mf = 0; mf < MF; mf++) {
    const int mbase = wr * 64 + mf * 16 + ((lane >> 4) * 4);
    if (gn < N) {
#pragma unroll
      for (int rr = 0; rr < 4; rr++)
        out[((size_t)b * C + mbase + rr) * N + gn] = acc[mf][rr] + bias[mbase + rr];
    }
  }
}

// ---------------------------------------------------------------------------
extern "C" void kernel_launch(void* const* d_in, const int* in_sizes, int n_in,
                              void* d_out, int out_size, void* d_ws, size_t ws_size,
                              hipStream_t stream) {
  const float* t_in = (const float*)d_in[0];
  const float* s_in = (const float*)d_in[1];
  const float* t_qw = (const float*)d_in[2];
  const float* t_qb = (const float*)d_in[3];
  const float* t_kw = (const float*)d_in[4];
  const float* t_kb = (const float*)d_in[5];
  const float* t_vw = (const float*)d_in[6];
  const float* t_vb = (const float*)d_in[7];
  const float* t_g = (const float*)d_in[8];
  const float* s_qw = (const float*)d_in[9];
  const float* s_qb = (const float*)d_in[10];
  const float* s_kw = (const float*)d_in[11];
  const float* s_kb = (const float*)d_in[12];
  const float* s_vw = (const float*)d_in[13];
  const float* s_vb = (const float*)d_in[14];
  const float* s_g = (const float*)d_in[15];
  const float* w_t_ch = (const float*)d_in[16];
  const float* w_s_ch = (const float*)d_in[17];
  const float* w_s2t = (const float*)d_in[18];
  const float* w_t2s = (const float*)d_in[19];
  const float* t_off_w = (const float*)d_in[20];
  const float* t_off_b = (const float*)d_in[21];
  const float* t_dcn_w = (const float*)d_in[22];
  const float* t_dcn_b = (const float*)d_in[23];
  const float* s_off_w = (const float*)d_in[24];
  const float* s_off_b = (const float*)d_in[25];
  const float* s_dcn_w = (const float*)d_in[26];
  const float* s_dcn_b = (const float*)d_in[27];
  (void)in_sizes; (void)n_in; (void)out_size; (void)ws_size;

  constexpr int Bn = 16, C = 256;
  constexpr int HT = 15, WT = 15, NT = HT * WT;    // 225
  constexpr int HS = 31, WS2 = 31, NS = HS * WS2;  // 961
  constexpr int NpT = 256, NpS = 1024;             // Np widened to 1024 (r22)
  constexpr int NRT = 256, NRS = 1024;

  float* ws = (float*)d_ws;
  size_t off = 0;
  auto alloc = [&](size_t n) {
    n = (n + 3) & ~(size_t)3;
    float* p = ws + off; off += n; return p;
  };
  auto allocU = [&](size_t nu) { return (ushort*)alloc((nu + 1) / 2); };

  float* qk_t = alloc((size_t)Bn * 64 * NT);
  float* qk_s = alloc((size_t)Bn * 64 * NS);
  ushort* Wall_t = allocU((size_t)320 * C);
  ushort* Wall_s = allocU((size_t)320 * C);
  float* biasAll_t = alloc(320);
  float* biasAll_s = alloc(320);
  ushort* xT_t = allocU((size_t)Bn * NRT * C);
  ushort* xT_s = allocU((size_t)Bn * NRS * C);
  ushort* xbf_t = allocU((size_t)Bn * C * NpT);
  ushort* xbf_s = allocU((size_t)Bn * C * NpS);
  ushort* v_tbf = allocU((size_t)Bn * C * NpT);
  ushort* v_sbf = allocU((size_t)Bn * C * NpS);
  ushort* pvb_t = allocU((size_t)Bn * NpT * C);
  ushort* pvb_s = allocU((size_t)Bn * NpS * C);
  ushort* xsT_t = allocU((size_t)Bn * NRT * C);
  ushort* xsT_s = allocU((size_t)Bn * NRS * C);
  float* Atc = alloc((size_t)Bn * C * C);
  float* Asc = alloc((size_t)Bn * C * C);
  ushort* Mc_t = allocU((size_t)Bn * C * C);
  ushort* Mc_s = allocU((size_t)Bn * C * C);
  ushort* owb_t = allocU((size_t)32 * 2304);
  ushort* owb_s = allocU((size_t)32 * 2304);
  ushort* Awb_t = allocU((size_t)256 * 2304);
  ushort* Awb_s = allocU((size_t)256 * 2304);
  uint4* prep_t = (uint4*)alloc((size_t)Bn * 9 * NT * 4);
  uint4* prep_s = (uint4*)alloc((size_t)Bn * 9 * NS * 4);

  dim3 blk(256);

  // 1. UNION A: weight prep (5832) + cast/transpose/pad (1280)
  prep_cast_fused_kernel<<<dim3(5832 + 1280), blk, 0, stream>>>(
      t_qw, t_qb, t_kw, t_kb, s_qw, s_qb, s_kw, s_kb,
      t_vw, t_vb, s_vw, s_vb, t_off_w, s_off_w, t_dcn_w, s_dcn_w,
      Wall_t, Wall_s, biasAll_t, biasAll_s, owb_t, owb_s, Awb_t, Awb_s,
      s_in, xT_s, xbf_s, NS, NRS, NpS, t_in, xT_t, xbf_t, NT, NRT, NpT);

  // 2. UNION B: combined projection GEMM (1600) + gram GEMM (256)
  proj_gram_fused_kernel<<<dim3(1600 + 256), blk, 0, stream>>>(
      Wall_s, biasAll_s, xT_s, v_sbf, qk_s, NS, NpS, NRS,
      Wall_t, biasAll_t, xT_t, v_tbf, qk_t, NT, NpT, NRT,
      xbf_s, Asc, NpS, xbf_t, Atc, NpT);

  // 3. UNION C: flash spatial attention (640) + channel softmax/mcomb (4096)
  flash_mcomb_fused_kernel<<<dim3(640 + 4096), blk, 0, stream>>>(
      qk_s, v_sbf, s_g, pvb_s, NS, NpS,
      qk_t, v_tbf, t_g, pvb_t, NT, NpT,
      Atc, Asc, w_t_ch, w_s2t, w_s_ch, w_t2s, Mc_t, Mc_s);

  // 4. chan GEMM + pv add -> xsT
  pv_chan_fused_kernel<<<dim3(640), blk, 0, stream>>>(
      pvb_s, Mc_s, xT_s, s_in, xsT_s, NS, NpS, NRS,
      pvb_t, Mc_t, xT_t, t_in, xsT_t, NT, NpT, NRT);

  // 5. fused offconv + gather-table prep
  offconv_prep_fused_kernel<<<dim3(320), blk, 0, stream>>>(
      xsT_s, owb_s, s_off_b, prep_s, HS, WS2, NS, NRS,
      xsT_t, owb_t, t_off_b, prep_t, HT, WT, NT, NRT);

  // 6. fused DCN (r14 best config)
  float* out_t = (float*)d_out;
  float* out_s = out_t + (size_t)Bn * C * NT;
  dcn_fused_kernel<<<dim3(640), dim3(512), 0, stream>>>(
      xsT_s, prep_s, Awb_s, s_dcn_b, out_s, NS, WS2, NRS,
      xsT_t, prep_t, Awb_t, t_dcn_b, out_t, NT, WT, NRT);
}